// Round 1
// baseline (6063.666 us; speedup 1.0000x reference)
//
#include <hip/hip_runtime.h>

#define BATCH 16
#define NBATCH 32
#define SEQL 130
#define LSEQ 131
#define DIM 512
#define HEADS 8
#define DH 64
#define MF 256
#define VSZ 523
#define ROWS (BATCH*SEQL)          // 2080
#define BHL (BATCH*HEADS*SEQL)     // 16640

// ---------------- reduction helpers (256-thread blocks, deterministic) -----
__device__ __forceinline__ float blk_sum(float v){
  #pragma unroll
  for(int off=32;off;off>>=1) v += __shfl_xor(v,off);
  __shared__ float tmp_s[4];
  int t=threadIdx.x;
  if((t&63)==0) tmp_s[t>>6]=v;
  __syncthreads();
  v = tmp_s[0]+tmp_s[1]+tmp_s[2]+tmp_s[3];
  __syncthreads();
  return v;
}
__device__ __forceinline__ float blk_max(float v){
  #pragma unroll
  for(int off=32;off;off>>=1) v = fmaxf(v,__shfl_xor(v,off));
  __shared__ float tmp_m[4];
  int t=threadIdx.x;
  if((t&63)==0) tmp_m[t>>6]=v;
  __syncthreads();
  v = fmaxf(fmaxf(tmp_m[0],tmp_m[1]),fmaxf(tmp_m[2],tmp_m[3]));
  __syncthreads();
  return v;
}

__device__ __forceinline__ float gelu_f(float x){
  float x3 = x*x*x;
  return 0.5f*x*(1.f+tanhf(0.7978845608028654f*(x+0.044715f*x3)));
}

// ---------------- conv1: (32,1,16,16,16) -> relu (32,32,8,8,8), stride2 pad1
__global__ __launch_bounds__(256) void conv1_k(const float* __restrict__ x,
    const float* __restrict__ xn, const float* __restrict__ w,
    const float* __restrict__ bias, float* __restrict__ out){
  int idx = blockIdx.x*256 + threadIdx.x;
  if(idx >= NBATCH*32*8*8*8) return;
  int ow = idx & 7, oh = (idx>>3)&7, od = (idx>>6)&7, oc = (idx>>9)&31, n = idx>>14;
  const float* xp = (n<16) ? (x + n*4096) : (xn + (n-16)*4096);
  const float* wp = w + oc*64;
  float acc = bias[oc];
  #pragma unroll
  for(int kd=0;kd<4;kd++){ int id = od*2-1+kd; if((unsigned)id>=16u) continue;
    #pragma unroll
    for(int kh=0;kh<4;kh++){ int ih = oh*2-1+kh; if((unsigned)ih>=16u) continue;
      #pragma unroll
      for(int kw=0;kw<4;kw++){ int iw = ow*2-1+kw; if((unsigned)iw>=16u) continue;
        acc += xp[(id*16+ih)*16+iw]*wp[(kd*4+kh)*4+kw];
      }}}
  out[idx] = fmaxf(acc,0.f);
}

// ---------------- conv2: (32,32,8,8,8) -> (32,64,4,4,4), stride2 pad1 ------
__global__ __launch_bounds__(256) void conv2_k(const float* __restrict__ c1,
    const float* __restrict__ w, const float* __restrict__ bias,
    float* __restrict__ out){
  int idx = blockIdx.x*256 + threadIdx.x;
  if(idx >= NBATCH*64*4*4*4) return;
  int ow = idx & 3, oh = (idx>>2)&3, od = (idx>>4)&3, oc = (idx>>6)&63, n = idx>>12;
  float acc = bias[oc];
  for(int ic=0; ic<32; ic++){
    const float* cp = c1 + (n*32+ic)*512;
    const float* wp = w + (oc*32+ic)*64;
    #pragma unroll
    for(int kd=0;kd<4;kd++){ int id = od*2-1+kd; if((unsigned)id>=8u) continue;
      #pragma unroll
      for(int kh=0;kh<4;kh++){ int ih = oh*2-1+kh; if((unsigned)ih>=8u) continue;
        #pragma unroll
        for(int kw=0;kw<4;kw++){ int iw = ow*2-1+kw; if((unsigned)iw>=8u) continue;
          acc += cp[(id*8+ih)*8+iw]*wp[(kd*4+kh)*4+kw];
        }}}
  }
  out[idx] = acc;   // layout (n, oc, od, oh, ow)
}

// ---------------- VQ argmin: flat (2048,64) vs codebook (512,64) -----------
__global__ __launch_bounds__(256) void vq_k(const float* __restrict__ c2,
    const float* __restrict__ cb, int* __restrict__ inds){
  int nf = blockIdx.x;               // 0..2047
  int nb = nf>>6, sp = nf&63;
  __shared__ float z[64];
  int t = threadIdx.x;
  if(t<64) z[t] = c2[(nb*64+t)*64 + sp];
  __syncthreads();
  float best = 3.0e38f; int bi = 0;
  for(int j=t; j<512; j+=256){
    const float* cr = cb + j*64;
    float dot=0.f, nn=0.f;
    #pragma unroll 8
    for(int d=0;d<64;d++){ float cv=cr[d]; dot += z[d]*cv; nn += cv*cv; }
    float dist = nn - 2.f*dot;
    if(dist < best){ best=dist; bi=j; }
  }
  #pragma unroll
  for(int off=32;off;off>>=1){
    float ob = __shfl_down(best,off); int oi = __shfl_down(bi,off);
    if(ob<best || (ob==best && oi<bi)){ best=ob; bi=oi; }
  }
  __shared__ float rb[4]; __shared__ int ri[4];
  if((t&63)==0){ rb[t>>6]=best; ri[t>>6]=bi; }
  __syncthreads();
  if(t==0){
    for(int wv=1;wv<4;wv++){ if(rb[wv]<best || (rb[wv]==best && ri[wv]<bi)){ best=rb[wv]; bi=ri[wv]; } }
    inds[nf]=bi;
  }
}

// ---------------- build seq (16,131) ---------------------------------------
__global__ void seq_k(const int* __restrict__ iarr, const int* __restrict__ inds,
                      int* __restrict__ seq){
  int idx = blockIdx.x*256 + threadIdx.x;
  if(idx >= BATCH*LSEQ) return;
  int b = idx/LSEQ, p = idx%LSEQ;
  int v;
  if(p<3)       v = iarr[b*3+p];
  else if(p<67) v = inds[(16+b)*64 + (p-3)];
  else          v = inds[b*64 + (p-67)];
  seq[idx] = v;
}

// ---------------- embedding -------------------------------------------------
__global__ __launch_bounds__(256) void embed_k(const int* __restrict__ seq,
    const float* __restrict__ tok, const float* __restrict__ pos,
    float* __restrict__ h){
  int idx = blockIdx.x*256 + threadIdx.x;   // ROWS*DIM
  int c = idx & 511; int row = idx >> 9;
  int b = row/SEQL, l = row%SEQL;
  int tk = seq[b*LSEQ + l];
  h[idx] = tok[tk*DIM + c] + pos[l*DIM + c];
}

// ---------------- layernorm (row of 512) ------------------------------------
__global__ __launch_bounds__(256) void ln_k(const float* __restrict__ in,
    const float* __restrict__ g, const float* __restrict__ bb,
    float* __restrict__ out){
  int row = blockIdx.x; int t = threadIdx.x;
  const float* xr = in + row*DIM;
  float x0 = xr[t], x1 = xr[t+256];
  float s = x0+x1, ss = x0*x0 + x1*x1;
  #pragma unroll
  for(int off=32;off;off>>=1){ s += __shfl_xor(s,off); ss += __shfl_xor(ss,off); }
  __shared__ float bs[4], bss[4];
  if((t&63)==0){ bs[t>>6]=s; bss[t>>6]=ss; }
  __syncthreads();
  s = bs[0]+bs[1]+bs[2]+bs[3]; ss = bss[0]+bss[1]+bss[2]+bss[3];
  float mu = s*(1.f/512.f);
  float var = ss*(1.f/512.f) - mu*mu;
  float inv = rsqrtf(var + 1e-5f);
  out[row*DIM+t]     = (x0-mu)*inv*g[t]     + bb[t];
  out[row*DIM+t+256] = (x1-mu)*inv*g[t+256] + bb[t+256];
}

// ---------------- generic f32 GEMM: C[M,N] (+=) A[M,K]@B[K,N] (+bias)(gelu) -
template<int ACT, int ACC>
__global__ __launch_bounds__(256) void gemm_k(const float* __restrict__ A,
    const float* __restrict__ Bm, const float* __restrict__ bias,
    float* __restrict__ C, int M, int N, int K){
  __shared__ float As[16][64];
  __shared__ float Bs[16][64];
  int tid = threadIdx.x;
  int row0 = blockIdx.y*64, col0 = blockIdx.x*64;
  float acc[4][4] = {};
  int tm = tid>>4, tn = tid&15;
  int lr = tid>>2, lk = (tid&3)*4;     // A loader
  int lkb = tid>>4, lc = (tid&15)*4;   // B loader
  for(int k0=0; k0<K; k0+=16){
    int grow = row0 + lr;
    if(grow < M){
      const float* ap = A + grow*K + k0 + lk;
      As[lk+0][lr]=ap[0]; As[lk+1][lr]=ap[1]; As[lk+2][lr]=ap[2]; As[lk+3][lr]=ap[3];
    } else {
      As[lk+0][lr]=0.f; As[lk+1][lr]=0.f; As[lk+2][lr]=0.f; As[lk+3][lr]=0.f;
    }
    const float* bp = Bm + (size_t)(k0+lkb)*N + col0 + lc;
    #pragma unroll
    for(int j=0;j<4;j++){
      int gc = col0+lc+j;
      Bs[lkb][lc+j] = (gc < N) ? bp[j] : 0.f;
    }
    __syncthreads();
    #pragma unroll
    for(int kk=0;kk<16;kk++){
      float a0=As[kk][tm*4+0], a1=As[kk][tm*4+1], a2=As[kk][tm*4+2], a3=As[kk][tm*4+3];
      float b0=Bs[kk][tn*4+0], b1=Bs[kk][tn*4+1], b2=Bs[kk][tn*4+2], b3=Bs[kk][tn*4+3];
      acc[0][0]+=a0*b0; acc[0][1]+=a0*b1; acc[0][2]+=a0*b2; acc[0][3]+=a0*b3;
      acc[1][0]+=a1*b0; acc[1][1]+=a1*b1; acc[1][2]+=a1*b2; acc[1][3]+=a1*b3;
      acc[2][0]+=a2*b0; acc[2][1]+=a2*b1; acc[2][2]+=a2*b2; acc[2][3]+=a2*b3;
      acc[3][0]+=a3*b0; acc[3][1]+=a3*b1; acc[3][2]+=a3*b2; acc[3][3]+=a3*b3;
    }
    __syncthreads();
  }
  #pragma unroll
  for(int i=0;i<4;i++){
    int r = row0 + tm*4 + i; if(r>=M) continue;
    #pragma unroll
    for(int j=0;j<4;j++){
      int c = col0 + tn*4 + j; if(c>=N) continue;
      float val = acc[i][j];
      if(bias) val += bias[c];
      if(ACT==1) val = gelu_f(val);
      if(ACC) C[(size_t)r*N+c] += val; else C[(size_t)r*N+c] = val;
    }
  }
}

// ---------------- query feature map (fused: per-row max) --------------------
__global__ __launch_bounds__(256) void ddq_k(const float* __restrict__ q,
    const float* __restrict__ proj, float* __restrict__ qp){
  int bid = blockIdx.x;                // (b*HEADS+h)*SEQL + l
  int b = bid/(HEADS*SEQL); int r = bid%(HEADS*SEQL);
  int hh = r/SEQL; int l = r%SEQL;
  const float* qr = q + ((size_t)(b*SEQL+l))*DIM + hh*DH;
  __shared__ float dn[64];
  int t = threadIdx.x;
  if(t<64) dn[t] = qr[t]*0.3535533905932738f;
  __syncthreads();
  const float* pr = proj + t*DH;
  float dot = 0.f;
  #pragma unroll 8
  for(int d=0;d<64;d++) dot += dn[d]*pr[d];
  float diag = 0.f;
  #pragma unroll 8
  for(int d=0;d<64;d++){ float z = dn[d]; diag += z*z; }
  diag *= 0.5f;
  float mx = blk_max(dot);
  qp[(size_t)bid*MF + t] = expf(dot - diag - mx)*0.0625f + 1e-4f;
}

// ---------------- key feature map pass 1 (raw dd + diag + block max) --------
__global__ __launch_bounds__(256) void ddk_k(const float* __restrict__ k,
    const float* __restrict__ proj, float* __restrict__ ddk,
    float* __restrict__ diagk, float* __restrict__ bmax){
  int bid = blockIdx.x;
  int b = bid/(HEADS*SEQL); int r = bid%(HEADS*SEQL);
  int hh = r/SEQL; int l = r%SEQL;
  const float* kr = k + ((size_t)(b*SEQL+l))*DIM + hh*DH;
  __shared__ float dn[64];
  int t = threadIdx.x;
  if(t<64) dn[t] = kr[t]*0.3535533905932738f;
  __syncthreads();
  const float* pr = proj + t*DH;
  float dot = 0.f;
  #pragma unroll 8
  for(int d=0;d<64;d++) dot += dn[d]*pr[d];
  float diag = 0.f;
  #pragma unroll 8
  for(int d=0;d<64;d++){ float z = dn[d]; diag += z*z; }
  diag *= 0.5f;
  float mx = blk_max(dot);
  ddk[(size_t)bid*MF + t] = dot;
  if(t==0){ diagk[bid] = diag; bmax[bid] = mx; }
}

__global__ __launch_bounds__(256) void gmax_k(const float* __restrict__ bmax,
    float* __restrict__ gmax){
  int t = threadIdx.x;
  float m = -3.0e38f;
  for(int i=t;i<BHL;i+=256) m = fmaxf(m, bmax[i]);
  m = blk_max(m);
  if(t==0) gmax[0] = m;
}

__global__ __launch_bounds__(256) void kexp_k(float* __restrict__ kp,
    const float* __restrict__ diagk, const float* __restrict__ gmax){
  int idx = blockIdx.x*256 + threadIdx.x;   // BHL*MF
  float g = gmax[0];
  kp[idx] = expf(kp[idx] - diagk[idx>>8] - g)*0.0625f + 1e-4f;
}

// ---------------- causal linear attention scan ------------------------------
__global__ __launch_bounds__(256) void scan_k(const float* __restrict__ qp,
    const float* __restrict__ kp, const float* __restrict__ v,
    float* __restrict__ o){
  int bh = blockIdx.x;                 // b*HEADS+h
  int b = bh/HEADS, hh = bh%HEADS;
  __shared__ float kv[MF*DH];          // 64KB, [m][d]
  __shared__ float kc[MF];
  __shared__ float kpl[MF], qpl[MF], vl[DH];
  __shared__ float pbuf[256];
  __shared__ float denb[4];
  int t = threadIdx.x;
  for(int i=t;i<MF*DH;i+=256) kv[i]=0.f;
  kc[t]=0.f;
  __syncthreads();
  const float* qpb = qp + (size_t)bh*SEQL*MF;
  const float* kpb = kp + (size_t)bh*SEQL*MF;
  int d = t&63, qq = t>>6;
  for(int l=0;l<SEQL;l++){
    kpl[t] = kpb[l*MF+t];
    qpl[t] = qpb[l*MF+t];
    if(t<64) vl[t] = v[((size_t)(b*SEQL+l))*DIM + hh*DH + t];
    __syncthreads();
    // kc update + den partial (thread t owns m=t)
    float kcm = kc[t] + kpl[t]; kc[t] = kcm;
    float dp = qpl[t]*kcm;
    #pragma unroll
    for(int off=32;off;off>>=1) dp += __shfl_xor(dp,off);
    if((t&63)==0) denb[t>>6]=dp;
    // kv update + out partial: quarter qq handles m in [qq*64, qq*64+64)
    float vd = vl[d];
    float a0=0.f, a1=0.f;
    int mbase = qq*64;
    #pragma unroll 8
    for(int mi=0;mi<64;mi+=2){
      int m0 = mbase+mi, m1 = mbase+mi+1;
      float kv0 = kv[m0*DH+d] + kpl[m0]*vd; kv[m0*DH+d]=kv0; a0 += qpl[m0]*kv0;
      float kv1 = kv[m1*DH+d] + kpl[m1]*vd; kv[m1*DH+d]=kv1; a1 += qpl[m1]*kv1;
    }
    pbuf[t] = a0+a1;
    __syncthreads();
    if(t<64){
      float den = denb[0]+denb[1]+denb[2]+denb[3];
      float ov = pbuf[t]+pbuf[64+t]+pbuf[128+t]+pbuf[192+t];
      o[((size_t)(b*SEQL+l))*DIM + hh*DH + t] = ov/den;
    }
    __syncthreads();
  }
}

// ---------------- loss ------------------------------------------------------
__global__ __launch_bounds__(256) void loss_k(const float* __restrict__ logits,
    const int* __restrict__ seq, float* __restrict__ rnll){
  int row = blockIdx.x; int t = threadIdx.x;
  const float* lr = logits + (size_t)row*VSZ;
  float m = -3.0e38f;
  for(int j=t;j<VSZ;j+=256) m = fmaxf(m, lr[j]);
  m = blk_max(m);
  float s = 0.f;
  for(int j=t;j<VSZ;j+=256) s += expf(lr[j]-m);
  s = blk_sum(s);
  if(t==0){
    int b = row/SEQL, l = row%SEQL;
    int tgt = seq[b*LSEQ + l + 1];
    rnll[row] = (m + logf(s)) - lr[tgt];
  }
}

__global__ __launch_bounds__(256) void fin_k(const float* __restrict__ rnll,
    float* __restrict__ out){
  int t = threadIdx.x;
  float s = 0.f;
  for(int i=t;i<ROWS;i+=256) s += rnll[i];
  s = blk_sum(s);
  if(t==0) out[0] = s/(float)ROWS;
}

// ---------------------------------------------------------------------------
extern "C" void kernel_launch(void* const* d_in, const int* in_sizes, int n_in,
                              void* d_out, int out_size, void* d_ws, size_t ws_size,
                              hipStream_t stream){
  (void)in_sizes; (void)n_in; (void)out_size; (void)ws_size;
  const float* x        = (const float*)d_in[0];
  const float* xn       = (const float*)d_in[1];
  const int*   iarr     = (const int*)  d_in[2];
  const float* conv1_w  = (const float*)d_in[3];
  const float* conv1_b  = (const float*)d_in[4];
  const float* conv2_w  = (const float*)d_in[5];
  const float* conv2_b  = (const float*)d_in[6];
  const float* codebook = (const float*)d_in[7];
  const float* proj     = (const float*)d_in[8];
  const float* tok_emb  = (const float*)d_in[9];
  const float* pos_emb  = (const float*)d_in[10];
  const float* ln1_g    = (const float*)d_in[11];
  const float* ln1_b    = (const float*)d_in[12];
  const float* wq       = (const float*)d_in[13];
  const float* wk       = (const float*)d_in[14];
  const float* wv       = (const float*)d_in[15];
  const float* wo       = (const float*)d_in[16];
  const float* bo       = (const float*)d_in[17];
  const float* ln2_g    = (const float*)d_in[18];
  const float* ln2_b    = (const float*)d_in[19];
  const float* ff1_w    = (const float*)d_in[20];
  const float* ff1_b    = (const float*)d_in[21];
  const float* ff2_w    = (const float*)d_in[22];
  const float* ff2_b    = (const float*)d_in[23];
  const float* lnf_g    = (const float*)d_in[24];
  const float* lnf_b    = (const float*)d_in[25];
  const float* logits_w = (const float*)d_in[26];
  const float* logits_b = (const float*)d_in[27];

  float* wsf = (float*)d_ws;
  size_t off = 0;
  float* c1    = wsf + off; off += 524288;       // 32*32*8*8*8
  float* c2    = wsf + off; off += 131072;       // 32*64*4*4*4
  int*   inds  = (int*)(wsf + off); off += 2048;
  int*   seq   = (int*)(wsf + off); off += 2112;
  float* h     = wsf + off; off += (size_t)ROWS*DIM;
  float* x1    = wsf + off; off += (size_t)ROWS*DIM;
  float* qb    = wsf + off; off += (size_t)ROWS*DIM;
  float* kb    = wsf + off; off += (size_t)ROWS*DIM;
  float* vb    = wsf + off; off += (size_t)ROWS*DIM;
  float* ob    = wsf + off; off += (size_t)ROWS*DIM;
  float* qpb   = wsf + off; off += (size_t)BHL*MF;   // aliased as ffmid
  float* kpb   = wsf + off; off += (size_t)BHL*MF;   // aliased as logits
  float* diagk = wsf + off; off += BHL;
  float* bmax  = wsf + off; off += BHL;
  float* gmax  = wsf + off; off += 64;
  float* rnll  = wsf + off; off += 2112;
  float* ffmid  = qpb;
  float* logits = kpb;

  conv1_k<<<2048,256,0,stream>>>(x, xn, conv1_w, conv1_b, c1);
  conv2_k<<<512,256,0,stream>>>(c1, conv2_w, conv2_b, c2);
  vq_k<<<2048,256,0,stream>>>(c2, codebook, inds);
  seq_k<<<(BATCH*LSEQ+255)/256,256,0,stream>>>(iarr, inds, seq);
  embed_k<<<(ROWS*DIM)/256,256,0,stream>>>(seq, tok_emb, pos_emb, h);

  for(int l=0;l<6;l++){
    const float* wq_l = wq + (size_t)l*DIM*DIM;
    const float* wk_l = wk + (size_t)l*DIM*DIM;
    const float* wv_l = wv + (size_t)l*DIM*DIM;
    const float* wo_l = wo + (size_t)l*DIM*DIM;
    const float* pj_l = proj + (size_t)l*MF*DH;
    const float* f1_l = ff1_w + (size_t)l*DIM*2048;
    const float* f2_l = ff2_w + (size_t)l*2048*DIM;

    ln_k<<<ROWS,256,0,stream>>>(h, ln1_g+l*DIM, ln1_b+l*DIM, x1);
    gemm_k<0,0><<<dim3(8,33),256,0,stream>>>(x1, wq_l, nullptr, qb, ROWS, DIM, DIM);
    gemm_k<0,0><<<dim3(8,33),256,0,stream>>>(x1, wk_l, nullptr, kb, ROWS, DIM, DIM);
    gemm_k<0,0><<<dim3(8,33),256,0,stream>>>(x1, wv_l, nullptr, vb, ROWS, DIM, DIM);
    ddq_k<<<BHL,256,0,stream>>>(qb, pj_l, qpb);
    ddk_k<<<BHL,256,0,stream>>>(kb, pj_l, kpb, diagk, bmax);
    gmax_k<<<1,256,0,stream>>>(bmax, gmax);
    kexp_k<<<(BHL*MF)/256,256,0,stream>>>(kpb, diagk, gmax);
    scan_k<<<BATCH*HEADS,256,0,stream>>>(qpb, kpb, vb, ob);
    gemm_k<0,1><<<dim3(8,33),256,0,stream>>>(ob, wo_l, bo+l*DIM, h, ROWS, DIM, DIM);
    ln_k<<<ROWS,256,0,stream>>>(h, ln2_g+l*DIM, ln2_b+l*DIM, x1);
    gemm_k<1,0><<<dim3(32,33),256,0,stream>>>(x1, f1_l, ff1_b+l*2048, ffmid, ROWS, 2048, DIM);
    gemm_k<0,1><<<dim3(8,33),256,0,stream>>>(ffmid, f2_l, ff2_b+l*DIM, h, ROWS, DIM, 2048);
  }

  ln_k<<<ROWS,256,0,stream>>>(h, lnf_g, lnf_b, x1);
  gemm_k<0,0><<<dim3(9,33),256,0,stream>>>(x1, logits_w, logits_b, logits, ROWS, VSZ, DIM);
  loss_k<<<ROWS,256,0,stream>>>(logits, seq, rnll);
  fin_k<<<1,256,0,stream>>>(rnll, (float*)d_out);
}

// Round 2
// 1227.748 us; speedup vs baseline: 4.9389x; 4.9389x over previous
//
#include <hip/hip_runtime.h>

#define SEQL 130
#define LSEQ 131
#define DIMM 512
#define NHEADS 8
#define MF 256
#define VSZ 523
#define NROWS (16*SEQL)          // 2080
#define NBH (16*NHEADS)          // 128
#define NBHL (NBH*SEQL)          // 16640

typedef __attribute__((ext_vector_type(8))) short short8;
typedef __attribute__((ext_vector_type(8))) unsigned short us8;
typedef __attribute__((ext_vector_type(4))) unsigned short us4;
typedef __attribute__((ext_vector_type(4))) float f32x4;

__device__ __forceinline__ unsigned short f2bf(float f){
  unsigned int u = __float_as_uint(f);
  u += 0x7fffu + ((u>>16)&1u);
  return (unsigned short)(u>>16);
}
__device__ __forceinline__ float bf2f(unsigned short h){
  return __uint_as_float(((unsigned int)h)<<16);
}
__device__ __forceinline__ float gelu_f(float x){
  float x3 = x*x*x;
  return 0.5f*x*(1.f+tanhf(0.7978845608028654f*(x+0.044715f*x3)));
}
__device__ __forceinline__ float blk_sum(float v){
  #pragma unroll
  for(int off=32;off;off>>=1) v += __shfl_xor(v,off);
  __shared__ float tmp_s[4];
  int t=threadIdx.x;
  if((t&63)==0) tmp_s[t>>6]=v;
  __syncthreads();
  v = tmp_s[0]+tmp_s[1]+tmp_s[2]+tmp_s[3];
  __syncthreads();
  return v;
}
__device__ __forceinline__ float blk_max(float v){
  #pragma unroll
  for(int off=32;off;off>>=1) v = fmaxf(v,__shfl_xor(v,off));
  __shared__ float tmp_m[4];
  int t=threadIdx.x;
  if((t&63)==0) tmp_m[t>>6]=v;
  __syncthreads();
  v = fmaxf(fmaxf(tmp_m[0],tmp_m[1]),fmaxf(tmp_m[2],tmp_m[3]));
  __syncthreads();
  return v;
}

// ---------------- conv1: (32,1,16,16,16) -> relu (32,32,8,8,8), stride2 pad1
__global__ __launch_bounds__(256) void conv1_k(const float* __restrict__ x,
    const float* __restrict__ xn, const float* __restrict__ w,
    const float* __restrict__ bias, float* __restrict__ out){
  int idx = blockIdx.x*256 + threadIdx.x;
  if(idx >= 32*32*8*8*8) return;
  int ow = idx & 7, oh = (idx>>3)&7, od = (idx>>6)&7, oc = (idx>>9)&31, n = idx>>14;
  const float* xp = (n<16) ? (x + n*4096) : (xn + (n-16)*4096);
  const float* wp = w + oc*64;
  float acc = bias[oc];
  #pragma unroll
  for(int kd=0;kd<4;kd++){ int id = od*2-1+kd; if((unsigned)id>=16u) continue;
    #pragma unroll
    for(int kh=0;kh<4;kh++){ int ih = oh*2-1+kh; if((unsigned)ih>=16u) continue;
      #pragma unroll
      for(int kw=0;kw<4;kw++){ int iw = ow*2-1+kw; if((unsigned)iw>=16u) continue;
        acc += xp[(id*16+ih)*16+iw]*wp[(kd*4+kh)*4+kw];
      }}}
  out[idx] = fmaxf(acc,0.f);
}

// ---------------- conv2: (32,32,8,8,8) -> (32,64,4,4,4), stride2 pad1 ------
__global__ __launch_bounds__(256) void conv2_k(const float* __restrict__ c1,
    const float* __restrict__ w, const float* __restrict__ bias,
    float* __restrict__ out){
  int idx = blockIdx.x*256 + threadIdx.x;
  if(idx >= 32*64*4*4*4) return;
  int ow = idx & 3, oh = (idx>>2)&3, od = (idx>>4)&3, oc = (idx>>6)&63, n = idx>>12;
  float acc = bias[oc];
  for(int ic=0; ic<32; ic++){
    const float* cp = c1 + (n*32+ic)*512;
    const float* wp = w + (oc*32+ic)*64;
    #pragma unroll
    for(int kd=0;kd<4;kd++){ int id = od*2-1+kd; if((unsigned)id>=8u) continue;
      #pragma unroll
      for(int kh=0;kh<4;kh++){ int ih = oh*2-1+kh; if((unsigned)ih>=8u) continue;
        #pragma unroll
        for(int kw=0;kw<4;kw++){ int iw = ow*2-1+kw; if((unsigned)iw>=8u) continue;
          acc += cp[(id*8+ih)*8+iw]*wp[(kd*4+kh)*4+kw];
        }}}
  }
  out[idx] = acc;
}

// ---------------- VQ argmin ------------------------------------------------
__global__ __launch_bounds__(256) void vq_k(const float* __restrict__ c2,
    const float* __restrict__ cb, int* __restrict__ inds){
  int nf = blockIdx.x;               // 0..2047
  int nb = nf>>6, sp = nf&63;
  __shared__ float z[64];
  int t = threadIdx.x;
  if(t<64) z[t] = c2[(nb*64+t)*64 + sp];
  __syncthreads();
  float best = 3.0e38f; int bi = 0;
  for(int j=t; j<512; j+=256){
    const float* cr = cb + j*64;
    float dot=0.f, nn=0.f;
    #pragma unroll 8
    for(int d=0;d<64;d++){ float cv=cr[d]; dot += z[d]*cv; nn += cv*cv; }
    float dist = nn - 2.f*dot;
    if(dist < best){ best=dist; bi=j; }
  }
  #pragma unroll
  for(int off=32;off;off>>=1){
    float ob = __shfl_down(best,off); int oi = __shfl_down(bi,off);
    if(ob<best || (ob==best && oi<bi)){ best=ob; bi=oi; }
  }
  __shared__ float rb[4]; __shared__ int ri[4];
  if((t&63)==0){ rb[t>>6]=best; ri[t>>6]=bi; }
  __syncthreads();
  if(t==0){
    for(int wv=1;wv<4;wv++){ if(rb[wv]<best || (rb[wv]==best && ri[wv]<bi)){ best=rb[wv]; bi=ri[wv]; } }
    inds[nf]=bi;
  }
}

__global__ void seq_k(const int* __restrict__ iarr, const int* __restrict__ inds,
                      int* __restrict__ seq){
  int idx = blockIdx.x*256 + threadIdx.x;
  if(idx >= 16*LSEQ) return;
  int b = idx/LSEQ, p = idx%LSEQ;
  int v;
  if(p<3)       v = iarr[b*3+p];
  else if(p<67) v = inds[(16+b)*64 + (p-3)];
  else          v = inds[b*64 + (p-67)];
  seq[idx] = v;
}

__global__ __launch_bounds__(256) void embed_k(const int* __restrict__ seq,
    const float* __restrict__ tok, const float* __restrict__ pos,
    float* __restrict__ h){
  int idx = blockIdx.x*256 + threadIdx.x;   // NROWS*DIMM
  int c = idx & 511; int row = idx >> 9;
  int b = row/SEQL, l = row - b*SEQL;
  int tk = seq[b*LSEQ + l];
  h[idx] = tok[tk*DIMM + c] + pos[l*DIMM + c];
}

// ---------------- layernorm: f32 in, bf16 out -------------------------------
__global__ __launch_bounds__(256) void ln_k(const float* __restrict__ in,
    const float* __restrict__ g, const float* __restrict__ bb,
    unsigned short* __restrict__ out){
  int row = blockIdx.x; int t = threadIdx.x;
  const float* xr = in + (size_t)row*DIMM;
  float x0 = xr[t], x1 = xr[t+256];
  float s = x0+x1, ss = x0*x0 + x1*x1;
  #pragma unroll
  for(int off=32;off;off>>=1){ s += __shfl_xor(s,off); ss += __shfl_xor(ss,off); }
  __shared__ float bs[4], bss[4];
  if((t&63)==0){ bs[t>>6]=s; bss[t>>6]=ss; }
  __syncthreads();
  s = bs[0]+bs[1]+bs[2]+bs[3]; ss = bss[0]+bss[1]+bss[2]+bss[3];
  float mu = s*(1.f/512.f);
  float var = ss*(1.f/512.f) - mu*mu;
  float inv = rsqrtf(var + 1e-5f);
  out[(size_t)row*DIMM+t]     = f2bf((x0-mu)*inv*g[t]     + bb[t]);
  out[(size_t)row*DIMM+t+256] = f2bf((x1-mu)*inv*g[t+256] + bb[t+256]);
}

// ---------------- weight transpose+convert: [K][N] f32 -> [N][K] bf16 -------
struct PtrPack { const float* p0; const float* p1; const float* p2; const float* p3; };

__global__ __launch_bounds__(256) void wconv4_k(PtrPack pk, unsigned short* __restrict__ dst){
  int z = blockIdx.z;
  const float* W = z==0?pk.p0: z==1?pk.p1: z==2?pk.p2: pk.p3;
  __shared__ float tile[32][33];
  int k0 = blockIdx.y*32, n0 = blockIdx.x*32;
  int t = threadIdx.x; int c = t&31, r = t>>5;
  #pragma unroll
  for(int j=0;j<4;j++) tile[r+8*j][c] = W[(size_t)(k0+r+8*j)*512 + n0+c];
  __syncthreads();
  unsigned short* D = dst + (size_t)z*262144;
  #pragma unroll
  for(int j=0;j<4;j++){
    int n = n0 + r + 8*j;
    D[(size_t)n*512 + k0 + c] = f2bf(tile[c][r+8*j]);
  }
}

__global__ __launch_bounds__(256) void wconv_k(const float* __restrict__ W,
    unsigned short* __restrict__ dst, int K, int N){
  __shared__ float tile[32][33];
  int k0 = blockIdx.y*32, n0 = blockIdx.x*32;
  int t = threadIdx.x; int c = t&31, r = t>>5;
  #pragma unroll
  for(int j=0;j<4;j++){
    int n = n0+c;
    tile[r+8*j][c] = (n<N) ? W[(size_t)(k0+r+8*j)*N + n] : 0.f;
  }
  __syncthreads();
  #pragma unroll
  for(int j=0;j<4;j++){
    int n = n0 + r + 8*j;
    if(n<N) dst[(size_t)n*K + k0 + c] = f2bf(tile[c][r+8*j]);
  }
}

__global__ __launch_bounds__(256) void projcv_k(const float* __restrict__ proj,
    unsigned short* __restrict__ pb){
  int i = blockIdx.x*256 + threadIdx.x;
  if(i < 6*MF*64) pb[i] = f2bf(proj[i]);
}

// ---------------- MFMA GEMM: C[M,N] = A[M,K](bf16) @ Bt[N,K](bf16)^T --------
// MODE 0: f32 out (+optional bias)
// MODE 1: bf16 out, head-major [(b*8+h)*SEQL+l][64], *scale
// MODE 3: f32 accumulate += (bias)
// MODE 4: bf16 out, bias+gelu
template<int MODE>
__global__ __launch_bounds__(256) void mgemm_k(const unsigned short* __restrict__ A,
    const unsigned short* __restrict__ Bt, const float* __restrict__ bias,
    float* __restrict__ Cf, unsigned short* __restrict__ Cb,
    int M, int N, int K, float scale){
  __shared__ unsigned short As[4096];
  __shared__ unsigned short Bs[4096];
  int t = threadIdx.x;
  const int m0 = blockIdx.y*64, n0 = blockIdx.x*64;
  int w = t>>6, l = t&63;
  int wr = w>>1, wc = w&1;
  f32x4 acc[2][2] = {};
  int srow = t>>2, sp = (t&3)*2;
  int arow = m0 + srow, brow = n0 + srow;
  bool aok = arow < M, bok = brow < N;
  const us8* Ap = (const us8*)(A + (size_t)arow*K + sp*8);
  const us8* Bp = (const us8*)(Bt + (size_t)brow*K + sp*8);
  unsigned short* Aw0 = As + srow*64 + (((sp  )^(srow&7))<<3);
  unsigned short* Aw1 = As + srow*64 + (((sp+1)^(srow&7))<<3);
  unsigned short* Bw0 = Bs + srow*64 + (((sp  )^(srow&7))<<3);
  unsigned short* Bw1 = Bs + srow*64 + (((sp+1)^(srow&7))<<3);
  for(int k0=0; k0<K; k0+=64){
    us8 a0={}, a1={}, b0={}, b1={};
    if(aok){ a0 = Ap[0]; a1 = Ap[1]; }
    if(bok){ b0 = Bp[0]; b1 = Bp[1]; }
    Ap += 8; Bp += 8;
    __syncthreads();
    *(us8*)Aw0 = a0; *(us8*)Aw1 = a1;
    *(us8*)Bw0 = b0; *(us8*)Bw1 = b1;
    __syncthreads();
    #pragma unroll
    for(int kk=0;kk<2;kk++){
      short8 af[2], bf[2];
      #pragma unroll
      for(int m=0;m<2;m++){
        int row = wr*32 + m*16 + (l&15);
        int slot = kk*4 + (l>>4);
        af[m] = *(const short8*)(As + row*64 + ((slot^(row&7))<<3));
      }
      #pragma unroll
      for(int n=0;n<2;n++){
        int col = wc*32 + n*16 + (l&15);
        int slot = kk*4 + (l>>4);
        bf[n] = *(const short8*)(Bs + col*64 + ((slot^(col&7))<<3));
      }
      #pragma unroll
      for(int m=0;m<2;m++)
        #pragma unroll
        for(int n=0;n<2;n++)
          acc[m][n] = __builtin_amdgcn_mfma_f32_16x16x32_bf16(af[m], bf[n], acc[m][n], 0, 0, 0);
    }
  }
  // epilogue
  #pragma unroll
  for(int m=0;m<2;m++){
    #pragma unroll
    for(int n=0;n<2;n++){
      int col = n0 + wc*32 + n*16 + (l&15);
      #pragma unroll
      for(int i=0;i<4;i++){
        int row = m0 + wr*32 + m*16 + (l>>4)*4 + i;
        if(row < M && col < N){
          float v = acc[m][n][i];
          if(MODE==0){
            if(bias) v += bias[col];
            Cf[(size_t)row*N+col] = v;
          } else if(MODE==1){
            v *= scale;
            int bb = row/SEQL, ll = row - bb*SEQL;
            int hh = col>>6, d = col&63;
            Cb[(((size_t)(bb*NHEADS+hh))*SEQL + ll)*64 + d] = f2bf(v);
          } else if(MODE==3){
            v += bias[col];
            Cf[(size_t)row*N+col] += v;
          } else {
            v += bias[col];
            v = gelu_f(v);
            Cb[(size_t)row*N+col] = f2bf(v);
          }
        }
      }
    }
  }
}

// ---------------- q-side exp (per-row max), reads dd f32, writes bf16 -------
__global__ __launch_bounds__(256) void qexp_k(const float* __restrict__ dd,
    const unsigned short* __restrict__ qn, unsigned short* __restrict__ qp){
  int t = threadIdx.x;
  int rr = t>>4, lane = t&15;
  size_t R = (size_t)blockIdx.x*16 + rr;
  // diag from bf16 dn
  float ds = 0.f;
  {
    const unsigned short* s = qn + R*64 + lane*4;
    #pragma unroll
    for(int j=0;j<4;j++){ float x = bf2f(s[j]); ds += x*x; }
  }
  #pragma unroll
  for(int off=1;off<16;off<<=1) ds += __shfl_xor(ds,off);
  ds *= 0.5f;
  const float* dr = dd + R*256;
  f32x4 v[4];
  #pragma unroll
  for(int j=0;j<4;j++) v[j] = *(const f32x4*)(dr + lane*4 + j*64);
  float mx = -3.0e38f;
  #pragma unroll
  for(int j=0;j<4;j++)
    #pragma unroll
    for(int i=0;i<4;i++) mx = fmaxf(mx, v[j][i]);
  #pragma unroll
  for(int off=1;off<16;off<<=1) mx = fmaxf(mx, __shfl_xor(mx,off));
  unsigned short* op = qp + R*256;
  #pragma unroll
  for(int j=0;j<4;j++){
    us4 u;
    #pragma unroll
    for(int i=0;i<4;i++) u[i] = f2bf(expf(v[j][i] - ds - mx)*0.0625f + 1e-4f);
    *(us4*)(op + lane*4 + j*64) = u;
  }
}

__global__ __launch_bounds__(256) void kmax_k(const float* __restrict__ dd,
    float* __restrict__ bmax){
  int t = threadIdx.x;
  float m = -3.0e38f;
  for(size_t i = (size_t)blockIdx.x*256 + t; i < (size_t)NBHL*256; i += 65536)
    m = fmaxf(m, dd[i]);
  m = blk_max(m);
  if(t==0) bmax[blockIdx.x] = m;
}

__global__ __launch_bounds__(256) void gmax_k(const float* __restrict__ bmax,
    float* __restrict__ gmax){
  int t = threadIdx.x;
  float m = blk_max(bmax[t]);
  if(t==0) gmax[0] = m;
}

__global__ __launch_bounds__(256) void kexp_k(const float* __restrict__ dd,
    const unsigned short* __restrict__ kn, const float* __restrict__ gmax,
    unsigned short* __restrict__ kp){
  int t = threadIdx.x;
  int rr = t>>4, lane = t&15;
  size_t R = (size_t)blockIdx.x*16 + rr;
  float ds = 0.f;
  {
    const unsigned short* s = kn + R*64 + lane*4;
    #pragma unroll
    for(int j=0;j<4;j++){ float x = bf2f(s[j]); ds += x*x; }
  }
  #pragma unroll
  for(int off=1;off<16;off<<=1) ds += __shfl_xor(ds,off);
  ds *= 0.5f;
  float g = gmax[0];
  const float* dr = dd + R*256;
  unsigned short* op = kp + R*256;
  #pragma unroll
  for(int j=0;j<4;j++){
    f32x4 v = *(const f32x4*)(dr + lane*4 + j*64);
    us4 u;
    #pragma unroll
    for(int i=0;i<4;i++) u[i] = f2bf(expf(v[i] - ds - g)*0.0625f + 1e-4f);
    *(us4*)(op + lane*4 + j*64) = u;
  }
}

// ---------------- quadratic causal attention --------------------------------
// o[l] = sum_{l'<=l} (qp[l].kp[l']) v[l'] / den[l]
__global__ __launch_bounds__(256) void attn_k(const unsigned short* __restrict__ qp,
    const unsigned short* __restrict__ kp, const unsigned short* __restrict__ vn,
    unsigned short* __restrict__ ob){
  int qt = blockIdx.x, bh = blockIdx.y;
  int b = bh>>3, hh = bh&7;
  __shared__ unsigned short qs[32*256];
  __shared__ unsigned short ks[32*256];
  __shared__ float vs[32][68];
  __shared__ float Ss[32][33];
  __shared__ float dens[2][32];
  int t = threadIdx.x;
  int w = t>>6, l = t&63;
  int qh = w>>1, kh = w&1;
  {
    int rr = t>>3, s0 = (t&7)*4;
    int gr = qt*32 + rr;
    const us8* src = (const us8*)(qp + ((size_t)bh*SEQL + (gr<SEQL?gr:0))*256 + s0*8);
    #pragma unroll
    for(int j=0;j<4;j++){
      us8 u = {};
      if(gr<SEQL) u = src[j];
      *(us8*)(qs + rr*256 + (((s0+j)^(rr&7))<<3)) = u;
    }
  }
  if(t<64) dens[t>>5][t&31] = 0.f;
  float o[8] = {0.f,0.f,0.f,0.f,0.f,0.f,0.f,0.f};
  int orow = t>>3, od = (t&7)*8;
  for(int kt=0; kt<=qt; kt++){
    __syncthreads();
    {
      int rr = t>>3, s0 = (t&7)*4;
      int gk = kt*32 + rr;
      const us8* src = (const us8*)(kp + ((size_t)bh*SEQL + (gk<SEQL?gk:0))*256 + s0*8);
      #pragma unroll
      for(int j=0;j<4;j++){
        us8 u = {};
        if(gk<SEQL) u = src[j];
        *(us8*)(ks + rr*256 + (((s0+j)^(rr&7))<<3)) = u;
      }
      const us8* vsrc = (const us8*)(vn + ((size_t)bh*SEQL + (gk<SEQL?gk:0))*64 + od);
      us8 uv = {};
      if(gk<SEQL) uv = vsrc[0];
      #pragma unroll
      for(int i=0;i<8;i++) vs[rr][od+i] = bf2f(uv[i]);
    }
    __syncthreads();
    // scores: each wave one 16x16 quadrant via MFMA
    f32x4 sacc = {};
    #pragma unroll
    for(int kk=0;kk<8;kk++){
      int ar = qh*16 + (l&15); int slot = kk*4 + (l>>4);
      short8 a = *(const short8*)(qs + ar*256 + ((slot^(ar&7))<<3));
      int br = kh*16 + (l&15);
      short8 bb2 = *(const short8*)(ks + br*256 + ((slot^(br&7))<<3));
      sacc = __builtin_amdgcn_mfma_f32_16x16x32_bf16(a, bb2, sacc, 0, 0, 0);
    }
    int scol = kh*16 + (l&15);
    int gcol = kt*32 + scol;
    float dp[4];
    #pragma unroll
    for(int i=0;i<4;i++){
      int sr = qh*16 + (l>>4)*4 + i;
      int grw = qt*32 + sr;
      float v2 = sacc[i];
      if(gcol > grw) v2 = 0.f;
      Ss[sr][scol] = v2;
      dp[i] = v2;
    }
    #pragma unroll
    for(int off=1;off<16;off<<=1)
      #pragma unroll
      for(int i=0;i<4;i++) dp[i] += __shfl_xor(dp[i], off);
    if((l&15)==0){
      #pragma unroll
      for(int i=0;i<4;i++) dens[kh][qh*16 + (l>>4)*4 + i] += dp[i];
    }
    __syncthreads();
    #pragma unroll
    for(int k2=0;k2<32;k2++){
      float s = Ss[orow][k2];
      #pragma unroll
      for(int j=0;j<8;j++) o[j] += s*vs[k2][od+j];
    }
  }
  __syncthreads();
  int gr = qt*32 + orow;
  if(gr < SEQL){
    float inv = 1.f/(dens[0][orow] + dens[1][orow]);
    us8 u;
    #pragma unroll
    for(int j=0;j<8;j++) u[j] = f2bf(o[j]*inv);
    *(us8*)(ob + ((size_t)(b*SEQL+gr))*DIMM + hh*64 + od) = u;
  }
}

// ---------------- loss ------------------------------------------------------
__global__ __launch_bounds__(256) void loss_k(const float* __restrict__ logits,
    const int* __restrict__ seq, float* __restrict__ rnll){
  int row = blockIdx.x; int t = threadIdx.x;
  const float* lr = logits + (size_t)row*VSZ;
  float m = -3.0e38f;
  for(int j=t;j<VSZ;j+=256) m = fmaxf(m, lr[j]);
  m = blk_max(m);
  float s = 0.f;
  for(int j=t;j<VSZ;j+=256) s += expf(lr[j]-m);
  s = blk_sum(s);
  if(t==0){
    int b = row/SEQL, l = row - b*SEQL;
    int tgt = seq[b*LSEQ + l + 1];
    rnll[row] = (m + logf(s)) - lr[tgt];
  }
}

__global__ __launch_bounds__(256) void fin_k(const float* __restrict__ rnll,
    float* __restrict__ out){
  int t = threadIdx.x;
  float s = 0.f;
  for(int i=t;i<NROWS;i+=256) s += rnll[i];
  s = blk_sum(s);
  if(t==0) out[0] = s/(float)NROWS;
}

// ---------------------------------------------------------------------------
extern "C" void kernel_launch(void* const* d_in, const int* in_sizes, int n_in,
                              void* d_out, int out_size, void* d_ws, size_t ws_size,
                              hipStream_t stream){
  (void)in_sizes; (void)n_in; (void)out_size; (void)ws_size;
  const float* x        = (const float*)d_in[0];
  const float* xn       = (const float*)d_in[1];
  const int*   iarr     = (const int*)  d_in[2];
  const float* conv1_w  = (const float*)d_in[3];
  const float* conv1_b  = (const float*)d_in[4];
  const float* conv2_w  = (const float*)d_in[5];
  const float* conv2_b  = (const float*)d_in[6];
  const float* codebook = (const float*)d_in[7];
  const float* proj     = (const float*)d_in[8];
  const float* tok_emb  = (const float*)d_in[9];
  const float* pos_emb  = (const float*)d_in[10];
  const float* ln1_g    = (const float*)d_in[11];
  const float* ln1_b    = (const float*)d_in[12];
  const float* wq       = (const float*)d_in[13];
  const float* wk       = (const float*)d_in[14];
  const float* wv       = (const float*)d_in[15];
  const float* wo       = (const float*)d_in[16];
  const float* bo       = (const float*)d_in[17];
  const float* ln2_g    = (const float*)d_in[18];
  const float* ln2_b    = (const float*)d_in[19];
  const float* ff1_w    = (const float*)d_in[20];
  const float* ff1_b    = (const float*)d_in[21];
  const float* ff2_w    = (const float*)d_in[22];
  const float* ff2_b    = (const float*)d_in[23];
  const float* lnf_g    = (const float*)d_in[24];
  const float* lnf_b    = (const float*)d_in[25];
  const float* logits_w = (const float*)d_in[26];
  const float* logits_b = (const float*)d_in[27];

  float* wsf = (float*)d_ws;
  size_t off = 0;
  float* ddraw = wsf + off; off += 4259840;            // 16640*256 f32
  unsigned short* qp_bf = (unsigned short*)(wsf + off); off += 2129920;
  unsigned short* kp_bf = (unsigned short*)(wsf + off); off += 2129920;
  float* h = wsf + off; off += 1064960;
  unsigned short* x1b = (unsigned short*)(wsf + off); off += 532480;
  unsigned short* qnb = (unsigned short*)(wsf + off); off += 532480;
  unsigned short* knb = (unsigned short*)(wsf + off); off += 532480;
  unsigned short* vnb = (unsigned short*)(wsf + off); off += 532480;
  unsigned short* ob  = (unsigned short*)(wsf + off); off += 532480;
  unsigned short* projb = (unsigned short*)(wsf + off); off += 49152;
  unsigned short* wbuf  = (unsigned short*)(wsf + off); off += 1572864;
  int* inds = (int*)(wsf + off); off += 2048;
  int* seq  = (int*)(wsf + off); off += 2112;
  float* bmax = wsf + off; off += 256;
  float* gmax = wsf + off; off += 64;
  float* rnll = wsf + off; off += 2112;

  // aliases into ddraw (dead regions at those times)
  float* c1 = ddraw;                    // 524288, dead after conv2
  float* c2 = ddraw + 524288;           // 131072, dead after vq
  unsigned short* ffmid = (unsigned short*)ddraw;       // 2080*2048 bf16
  float* logits = ddraw + 2129920;      // 2080*523 f32

  unsigned short* wqt  = wbuf;
  unsigned short* wkt  = wbuf + 262144;
  unsigned short* wvt  = wbuf + 524288;
  unsigned short* wot  = wbuf + 786432;
  unsigned short* ff1t = wbuf + 1048576;
  unsigned short* ff2t = wbuf + 2097152;
  unsigned short* logt = wbuf;          // after layers

  conv1_k<<<2048,256,0,stream>>>(x, xn, conv1_w, conv1_b, c1);
  conv2_k<<<512,256,0,stream>>>(c1, conv2_w, conv2_b, c2);
  vq_k<<<2048,256,0,stream>>>(c2, codebook, inds);
  seq_k<<<(16*LSEQ+255)/256,256,0,stream>>>(iarr, inds, seq);
  embed_k<<<(NROWS*DIMM)/256,256,0,stream>>>(seq, tok_emb, pos_emb, h);
  projcv_k<<<384,256,0,stream>>>(proj, projb);

  for(int l=0;l<6;l++){
    PtrPack pk{ wq + (size_t)l*262144, wk + (size_t)l*262144,
                wv + (size_t)l*262144, wo + (size_t)l*262144 };
    wconv4_k<<<dim3(16,16,4),256,0,stream>>>(pk, wqt);
    wconv_k<<<dim3(64,16),256,0,stream>>>(ff1_w + (size_t)l*1048576, ff1t, 512, 2048);
    wconv_k<<<dim3(16,64),256,0,stream>>>(ff2_w + (size_t)l*1048576, ff2t, 2048, 512);

    ln_k<<<NROWS,256,0,stream>>>(h, ln1_g+l*DIMM, ln1_b+l*DIMM, x1b);
    mgemm_k<1><<<dim3(8,33),256,0,stream>>>(x1b, wqt, nullptr, nullptr, qnb, NROWS, DIMM, DIMM, 0.35355339059327378f);
    mgemm_k<1><<<dim3(8,33),256,0,stream>>>(x1b, wkt, nullptr, nullptr, knb, NROWS, DIMM, DIMM, 0.35355339059327378f);
    mgemm_k<1><<<dim3(8,33),256,0,stream>>>(x1b, wvt, nullptr, nullptr, vnb, NROWS, DIMM, DIMM, 1.0f);
    // dd = dn @ proj^T   (proj already [256][64] = Bt layout)
    mgemm_k<0><<<dim3(4,260),256,0,stream>>>(qnb, projb + l*16384, nullptr, ddraw, nullptr, NBHL, MF, 64, 1.0f);
    qexp_k<<<1040,256,0,stream>>>(ddraw, qnb, qp_bf);
    mgemm_k<0><<<dim3(4,260),256,0,stream>>>(knb, projb + l*16384, nullptr, ddraw, nullptr, NBHL, MF, 64, 1.0f);
    kmax_k<<<256,256,0,stream>>>(ddraw, bmax);
    gmax_k<<<1,256,0,stream>>>(bmax, gmax);
    kexp_k<<<1040,256,0,stream>>>(ddraw, knb, gmax, kp_bf);
    attn_k<<<dim3(5,NBH),256,0,stream>>>(qp_bf, kp_bf, vnb, ob);
    mgemm_k<3><<<dim3(8,33),256,0,stream>>>(ob, wot, bo+l*DIMM, h, nullptr, NROWS, DIMM, DIMM, 1.0f);
    ln_k<<<NROWS,256,0,stream>>>(h, ln2_g+l*DIMM, ln2_b+l*DIMM, x1b);
    mgemm_k<4><<<dim3(32,33),256,0,stream>>>(x1b, ff1t, ff1_b+l*2048, nullptr, ffmid, NROWS, 2048, DIMM, 1.0f);
    mgemm_k<3><<<dim3(8,33),256,0,stream>>>(ffmid, ff2t, ff2_b+l*DIMM, h, nullptr, NROWS, DIMM, 2048, 1.0f);
  }

  ln_k<<<NROWS,256,0,stream>>>(h, lnf_g, lnf_b, x1b);
  wconv_k<<<dim3(17,16),256,0,stream>>>(logits_w, logt, 512, 523);
  mgemm_k<0><<<dim3(9,33),256,0,stream>>>(x1b, logt, logits_b, logits, nullptr, NROWS, VSZ, DIMM, 1.0f);
  loss_k<<<NROWS,256,0,stream>>>(logits, seq, rnll);
  fin_k<<<1,256,0,stream>>>(rnll, (float*)d_out);
}

// Round 3
// 852.069 us; speedup vs baseline: 7.1164x; 1.4409x over previous
//
#include <hip/hip_runtime.h>

#define SEQL 130
#define LSEQ 131
#define DIMM 512
#define NHEADS 8
#define MF 256
#define VSZ 523
#define NROWS (16*SEQL)          // 2080
#define NBH (16*NHEADS)          // 128
#define NBHL (NBH*SEQL)          // 16640
#define QSEG 1064960             // us elements per q/k/v segment

typedef __attribute__((ext_vector_type(8))) short short8;
typedef __attribute__((ext_vector_type(8))) unsigned short us8;
typedef __attribute__((ext_vector_type(4))) unsigned short us4;
typedef __attribute__((ext_vector_type(4))) float f32x4;

__device__ __forceinline__ unsigned short f2bf(float f){
  unsigned int u = __float_as_uint(f);
  u += 0x7fffu + ((u>>16)&1u);
  return (unsigned short)(u>>16);
}
__device__ __forceinline__ float bf2f(unsigned short h){
  return __uint_as_float(((unsigned int)h)<<16);
}
__device__ __forceinline__ float gelu_f(float x){
  float x3 = x*x*x;
  return 0.5f*x*(1.f+tanhf(0.7978845608028654f*(x+0.044715f*x3)));
}
__device__ __forceinline__ unsigned enc_max(float f){
  unsigned u = __float_as_uint(f);
  return (u & 0x80000000u) ? ~u : (u | 0x80000000u);
}
__device__ __forceinline__ float dec_max(unsigned k){
  unsigned u = (k>>31) ? (k & 0x7fffffffu) : ~k;
  return __uint_as_float(u);
}
__device__ __forceinline__ float blk_sum(float v){
  #pragma unroll
  for(int off=32;off;off>>=1) v += __shfl_xor(v,off);
  __shared__ float tmp_s[4];
  int t=threadIdx.x;
  if((t&63)==0) tmp_s[t>>6]=v;
  __syncthreads();
  v = tmp_s[0]+tmp_s[1]+tmp_s[2]+tmp_s[3];
  __syncthreads();
  return v;
}
__device__ __forceinline__ float blk_max(float v){
  #pragma unroll
  for(int off=32;off;off>>=1) v = fmaxf(v,__shfl_xor(v,off));
  __shared__ float tmp_m[4];
  int t=threadIdx.x;
  if((t&63)==0) tmp_m[t>>6]=v;
  __syncthreads();
  v = fmaxf(fmaxf(tmp_m[0],tmp_m[1]),fmaxf(tmp_m[2],tmp_m[3]));
  __syncthreads();
  return v;
}

// ---------------- conv1: (32,1,16,16,16) -> relu (32,32,8,8,8), stride2 pad1
__global__ __launch_bounds__(256) void conv1_k(const float* __restrict__ x,
    const float* __restrict__ xn, const float* __restrict__ w,
    const float* __restrict__ bias, float* __restrict__ out){
  int idx = blockIdx.x*256 + threadIdx.x;
  if(idx >= 32*32*8*8*8) return;
  int ow = idx & 7, oh = (idx>>3)&7, od = (idx>>6)&7, oc = (idx>>9)&31, n = idx>>14;
  const float* xp = (n<16) ? (x + n*4096) : (xn + (n-16)*4096);
  const float* wp = w + oc*64;
  float acc = bias[oc];
  #pragma unroll
  for(int kd=0;kd<4;kd++){ int id = od*2-1+kd; if((unsigned)id>=16u) continue;
    #pragma unroll
    for(int kh=0;kh<4;kh++){ int ih = oh*2-1+kh; if((unsigned)ih>=16u) continue;
      #pragma unroll
      for(int kw=0;kw<4;kw++){ int iw = ow*2-1+kw; if((unsigned)iw>=16u) continue;
        acc += xp[(id*16+ih)*16+iw]*wp[(kd*4+kh)*4+kw];
      }}}
  out[idx] = fmaxf(acc,0.f);
}

// ---------------- conv2 (LDS-staged, padded, vectorized) --------------------
// grid (4 od, 32 n); out layout (n, oc, od, oh, ow)
__global__ __launch_bounds__(256) void conv2_k(const float* __restrict__ c1,
    const float* __restrict__ w, const float* __restrict__ bias,
    float* __restrict__ out){
  __shared__ float in_s[32][4][120];   // [ic][kd][(ih+1)*12 + (iw+1)], 60KB
  int od = blockIdx.x, n = blockIdx.y;
  int t = threadIdx.x;
  // zero-init
  float4* zf = (float4*)&in_s[0][0][0];
  #pragma unroll
  for(int j=0;j<15;j++) zf[t + 256*j] = make_float4(0.f,0.f,0.f,0.f);
  __syncthreads();
  // load valid planes
  #pragma unroll
  for(int j=0;j<4;j++){
    int ridx = t + 256*j;            // 0..1023 : ic(5b) kd(2b) ih(3b)
    int ic = ridx>>5, rem = ridx&31;
    int kd = rem>>3, ih = rem&7;
    int id = od*2 - 1 + kd;
    if((unsigned)id < 8u){
      const float* src = c1 + (size_t)(n*32+ic)*512 + id*64 + ih*8;
      float4 a = *(const float4*)src;
      float4 b = *(const float4*)(src+4);
      float* dst = &in_s[ic][kd][(ih+1)*12 + 1];
      dst[0]=a.x; dst[1]=a.y; dst[2]=a.z; dst[3]=a.w;
      dst[4]=b.x; dst[5]=b.y; dst[6]=b.z; dst[7]=b.w;
    }
  }
  __syncthreads();
  int oc = t>>2, oh = t&3;
  float acc0=bias[oc], acc1=acc0, acc2=acc0, acc3=acc0;
  for(int ic=0; ic<32; ic++){
    #pragma unroll
    for(int kd=0;kd<4;kd++){
      #pragma unroll
      for(int kh=0;kh<4;kh++){
        const float* rp = &in_s[ic][kd][(oh*2+kh)*12];
        f32x4 f0 = *(const f32x4*)rp;
        f32x4 f1 = *(const f32x4*)(rp+4);
        f32x4 f2 = *(const f32x4*)(rp+8);
        f32x4 wv = *(const f32x4*)(w + ((size_t)(oc*32+ic)*64 + (kd*4+kh)*4));
        float in0=f0[0],in1=f0[1],in2=f0[2],in3=f0[3];
        float in4=f1[0],in5=f1[1],in6=f1[2],in7=f1[3];
        float in8=f2[0],in9=f2[1];
        acc0 += wv[0]*in0 + wv[1]*in1 + wv[2]*in2 + wv[3]*in3;
        acc1 += wv[0]*in2 + wv[1]*in3 + wv[2]*in4 + wv[3]*in5;
        acc2 += wv[0]*in4 + wv[1]*in5 + wv[2]*in6 + wv[3]*in7;
        acc3 += wv[0]*in6 + wv[1]*in7 + wv[2]*in8 + wv[3]*in9;
      }
    }
  }
  float4 res = make_float4(acc0,acc1,acc2,acc3);
  *(float4*)(out + (size_t)(n*64+oc)*64 + od*16 + oh*4) = res;
}

// ---------------- VQ argmin ------------------------------------------------
__global__ __launch_bounds__(256) void vq_k(const float* __restrict__ c2,
    const float* __restrict__ cb, int* __restrict__ inds){
  int nf = blockIdx.x;               // 0..2047
  int nb = nf>>6, sp = nf&63;
  __shared__ float z[64];
  int t = threadIdx.x;
  if(t<64) z[t] = c2[(nb*64+t)*64 + sp];
  __syncthreads();
  float best = 3.0e38f; int bi = 0;
  for(int j=t; j<512; j+=256){
    const float* cr = cb + j*64;
    float dot=0.f, nn=0.f;
    #pragma unroll 8
    for(int d=0;d<64;d++){ float cv=cr[d]; dot += z[d]*cv; nn += cv*cv; }
    float dist = nn - 2.f*dot;
    if(dist < best){ best=dist; bi=j; }
  }
  #pragma unroll
  for(int off=32;off;off>>=1){
    float ob = __shfl_down(best,off); int oi = __shfl_down(bi,off);
    if(ob<best || (ob==best && oi<bi)){ best=ob; bi=oi; }
  }
  __shared__ float rb[4]; __shared__ int ri[4];
  if((t&63)==0){ rb[t>>6]=best; ri[t>>6]=bi; }
  __syncthreads();
  if(t==0){
    for(int wv=1;wv<4;wv++){ if(rb[wv]<best || (rb[wv]==best && ri[wv]<bi)){ best=rb[wv]; bi=ri[wv]; } }
    inds[nf]=bi;
  }
}

__global__ void seq_k(const int* __restrict__ iarr, const int* __restrict__ inds,
                      int* __restrict__ seq){
  int idx = blockIdx.x*256 + threadIdx.x;
  if(idx >= 16*LSEQ) return;
  int b = idx/LSEQ, p = idx%LSEQ;
  int v;
  if(p<3)       v = iarr[b*3+p];
  else if(p<67) v = inds[(16+b)*64 + (p-3)];
  else          v = inds[b*64 + (p-67)];
  seq[idx] = v;
}

__global__ __launch_bounds__(256) void embed_k(const int* __restrict__ seq,
    const float* __restrict__ tok, const float* __restrict__ pos,
    float* __restrict__ h){
  int idx = blockIdx.x*256 + threadIdx.x;
  int c = idx & 511; int row = idx >> 9;
  int b = row/SEQL, l = row - b*SEQL;
  int tk = seq[b*LSEQ + l];
  h[idx] = tok[tk*DIMM + c] + pos[l*DIMM + c];
}

// ---------------- layernorm: f32 in, bf16 out -------------------------------
__global__ __launch_bounds__(256) void ln_k(const float* __restrict__ in,
    const float* __restrict__ g, const float* __restrict__ bb,
    unsigned short* __restrict__ out){
  int row = blockIdx.x; int t = threadIdx.x;
  const float* xr = in + (size_t)row*DIMM;
  float x0 = xr[t], x1 = xr[t+256];
  float s = x0+x1, ss = x0*x0 + x1*x1;
  #pragma unroll
  for(int off=32;off;off>>=1){ s += __shfl_xor(s,off); ss += __shfl_xor(ss,off); }
  __shared__ float bs[4], bss[4];
  if((t&63)==0){ bs[t>>6]=s; bss[t>>6]=ss; }
  __syncthreads();
  s = bs[0]+bs[1]+bs[2]+bs[3]; ss = bss[0]+bss[1]+bss[2]+bss[3];
  float mu = s*(1.f/512.f);
  float var = ss*(1.f/512.f) - mu*mu;
  float inv = rsqrtf(var + 1e-5f);
  out[(size_t)row*DIMM+t]     = f2bf((x0-mu)*inv*g[t]     + bb[t]);
  out[(size_t)row*DIMM+t+256] = f2bf((x1-mu)*inv*g[t+256] + bb[t+256]);
}

// ---------------- per-layer weight prep (transpose + bf16) ------------------
// blocks: [0,768) wqkv -> wqkvt[1536][512]; [768,1024) wo -> wot[512][512];
// [1024,2048) ff1 [512][2048] -> ff1t[2048][512]; [2048,3072) ff2 [2048][512] -> ff2t[512][2048]
__global__ __launch_bounds__(256) void wprep_k(const float* __restrict__ wq_l,
    const float* __restrict__ wk_l, const float* __restrict__ wv_l,
    const float* __restrict__ wo_l, const float* __restrict__ ff1_l,
    const float* __restrict__ ff2_l,
    unsigned short* __restrict__ wqkvt, unsigned short* __restrict__ wot,
    unsigned short* __restrict__ ff1t, unsigned short* __restrict__ ff2t,
    unsigned int* __restrict__ gmaxbits){
  int bid = blockIdx.x;
  int t = threadIdx.x;
  if(bid==0 && t==0) gmaxbits[0] = 0u;
  const float* src; unsigned short* dst;
  int n0, k0, srcN, dstK;
  if(bid < 768){
    int nt = bid % 48, kt = bid / 48;
    n0 = nt*32; k0 = kt*32;
    int seg = n0 >> 9;
    src = (seg==0 ? wq_l : seg==1 ? wk_l : wv_l);
    dst = wqkvt; srcN = 512; dstK = 512;
    // src column offset within segment
    n0 &= 0x1ff; n0 |= (seg<<9);   // keep global n for dst; src col = n0&511 handled below
  } else if(bid < 1024){
    int b2 = bid-768; int nt = b2 % 16, kt = b2 / 16;
    n0 = nt*32; k0 = kt*32; src = wo_l; dst = wot; srcN = 512; dstK = 512;
  } else if(bid < 2048){
    int b2 = bid-1024; int nt = b2 % 64, kt = b2 / 64;
    n0 = nt*32; k0 = kt*32; src = ff1_l; dst = ff1t; srcN = 2048; dstK = 512;
  } else {
    int b2 = bid-2048; int nt = b2 % 16, kt = b2 / 16;
    n0 = nt*32; k0 = kt*32; src = ff2_l; dst = ff2t; srcN = 512; dstK = 2048;
  }
  int srcCol0 = (bid < 768) ? (n0 & 0x1ff) : n0;
  __shared__ float tile[32][33];
  int c = t&31, r = t>>5;
  #pragma unroll
  for(int j=0;j<4;j++)
    tile[r+8*j][c] = src[(size_t)(k0+r+8*j)*srcN + srcCol0 + c];
  __syncthreads();
  #pragma unroll
  for(int j=0;j<4;j++){
    int n = n0 + r + 8*j;
    dst[(size_t)n*dstK + k0 + c] = f2bf(tile[c][r+8*j]);
  }
}

// generic transpose for logits weight [512][523] -> [523][512]
__global__ __launch_bounds__(256) void wconv_k(const float* __restrict__ W,
    unsigned short* __restrict__ dst, int K, int N){
  __shared__ float tile[32][33];
  int k0 = blockIdx.y*32, n0 = blockIdx.x*32;
  int t = threadIdx.x; int c = t&31, r = t>>5;
  #pragma unroll
  for(int j=0;j<4;j++){
    int n = n0+c;
    tile[r+8*j][c] = (n<N) ? W[(size_t)(k0+r+8*j)*N + n] : 0.f;
  }
  __syncthreads();
  #pragma unroll
  for(int j=0;j<4;j++){
    int n = n0 + r + 8*j;
    if(n<N) dst[(size_t)n*K + k0 + c] = f2bf(tile[c][r+8*j]);
  }
}

__global__ __launch_bounds__(256) void projcv_k(const float* __restrict__ proj,
    unsigned short* __restrict__ pb){
  int i = blockIdx.x*256 + threadIdx.x;
  if(i < 6*MF*64) pb[i] = f2bf(proj[i]);
}

// ---------------- MFMA GEMM: C[M,N] = A[M,K](bf16) @ Bt[N,K](bf16)^T --------
// MODE 0: f32 out (+optional bias)
// MODE 1: bf16 out to fused qkv buffer (head-major per segment)
// MODE 3: f32 accumulate += (bias)
// MODE 4: bf16 out, bias+gelu
template<int MODE>
__global__ __launch_bounds__(256) void mgemm_k(const unsigned short* __restrict__ A,
    const unsigned short* __restrict__ Bt, const float* __restrict__ bias,
    float* __restrict__ Cf, unsigned short* __restrict__ Cb,
    int M, int N, int K){
  __shared__ unsigned short As[4096];
  __shared__ unsigned short Bs[4096];
  int t = threadIdx.x;
  const int m0 = blockIdx.y*64, n0 = blockIdx.x*64;
  int w = t>>6, l = t&63;
  int wr = w>>1, wc = w&1;
  f32x4 acc[2][2] = {};
  int srow = t>>2, sp = (t&3)*2;
  int arow = m0 + srow, brow = n0 + srow;
  bool aok = arow < M, bok = brow < N;
  const us8* Ap = (const us8*)(A + (size_t)arow*K + sp*8);
  const us8* Bp = (const us8*)(Bt + (size_t)brow*K + sp*8);
  unsigned short* Aw0 = As + srow*64 + (((sp  )^(srow&7))<<3);
  unsigned short* Aw1 = As + srow*64 + (((sp+1)^(srow&7))<<3);
  unsigned short* Bw0 = Bs + srow*64 + (((sp  )^(srow&7))<<3);
  unsigned short* Bw1 = Bs + srow*64 + (((sp+1)^(srow&7))<<3);
  for(int k0=0; k0<K; k0+=64){
    us8 a0={}, a1={}, b0={}, b1={};
    if(aok){ a0 = Ap[0]; a1 = Ap[1]; }
    if(bok){ b0 = Bp[0]; b1 = Bp[1]; }
    Ap += 8; Bp += 8;
    __syncthreads();
    *(us8*)Aw0 = a0; *(us8*)Aw1 = a1;
    *(us8*)Bw0 = b0; *(us8*)Bw1 = b1;
    __syncthreads();
    #pragma unroll
    for(int kk=0;kk<2;kk++){
      short8 af[2], bf[2];
      #pragma unroll
      for(int m=0;m<2;m++){
        int row = wr*32 + m*16 + (l&15);
        int slot = kk*4 + (l>>4);
        af[m] = *(const short8*)(As + row*64 + ((slot^(row&7))<<3));
      }
      #pragma unroll
      for(int n=0;n<2;n++){
        int col = wc*32 + n*16 + (l&15);
        int slot = kk*4 + (l>>4);
        bf[n] = *(const short8*)(Bs + col*64 + ((slot^(col&7))<<3));
      }
      #pragma unroll
      for(int m=0;m<2;m++)
        #pragma unroll
        for(int n=0;n<2;n++)
          acc[m][n] = __builtin_amdgcn_mfma_f32_16x16x32_bf16(af[m], bf[n], acc[m][n], 0, 0, 0);
    }
  }
  #pragma unroll
  for(int m=0;m<2;m++){
    #pragma unroll
    for(int n=0;n<2;n++){
      int col = n0 + wc*32 + n*16 + (l&15);
      #pragma unroll
      for(int i=0;i<4;i++){
        int row = m0 + wr*32 + m*16 + (l>>4)*4 + i;
        if(row < M && col < N){
          float v = acc[m][n][i];
          if(MODE==0){
            if(bias) v += bias[col];
            Cf[(size_t)row*N+col] = v;
          } else if(MODE==1){
            v *= (col < 1024) ? 0.35355339059327378f : 1.0f;
            int seg = col>>9, d0 = col&511;
            int hh = d0>>6, d = d0&63;
            int bb = row/SEQL, ll = row - bb*SEQL;
            Cb[(size_t)seg*QSEG + (((size_t)(bb*NHEADS+hh))*SEQL + ll)*64 + d] = f2bf(v);
          } else if(MODE==3){
            v += bias[col];
            Cf[(size_t)row*N+col] += v;
          } else {
            v += bias[col];
            v = gelu_f(v);
            Cb[(size_t)row*N+col] = f2bf(v);
          }
        }
      }
    }
  }
}

// ---------------- fused feature-map kernels ---------------------------------
// featA: z=0 -> q-side: dd, per-row max, exp, write qp
//        z=1 -> k-side: dd, block max, atomicMax into gmaxbits
__global__ __launch_bounds__(256) void featA_k(const unsigned short* __restrict__ qn,
    const unsigned short* __restrict__ kn, const unsigned short* __restrict__ projl,
    unsigned short* __restrict__ qp, unsigned int* __restrict__ gmaxbits){
  int z = blockIdx.y;
  const unsigned short* dn = z ? kn : qn;
  __shared__ float uni[32*264];                  // dd buffer; low 32KB doubles as proj stage
  __shared__ unsigned short dns[2048];
  unsigned short* ps = (unsigned short*)uni;
  int t = threadIdx.x;
  size_t R0 = (size_t)blockIdx.x*32;
  {
    int row = t>>3, sl = t&7;
    us8 u = *(const us8*)(dn + (R0+row)*64 + sl*8);
    *(us8*)(dns + row*64 + ((sl^(row&7))<<3)) = u;
  }
  #pragma unroll
  for(int j=0;j<8;j++){
    int ridx = t + 256*j;
    int row = ridx>>3, sl = ridx&7;
    us8 u = *(const us8*)(projl + row*64 + sl*8);
    *(us8*)(ps + row*64 + ((sl^(row&7))<<3)) = u;
  }
  __syncthreads();
  int w = t>>6, l = t&63;
  int rt = w&1, cb = (w>>1)*8;
  f32x4 acc[8] = {};
  #pragma unroll
  for(int kk=0;kk<2;kk++){
    int ar = rt*16 + (l&15);
    int slot = kk*4 + (l>>4);
    short8 a = *(const short8*)(dns + ar*64 + ((slot^(ar&7))<<3));
    #pragma unroll
    for(int ct=0;ct<8;ct++){
      int br = (cb+ct)*16 + (l&15);
      short8 b = *(const short8*)(ps + br*64 + ((slot^(br&7))<<3));
      acc[ct] = __builtin_amdgcn_mfma_f32_16x16x32_bf16(a, b, acc[ct], 0, 0, 0);
    }
  }
  __syncthreads();
  #pragma unroll
  for(int ct=0;ct<8;ct++){
    int col = (cb+ct)*16 + (l&15);
    #pragma unroll
    for(int i=0;i<4;i++){
      int row = rt*16 + (l>>4)*4 + i;
      uni[row*264 + col] = acc[ct][i];
    }
  }
  __syncthreads();
  int r = t>>3, sub = t&7;
  float* rowp = uni + r*264 + sub*32;
  f32x4 v[8];
  #pragma unroll
  for(int jj=0;jj<8;jj++) v[jj] = *(const f32x4*)(rowp + jj*4);
  float m = -3.0e38f;
  #pragma unroll
  for(int jj=0;jj<8;jj++)
    #pragma unroll
    for(int i=0;i<4;i++) m = fmaxf(m, v[jj][i]);
  m = fmaxf(m, __shfl_xor(m,1));
  m = fmaxf(m, __shfl_xor(m,2));
  m = fmaxf(m, __shfl_xor(m,4));       // per-row max
  if(z==0){
    us8 dvu = *(const us8*)(dns + r*64 + ((sub^(r&7))<<3));
    float s2 = 0.f;
    #pragma unroll
    for(int j=0;j<8;j++){ float xx = bf2f(dvu[j]); s2 += xx*xx; }
    s2 += __shfl_xor(s2,1); s2 += __shfl_xor(s2,2); s2 += __shfl_xor(s2,4);
    float ds = 0.5f*s2;
    unsigned short* op = qp + (R0+r)*256 + sub*32;
    #pragma unroll
    for(int jj=0;jj<8;jj++){
      us4 u4;
      #pragma unroll
      for(int i=0;i<4;i++) u4[i] = f2bf(expf(v[jj][i] - ds - m)*0.0625f + 1e-4f);
      *(us4*)(op + jj*4) = u4;
    }
  } else {
    float bm = m;
    bm = fmaxf(bm, __shfl_xor(bm,8));
    bm = fmaxf(bm, __shfl_xor(bm,16));
    bm = fmaxf(bm, __shfl_xor(bm,32));
    __shared__ float wm[4];
    if(l==0) wm[w] = bm;
    __syncthreads();
    if(t==0){
      float g = fmaxf(fmaxf(wm[0],wm[1]),fmaxf(wm[2],wm[3]));
      atomicMax(gmaxbits, enc_max(g));
    }
  }
}

// featB: k-side recompute dd + exp with global max
__global__ __launch_bounds__(256) void featB_k(const unsigned short* __restrict__ kn,
    const unsigned short* __restrict__ projl, const unsigned int* __restrict__ gmaxbits,
    unsigned short* __restrict__ kp){
  __shared__ float uni[32*264];
  __shared__ unsigned short dns[2048];
  unsigned short* ps = (unsigned short*)uni;
  int t = threadIdx.x;
  size_t R0 = (size_t)blockIdx.x*32;
  {
    int row = t>>3, sl = t&7;
    us8 u = *(const us8*)(kn + (R0+row)*64 + sl*8);
    *(us8*)(dns + row*64 + ((sl^(row&7))<<3)) = u;
  }
  #pragma unroll
  for(int j=0;j<8;j++){
    int ridx = t + 256*j;
    int row = ridx>>3, sl = ridx&7;
    us8 u = *(const us8*)(projl + row*64 + sl*8);
    *(us8*)(ps + row*64 + ((sl^(row&7))<<3)) = u;
  }
  __syncthreads();
  int w = t>>6, l = t&63;
  int rt = w&1, cb = (w>>1)*8;
  f32x4 acc[8] = {};
  #pragma unroll
  for(int kk=0;kk<2;kk++){
    int ar = rt*16 + (l&15);
    int slot = kk*4 + (l>>4);
    short8 a = *(const short8*)(dns + ar*64 + ((slot^(ar&7))<<3));
    #pragma unroll
    for(int ct=0;ct<8;ct++){
      int br = (cb+ct)*16 + (l&15);
      short8 b = *(const short8*)(ps + br*64 + ((slot^(br&7))<<3));
      acc[ct] = __builtin_amdgcn_mfma_f32_16x16x32_bf16(a, b, acc[ct], 0, 0, 0);
    }
  }
  __syncthreads();
  #pragma unroll
  for(int ct=0;ct<8;ct++){
    int col = (cb+ct)*16 + (l&15);
    #pragma unroll
    for(int i=0;i<4;i++){
      int row = rt*16 + (l>>4)*4 + i;
      uni[row*264 + col] = acc[ct][i];
    }
  }
  __syncthreads();
  float g = dec_max(gmaxbits[0]);
  int r = t>>3, sub = t&7;
  us8 dvu = *(const us8*)(dns + r*64 + ((sub^(r&7))<<3));
  float s2 = 0.f;
  #pragma unroll
  for(int j=0;j<8;j++){ float xx = bf2f(dvu[j]); s2 += xx*xx; }
  s2 += __shfl_xor(s2,1); s2 += __shfl_xor(s2,2); s2 += __shfl_xor(s2,4);
  float ds = 0.5f*s2;
  float* rowp = uni + r*264 + sub*32;
  unsigned short* op = kp + (R0+r)*256 + sub*32;
  #pragma unroll
  for(int jj=0;jj<8;jj++){
    f32x4 v = *(const f32x4*)(rowp + jj*4);
    us4 u4;
    #pragma unroll
    for(int i=0;i<4;i++) u4[i] = f2bf(expf(v[i] - ds - g)*0.0625f + 1e-4f);
    *(us4*)(op + jj*4) = u4;
  }
}

// ---------------- quadratic causal attention --------------------------------
__global__ __launch_bounds__(256) void attn_k(const unsigned short* __restrict__ qp,
    const unsigned short* __restrict__ kp, const unsigned short* __restrict__ vn,
    unsigned short* __restrict__ ob){
  int qt = blockIdx.x, bh = blockIdx.y;
  int b = bh>>3, hh = bh&7;
  __shared__ unsigned short qs[32*256];
  __shared__ unsigned short ks[32*256];
  __shared__ float vs[32][68];
  __shared__ float Ss[32][33];
  __shared__ float dens[2][32];
  int t = threadIdx.x;
  int w = t>>6, l = t&63;
  int qh = w>>1, kh = w&1;
  {
    int rr = t>>3, s0 = (t&7)*4;
    int gr = qt*32 + rr;
    const us8* src = (const us8*)(qp + ((size_t)bh*SEQL + (gr<SEQL?gr:0))*256 + s0*8);
    #pragma unroll
    for(int j=0;j<4;j++){
      us8 u = {};
      if(gr<SEQL) u = src[j];
      *(us8*)(qs + rr*256 + (((s0+j)^(rr&7))<<3)) = u;
    }
  }
  if(t<64) dens[t>>5][t&31] = 0.f;
  float o[8] = {0.f,0.f,0.f,0.f,0.f,0.f,0.f,0.f};
  int orow = t>>3, od = (t&7)*8;
  for(int kt=0; kt<=qt; kt++){
    __syncthreads();
    {
      int rr = t>>3, s0 = (t&7)*4;
      int gk = kt*32 + rr;
      const us8* src = (const us8*)(kp + ((size_t)bh*SEQL + (gk<SEQL?gk:0))*256 + s0*8);
      #pragma unroll
      for(int j=0;j<4;j++){
        us8 u = {};
        if(gk<SEQL) u = src[j];
        *(us8*)(ks + rr*256 + (((s0+j)^(rr&7))<<3)) = u;
      }
      const us8* vsrc = (const us8*)(vn + ((size_t)bh*SEQL + (gk<SEQL?gk:0))*64 + od);
      us8 uv = {};
      if(gk<SEQL) uv = vsrc[0];
      #pragma unroll
      for(int i=0;i<8;i++) vs[rr][od+i] = bf2f(uv[i]);
    }
    __syncthreads();
    f32x4 sacc = {};
    #pragma unroll
    for(int kk=0;kk<8;kk++){
      int ar = qh*16 + (l&15); int slot = kk*4 + (l>>4);
      short8 a = *(const short8*)(qs + ar*256 + ((slot^(ar&7))<<3));
      int br = kh*16 + (l&15);
      short8 bb2 = *(const short8*)(ks + br*256 + ((slot^(br&7))<<3));
      sacc = __builtin_amdgcn_mfma_f32_16x16x32_bf16(a, bb2, sacc, 0, 0, 0);
    }
    int scol = kh*16 + (l&15);
    int gcol = kt*32 + scol;
    float dp[4];
    #pragma unroll
    for(int i=0;i<4;i++){
      int sr = qh*16 + (l>>4)*4 + i;
      int grw = qt*32 + sr;
      float v2 = sacc[i];
      if(gcol > grw) v2 = 0.f;
      Ss[sr][scol] = v2;
      dp[i] = v2;
    }
    #pragma unroll
    for(int off=1;off<16;off<<=1)
      #pragma unroll
      for(int i=0;i<4;i++) dp[i] += __shfl_xor(dp[i], off);
    if((l&15)==0){
      #pragma unroll
      for(int i=0;i<4;i++) dens[kh][qh*16 + (l>>4)*4 + i] += dp[i];
    }
    __syncthreads();
    #pragma unroll
    for(int k2=0;k2<32;k2++){
      float s = Ss[orow][k2];
      #pragma unroll
      for(int j=0;j<8;j++) o[j] += s*vs[k2][od+j];
    }
  }
  __syncthreads();
  int gr = qt*32 + orow;
  if(gr < SEQL){
    float inv = 1.f/(dens[0][orow] + dens[1][orow]);
    us8 u;
    #pragma unroll
    for(int j=0;j<8;j++) u[j] = f2bf(o[j]*inv);
    *(us8*)(ob + ((size_t)(b*SEQL+gr))*DIMM + hh*64 + od) = u;
  }
}

// ---------------- loss ------------------------------------------------------
__global__ __launch_bounds__(256) void loss_k(const float* __restrict__ logits,
    const int* __restrict__ seq, float* __restrict__ rnll){
  int row = blockIdx.x; int t = threadIdx.x;
  const float* lr = logits + (size_t)row*VSZ;
  float m = -3.0e38f;
  for(int j=t;j<VSZ;j+=256) m = fmaxf(m, lr[j]);
  m = blk_max(m);
  float s = 0.f;
  for(int j=t;j<VSZ;j+=256) s += expf(lr[j]-m);
  s = blk_sum(s);
  if(t==0){
    int b = row/SEQL, l = row - b*SEQL;
    int tgt = seq[b*LSEQ + l + 1];
    rnll[row] = (m + logf(s)) - lr[tgt];
  }
}

__global__ __launch_bounds__(256) void fin_k(const float* __restrict__ rnll,
    float* __restrict__ out){
  int t = threadIdx.x;
  float s = 0.f;
  for(int i=t;i<NROWS;i+=256) s += rnll[i];
  s = blk_sum(s);
  if(t==0) out[0] = s/(float)NROWS;
}

// ---------------------------------------------------------------------------
extern "C" void kernel_launch(void* const* d_in, const int* in_sizes, int n_in,
                              void* d_out, int out_size, void* d_ws, size_t ws_size,
                              hipStream_t stream){
  (void)in_sizes; (void)n_in; (void)out_size; (void)ws_size;
  const float* x        = (const float*)d_in[0];
  const float* xn       = (const float*)d_in[1];
  const int*   iarr     = (const int*)  d_in[2];
  const float* conv1_w  = (const float*)d_in[3];
  const float* conv1_b  = (const float*)d_in[4];
  const float* conv2_w  = (const float*)d_in[5];
  const float* conv2_b  = (const float*)d_in[6];
  const float* codebook = (const float*)d_in[7];
  const float* proj     = (const float*)d_in[8];
  const float* tok_emb  = (const float*)d_in[9];
  const float* pos_emb  = (const float*)d_in[10];
  const float* ln1_g    = (const float*)d_in[11];
  const float* ln1_b    = (const float*)d_in[12];
  const float* wq       = (const float*)d_in[13];
  const float* wk       = (const float*)d_in[14];
  const float* wv       = (const float*)d_in[15];
  const float* wo       = (const float*)d_in[16];
  const float* bo       = (const float*)d_in[17];
  const float* ln2_g    = (const float*)d_in[18];
  const float* ln2_b    = (const float*)d_in[19];
  const float* ff1_w    = (const float*)d_in[20];
  const float* ff1_b    = (const float*)d_in[21];
  const float* ff2_w    = (const float*)d_in[22];
  const float* ff2_b    = (const float*)d_in[23];
  const float* lnf_g    = (const float*)d_in[24];
  const float* lnf_b    = (const float*)d_in[25];
  const float* logits_w = (const float*)d_in[26];
  const float* logits_b = (const float*)d_in[27];

  float* wsf = (float*)d_ws;
  size_t off = 0;
  unsigned short* qp_bf = (unsigned short*)(wsf + off); off += 2129920;
  unsigned short* kp_bf = (unsigned short*)(wsf + off); off += 2129920;
  float* h = wsf + off; off += 1064960;
  unsigned short* x1b = (unsigned short*)(wsf + off); off += 532480;
  unsigned short* qkvb = (unsigned short*)(wsf + off); off += 1597440;
  unsigned short* ob  = (unsigned short*)(wsf + off); off += 532480;
  unsigned short* projb = (unsigned short*)(wsf + off); off += 49152;
  unsigned short* wqkvt = (unsigned short*)(wsf + off); off += 393216;
  unsigned short* wot   = (unsigned short*)(wsf + off); off += 131072;
  unsigned short* ff1t  = (unsigned short*)(wsf + off); off += 524288;
  unsigned short* ff2t  = (unsigned short*)(wsf + off); off += 524288;
  unsigned short* logt  = (unsigned short*)(wsf + off); off += 133888;
  unsigned short* ffmid = (unsigned short*)(wsf + off); off += 2129920;
  float* logits = wsf + off; off += 1087840;
  int* inds = (int*)(wsf + off); off += 2048;
  int* seq  = (int*)(wsf + off); off += 2112;
  unsigned int* gmaxbits = (unsigned int*)(wsf + off); off += 64;
  float* rnll = wsf + off; off += 2112;

  // conv scratch aliases dead ffmid region
  float* c1 = (float*)ffmid;            // 524288 f32
  float* c2 = ((float*)ffmid) + 524288; // 131072 f32

  unsigned short* qnb = qkvb;
  unsigned short* knb = qkvb + QSEG;
  unsigned short* vnb = qkvb + 2*QSEG;

  conv1_k<<<2048,256,0,stream>>>(x, xn, conv1_w, conv1_b, c1);
  conv2_k<<<dim3(4,32),256,0,stream>>>(c1, conv2_w, conv2_b, c2);
  vq_k<<<2048,256,0,stream>>>(c2, codebook, inds);
  seq_k<<<(16*LSEQ+255)/256,256,0,stream>>>(iarr, inds, seq);
  embed_k<<<(NROWS*DIMM)/256,256,0,stream>>>(seq, tok_emb, pos_emb, h);
  projcv_k<<<384,256,0,stream>>>(proj, projb);
  wconv_k<<<dim3(17,16),256,0,stream>>>(logits_w, logt, 512, 523);

  for(int l=0;l<6;l++){
    wprep_k<<<3072,256,0,stream>>>(wq + (size_t)l*262144, wk + (size_t)l*262144,
        wv + (size_t)l*262144, wo + (size_t)l*262144,
        ff1_w + (size_t)l*1048576, ff2_w + (size_t)l*1048576,
        wqkvt, wot, ff1t, ff2t, gmaxbits);
    ln_k<<<NROWS,256,0,stream>>>(h, ln1_g+l*DIMM, ln1_b+l*DIMM, x1b);
    mgemm_k<1><<<dim3(24,33),256,0,stream>>>(x1b, wqkvt, nullptr, nullptr, qkvb, NROWS, 1536, DIMM);
    featA_k<<<dim3(520,2),256,0,stream>>>(qnb, knb, projb + l*16384, qp_bf, gmaxbits);
    featB_k<<<520,256,0,stream>>>(knb, projb + l*16384, gmaxbits, kp_bf);
    attn_k<<<dim3(5,NBH),256,0,stream>>>(qp_bf, kp_bf, vnb, ob);
    mgemm_k<3><<<dim3(8,33),256,0,stream>>>(ob, wot, bo+l*DIMM, h, nullptr, NROWS, DIMM, DIMM);
    ln_k<<<NROWS,256,0,stream>>>(h, ln2_g+l*DIMM, ln2_b+l*DIMM, x1b);
    mgemm_k<4><<<dim3(32,33),256,0,stream>>>(x1b, ff1t, ff1_b+l*2048, nullptr, ffmid, NROWS, 2048, DIMM);
    mgemm_k<3><<<dim3(8,33),256,0,stream>>>(ffmid, ff2t, ff2_b+l*DIMM, h, nullptr, NROWS, DIMM, 2048);
  }

  ln_k<<<NROWS,256,0,stream>>>(h, lnf_g, lnf_b, x1b);
  mgemm_k<0><<<dim3(9,33),256,0,stream>>>(x1b, logt, logits_b, logits, nullptr, NROWS, VSZ, DIMM);
  loss_k<<<NROWS,256,0,stream>>>(logits, seq, rnll);
  fin_k<<<1,256,0,stream>>>(rnll, (float*)d_out);
}

// Round 4
// 795.975 us; speedup vs baseline: 7.6179x; 1.0705x over previous
//
#include <hip/hip_runtime.h>

#define SEQL 130
#define LSEQ 131
#define DIMM 512
#define NHEADS 8
#define MF 256
#define VSZ 523
#define NROWS (16*SEQL)          // 2080
#define NBH (16*NHEADS)          // 128
#define NBHL (NBH*SEQL)          // 16640
#define QSEG 1064960             // us elements per q/k/v segment

typedef __attribute__((ext_vector_type(8))) short short8;
typedef __attribute__((ext_vector_type(8))) unsigned short us8;
typedef __attribute__((ext_vector_type(4))) unsigned short us4;
typedef __attribute__((ext_vector_type(4))) float f32x4;

__device__ __forceinline__ unsigned short f2bf(float f){
  unsigned int u = __float_as_uint(f);
  u += 0x7fffu + ((u>>16)&1u);
  return (unsigned short)(u>>16);
}
__device__ __forceinline__ float bf2f(unsigned short h){
  return __uint_as_float(((unsigned int)h)<<16);
}
__device__ __forceinline__ float gelu_f(float x){
  float x3 = x*x*x;
  return 0.5f*x*(1.f+tanhf(0.7978845608028654f*(x+0.044715f*x3)));
}
__device__ __forceinline__ unsigned enc_max(float f){
  unsigned u = __float_as_uint(f);
  return (u & 0x80000000u) ? ~u : (u | 0x80000000u);
}
__device__ __forceinline__ float dec_max(unsigned k){
  unsigned u = (k>>31) ? (k & 0x7fffffffu) : ~k;
  return __uint_as_float(u);
}
__device__ __forceinline__ float blk_sum(float v){
  #pragma unroll
  for(int off=32;off;off>>=1) v += __shfl_xor(v,off);
  __shared__ float tmp_s[4];
  int t=threadIdx.x;
  if((t&63)==0) tmp_s[t>>6]=v;
  __syncthreads();
  v = tmp_s[0]+tmp_s[1]+tmp_s[2]+tmp_s[3];
  __syncthreads();
  return v;
}
__device__ __forceinline__ float blk_max(float v){
  #pragma unroll
  for(int off=32;off;off>>=1) v = fmaxf(v,__shfl_xor(v,off));
  __shared__ float tmp_m[4];
  int t=threadIdx.x;
  if((t&63)==0) tmp_m[t>>6]=v;
  __syncthreads();
  v = fmaxf(fmaxf(tmp_m[0],tmp_m[1]),fmaxf(tmp_m[2],tmp_m[3]));
  __syncthreads();
  return v;
}
__device__ __forceinline__ int tok_at(const int* __restrict__ iarr,
    const int* __restrict__ inds, int b, int p){
  if(p<3)  return iarr[b*3+p];
  if(p<67) return inds[(16+b)*64 + (p-3)];
  return inds[b*64 + (p-67)];
}

// ---------------- conv1: (32,1,16,16,16) -> relu (32,32,8,8,8), stride2 pad1
__global__ __launch_bounds__(256) void conv1_k(const float* __restrict__ x,
    const float* __restrict__ xn, const float* __restrict__ w,
    const float* __restrict__ bias, float* __restrict__ out){
  int idx = blockIdx.x*256 + threadIdx.x;
  if(idx >= 32*32*8*8*8) return;
  int ow = idx & 7, oh = (idx>>3)&7, od = (idx>>6)&7, oc = (idx>>9)&31, n = idx>>14;
  const float* xp = (n<16) ? (x + n*4096) : (xn + (n-16)*4096);
  const float* wp = w + oc*64;
  float acc = bias[oc];
  #pragma unroll
  for(int kd=0;kd<4;kd++){ int id = od*2-1+kd; if((unsigned)id>=16u) continue;
    #pragma unroll
    for(int kh=0;kh<4;kh++){ int ih = oh*2-1+kh; if((unsigned)ih>=16u) continue;
      #pragma unroll
      for(int kw=0;kw<4;kw++){ int iw = ow*2-1+kw; if((unsigned)iw>=16u) continue;
        acc += xp[(id*16+ih)*16+iw]*wp[(kd*4+kh)*4+kw];
      }}}
  out[idx] = fmaxf(acc,0.f);
}

// ---------------- conv2 (256 blocks x 512 threads) --------------------------
// grid (4 od, 32 n, 2 ocg); out layout (n, oc, od*16+oh*4+ow)
__global__ __launch_bounds__(512) void conv2_k(const float* __restrict__ c1,
    const float* __restrict__ w, const float* __restrict__ bias,
    float* __restrict__ out){
  __shared__ float in_s[32][4][120];   // [ic][kd][(ih+1)*12 + (iw+1)], 60KB
  int od = blockIdx.x, n = blockIdx.y, ocg = blockIdx.z;
  int t = threadIdx.x;
  // zero-init 3840 f32x4
  float4* zf = (float4*)&in_s[0][0][0];
  #pragma unroll
  for(int j=0;j<8;j++){
    int idx = t + 512*j;
    if(idx < 3840) zf[idx] = make_float4(0.f,0.f,0.f,0.f);
  }
  __syncthreads();
  // load valid planes: 1024 tuples (ic, kd, ih)
  #pragma unroll
  for(int j=0;j<2;j++){
    int ridx = t + 512*j;
    int ic = ridx>>5, rem = ridx&31;
    int kd = rem>>3, ih = rem&7;
    int id = od*2 - 1 + kd;
    if((unsigned)id < 8u){
      const float* src = c1 + (size_t)(n*32+ic)*512 + id*64 + ih*8;
      float4 a = *(const float4*)src;
      float4 b = *(const float4*)(src+4);
      float* dst = &in_s[ic][kd][(ih+1)*12 + 1];
      dst[0]=a.x; dst[1]=a.y; dst[2]=a.z; dst[3]=a.w;
      dst[4]=b.x; dst[5]=b.y; dst[6]=b.z; dst[7]=b.w;
    }
  }
  __syncthreads();
  int oc = ocg*32 + (t>>4);
  int oh = (t>>2)&3, ow = t&3;
  float acc = bias[oc];
  for(int ic=0; ic<32; ic++){
    #pragma unroll
    for(int kd=0;kd<4;kd++){
      #pragma unroll
      for(int kh=0;kh<4;kh++){
        f32x4 wv = *(const f32x4*)(w + ((size_t)(oc*32+ic)*64 + (kd*4+kh)*4));
        const float* base = &in_s[ic][kd][(oh*2+kh)*12 + ow*2];
        acc += wv[0]*base[0] + wv[1]*base[1] + wv[2]*base[2] + wv[3]*base[3];
      }
    }
  }
  out[(size_t)(n*64+oc)*64 + od*16 + oh*4 + ow] = acc;
}

// ---------------- VQ argmin ------------------------------------------------
__global__ __launch_bounds__(256) void vq_k(const float* __restrict__ c2,
    const float* __restrict__ cb, int* __restrict__ inds){
  int nf = blockIdx.x;               // 0..2047
  int nb = nf>>6, sp = nf&63;
  __shared__ float z[64];
  int t = threadIdx.x;
  if(t<64) z[t] = c2[(nb*64+t)*64 + sp];
  __syncthreads();
  float best = 3.0e38f; int bi = 0;
  for(int j=t; j<512; j+=256){
    const float* cr = cb + j*64;
    float dot=0.f, nn=0.f;
    #pragma unroll 8
    for(int d=0;d<64;d++){ float cv=cr[d]; dot += z[d]*cv; nn += cv*cv; }
    float dist = nn - 2.f*dot;
    if(dist < best){ best=dist; bi=j; }
  }
  #pragma unroll
  for(int off=32;off;off>>=1){
    float ob = __shfl_down(best,off); int oi = __shfl_down(bi,off);
    if(ob<best || (ob==best && oi<bi)){ best=ob; bi=oi; }
  }
  __shared__ float rb[4]; __shared__ int ri[4];
  if((t&63)==0){ rb[t>>6]=best; ri[t>>6]=bi; }
  __syncthreads();
  if(t==0){
    for(int wv=1;wv<4;wv++){ if(rb[wv]<best || (rb[wv]==best && ri[wv]<bi)){ best=rb[wv]; bi=ri[wv]; } }
    inds[nf]=bi;
  }
}

__global__ __launch_bounds__(256) void embed_k(const int* __restrict__ iarr,
    const int* __restrict__ inds, const float* __restrict__ tok,
    const float* __restrict__ pos, float* __restrict__ h){
  int idx = blockIdx.x*256 + threadIdx.x;
  int c = idx & 511; int row = idx >> 9;
  int b = row/SEQL, l = row - b*SEQL;
  int tk = tok_at(iarr, inds, b, l);
  h[idx] = tok[tk*DIMM + c] + pos[l*DIMM + c];
}

// ---------------- layernorm: f32 in, bf16 out -------------------------------
__global__ __launch_bounds__(256) void ln_k(const float* __restrict__ in,
    const float* __restrict__ g, const float* __restrict__ bb,
    unsigned short* __restrict__ out){
  int row = blockIdx.x; int t = threadIdx.x;
  const float* xr = in + (size_t)row*DIMM;
  float x0 = xr[t], x1 = xr[t+256];
  float s = x0+x1, ss = x0*x0 + x1*x1;
  #pragma unroll
  for(int off=32;off;off>>=1){ s += __shfl_xor(s,off); ss += __shfl_xor(ss,off); }
  __shared__ float bs[4], bss[4];
  if((t&63)==0){ bs[t>>6]=s; bss[t>>6]=ss; }
  __syncthreads();
  s = bs[0]+bs[1]+bs[2]+bs[3]; ss = bss[0]+bss[1]+bss[2]+bss[3];
  float mu = s*(1.f/512.f);
  float var = ss*(1.f/512.f) - mu*mu;
  float inv = rsqrtf(var + 1e-5f);
  out[(size_t)row*DIMM+t]     = f2bf((x0-mu)*inv*g[t]     + bb[t]);
  out[(size_t)row*DIMM+t+256] = f2bf((x1-mu)*inv*g[t+256] + bb[t+256]);
}

// ---------------- per-layer weight prep (transpose + bf16) ------------------
__global__ __launch_bounds__(256) void wprep_k(const float* __restrict__ wq_l,
    const float* __restrict__ wk_l, const float* __restrict__ wv_l,
    const float* __restrict__ wo_l, const float* __restrict__ ff1_l,
    const float* __restrict__ ff2_l,
    unsigned short* __restrict__ wqkvt, unsigned short* __restrict__ wot,
    unsigned short* __restrict__ ff1t, unsigned short* __restrict__ ff2t,
    unsigned int* __restrict__ gmaxbits){
  int bid = blockIdx.x;
  int t = threadIdx.x;
  if(bid==0 && t==0) gmaxbits[0] = 0u;
  const float* src; unsigned short* dst;
  int n0, k0, srcN, dstK;
  if(bid < 768){
    int nt = bid % 48, kt = bid / 48;
    n0 = nt*32; k0 = kt*32;
    int seg = n0 >> 9;
    src = (seg==0 ? wq_l : seg==1 ? wk_l : wv_l);
    dst = wqkvt; srcN = 512; dstK = 512;
  } else if(bid < 1024){
    int b2 = bid-768; int nt = b2 % 16, kt = b2 / 16;
    n0 = nt*32; k0 = kt*32; src = wo_l; dst = wot; srcN = 512; dstK = 512;
  } else if(bid < 2048){
    int b2 = bid-1024; int nt = b2 % 64, kt = b2 / 64;
    n0 = nt*32; k0 = kt*32; src = ff1_l; dst = ff1t; srcN = 2048; dstK = 512;
  } else {
    int b2 = bid-2048; int nt = b2 % 16, kt = b2 / 16;
    n0 = nt*32; k0 = kt*32; src = ff2_l; dst = ff2t; srcN = 512; dstK = 2048;
  }
  int srcCol0 = (bid < 768) ? (n0 & 0x1ff) : n0;
  __shared__ float tile[32][33];
  int c = t&31, r = t>>5;
  #pragma unroll
  for(int j=0;j<4;j++)
    tile[r+8*j][c] = src[(size_t)(k0+r+8*j)*srcN + srcCol0 + c];
  __syncthreads();
  #pragma unroll
  for(int j=0;j<4;j++){
    int n = n0 + r + 8*j;
    dst[(size_t)n*dstK + k0 + c] = f2bf(tile[c][r+8*j]);
  }
}

// generic transpose for logits weight [512][523] -> [523][512]
__global__ __launch_bounds__(256) void wconv_k(const float* __restrict__ W,
    unsigned short* __restrict__ dst, int K, int N){
  __shared__ float tile[32][33];
  int k0 = blockIdx.y*32, n0 = blockIdx.x*32;
  int t = threadIdx.x; int c = t&31, r = t>>5;
  #pragma unroll
  for(int j=0;j<4;j++){
    int n = n0+c;
    tile[r+8*j][c] = (n<N) ? W[(size_t)(k0+r+8*j)*N + n] : 0.f;
  }
  __syncthreads();
  #pragma unroll
  for(int j=0;j<4;j++){
    int n = n0 + r + 8*j;
    if(n<N) dst[(size_t)n*K + k0 + c] = f2bf(tile[c][r+8*j]);
  }
}

__global__ __launch_bounds__(256) void projcv_k(const float* __restrict__ proj,
    unsigned short* __restrict__ pb){
  int i = blockIdx.x*256 + threadIdx.x;
  if(i < 6*MF*64) pb[i] = f2bf(proj[i]);
}

// ---------------- MFMA GEMM 64x64: C[M,N] = A[M,K]bf16 @ Bt[N,K]bf16^T ------
// MODE 0: f32 out (+optional bias); MODE 1: bf16 qkv head-major; 
// MODE 3: f32 += (bias); MODE 4: bf16 out bias+gelu
template<int MODE>
__global__ __launch_bounds__(256) void mgemm_k(const unsigned short* __restrict__ A,
    const unsigned short* __restrict__ Bt, const float* __restrict__ bias,
    float* __restrict__ Cf, unsigned short* __restrict__ Cb,
    int M, int N, int K){
  __shared__ unsigned short As[4096];
  __shared__ unsigned short Bs[4096];
  int t = threadIdx.x;
  const int m0 = blockIdx.y*64, n0 = blockIdx.x*64;
  int w = t>>6, l = t&63;
  int wr = w>>1, wc = w&1;
  f32x4 acc[2][2] = {};
  int srow = t>>2, sp = (t&3)*2;
  int arow = m0 + srow, brow = n0 + srow;
  bool aok = arow < M, bok = brow < N;
  const us8* Ap = (const us8*)(A + (size_t)arow*K + sp*8);
  const us8* Bp = (const us8*)(Bt + (size_t)brow*K + sp*8);
  unsigned short* Aw0 = As + srow*64 + (((sp  )^(srow&7))<<3);
  unsigned short* Aw1 = As + srow*64 + (((sp+1)^(srow&7))<<3);
  unsigned short* Bw0 = Bs + srow*64 + (((sp  )^(srow&7))<<3);
  unsigned short* Bw1 = Bs + srow*64 + (((sp+1)^(srow&7))<<3);
  for(int k0=0; k0<K; k0+=64){
    us8 a0={}, a1={}, b0={}, b1={};
    if(aok){ a0 = Ap[0]; a1 = Ap[1]; }
    if(bok){ b0 = Bp[0]; b1 = Bp[1]; }
    Ap += 8; Bp += 8;
    __syncthreads();
    *(us8*)Aw0 = a0; *(us8*)Aw1 = a1;
    *(us8*)Bw0 = b0; *(us8*)Bw1 = b1;
    __syncthreads();
    #pragma unroll
    for(int kk=0;kk<2;kk++){
      short8 af[2], bf[2];
      #pragma unroll
      for(int m=0;m<2;m++){
        int row = wr*32 + m*16 + (l&15);
        int slot = kk*4 + (l>>4);
        af[m] = *(const short8*)(As + row*64 + ((slot^(row&7))<<3));
      }
      #pragma unroll
      for(int n=0;n<2;n++){
        int col = wc*32 + n*16 + (l&15);
        int slot = kk*4 + (l>>4);
        bf[n] = *(const short8*)(Bs + col*64 + ((slot^(col&7))<<3));
      }
      #pragma unroll
      for(int m=0;m<2;m++)
        #pragma unroll
        for(int n=0;n<2;n++)
          acc[m][n] = __builtin_amdgcn_mfma_f32_16x16x32_bf16(af[m], bf[n], acc[m][n], 0, 0, 0);
    }
  }
  #pragma unroll
  for(int m=0;m<2;m++){
    #pragma unroll
    for(int n=0;n<2;n++){
      int col = n0 + wc*32 + n*16 + (l&15);
      #pragma unroll
      for(int i=0;i<4;i++){
        int row = m0 + wr*32 + m*16 + (l>>4)*4 + i;
        if(row < M && col < N){
          float v = acc[m][n][i];
          if(MODE==0){
            if(bias) v += bias[col];
            Cf[(size_t)row*N+col] = v;
          } else if(MODE==1){
            v *= (col < 1024) ? 0.35355339059327378f : 1.0f;
            int seg = col>>9, d0 = col&511;
            int hh = d0>>6, d = d0&63;
            int bb = row/SEQL, ll = row - bb*SEQL;
            Cb[(size_t)seg*QSEG + (((size_t)(bb*NHEADS+hh))*SEQL + ll)*64 + d] = f2bf(v);
          } else if(MODE==3){
            v += bias[col];
            Cf[(size_t)row*N+col] += v;
          } else {
            v += bias[col];
            v = gelu_f(v);
            Cb[(size_t)row*N+col] = f2bf(v);
          }
        }
      }
    }
  }
}

// ---------------- MFMA GEMM 32x64 (M%32==0, N%64==0, K%64==0), f32 += bias --
__global__ __launch_bounds__(256) void mgemm32_k(const unsigned short* __restrict__ A,
    const unsigned short* __restrict__ Bt, const float* __restrict__ bias,
    float* __restrict__ Cf, int N, int K){
  __shared__ unsigned short As[2048];
  __shared__ unsigned short Bs[4096];
  int t = threadIdx.x;
  const int m0 = blockIdx.y*32, n0 = blockIdx.x*64;
  int w = t>>6, l = t&63;
  int wm = w&1, wn2 = w>>1;
  f32x4 acc[2] = {};
  int srowA = t>>3, spA = t&7;
  int srowB = t>>2, spB = (t&3)*2;
  const us8* Ap = (const us8*)(A + (size_t)(m0+srowA)*K + spA*8);
  const us8* Bp = (const us8*)(Bt + (size_t)(n0+srowB)*K + spB*8);
  unsigned short* Aw  = As + srowA*64 + ((spA^(srowA&7))<<3);
  unsigned short* Bw0 = Bs + srowB*64 + (((spB  )^(srowB&7))<<3);
  unsigned short* Bw1 = Bs + srowB*64 + (((spB+1)^(srowB&7))<<3);
  for(int k0=0; k0<K; k0+=64){
    us8 a0 = Ap[0];
    us8 b0 = Bp[0], b1 = Bp[1];
    Ap += 8; Bp += 8;
    __syncthreads();
    *(us8*)Aw = a0;
    *(us8*)Bw0 = b0; *(us8*)Bw1 = b1;
    __syncthreads();
    #pragma unroll
    for(int kk=0;kk<2;kk++){
      int arow = wm*16 + (l&15);
      int slot = kk*4 + (l>>4);
      short8 af = *(const short8*)(As + arow*64 + ((slot^(arow&7))<<3));
      #pragma unroll
      for(int n=0;n<2;n++){
        int col = (wn2*2+n)*16 + (l&15);
        short8 bf = *(const short8*)(Bs + col*64 + ((slot^(col&7))<<3));
        acc[n] = __builtin_amdgcn_mfma_f32_16x16x32_bf16(af, bf, acc[n], 0, 0, 0);
      }
    }
  }
  #pragma unroll
  for(int n=0;n<2;n++){
    int col = n0 + (wn2*2+n)*16 + (l&15);
    float bv = bias[col];
    #pragma unroll
    for(int i=0;i<4;i++){
      int row = m0 + wm*16 + (l>>4)*4 + i;
      Cf[(size_t)row*N+col] += acc[n][i] + bv;
    }
  }
}

// ---------------- fused feature-map kernels ---------------------------------
__global__ __launch_bounds__(256) void featA_k(const unsigned short* __restrict__ qn,
    const unsigned short* __restrict__ kn, const unsigned short* __restrict__ projl,
    unsigned short* __restrict__ qp, unsigned int* __restrict__ gmaxbits){
  int z = blockIdx.y;
  const unsigned short* dn = z ? kn : qn;
  __shared__ float uni[32*264];
  __shared__ unsigned short dns[2048];
  unsigned short* ps = (unsigned short*)uni;
  int t = threadIdx.x;
  size_t R0 = (size_t)blockIdx.x*32;
  {
    int row = t>>3, sl = t&7;
    us8 u = *(const us8*)(dn + (R0+row)*64 + sl*8);
    *(us8*)(dns + row*64 + ((sl^(row&7))<<3)) = u;
  }
  #pragma unroll
  for(int j=0;j<8;j++){
    int ridx = t + 256*j;
    int row = ridx>>3, sl = ridx&7;
    us8 u = *(const us8*)(projl + row*64 + sl*8);
    *(us8*)(ps + row*64 + ((sl^(row&7))<<3)) = u;
  }
  __syncthreads();
  int w = t>>6, l = t&63;
  int rt = w&1, cb = (w>>1)*8;
  f32x4 acc[8] = {};
  #pragma unroll
  for(int kk=0;kk<2;kk++){
    int ar = rt*16 + (l&15);
    int slot = kk*4 + (l>>4);
    short8 a = *(const short8*)(dns + ar*64 + ((slot^(ar&7))<<3));
    #pragma unroll
    for(int ct=0;ct<8;ct++){
      int br = (cb+ct)*16 + (l&15);
      short8 b = *(const short8*)(ps + br*64 + ((slot^(br&7))<<3));
      acc[ct] = __builtin_amdgcn_mfma_f32_16x16x32_bf16(a, b, acc[ct], 0, 0, 0);
    }
  }
  __syncthreads();
  #pragma unroll
  for(int ct=0;ct<8;ct++){
    int col = (cb+ct)*16 + (l&15);
    #pragma unroll
    for(int i=0;i<4;i++){
      int row = rt*16 + (l>>4)*4 + i;
      uni[row*264 + col] = acc[ct][i];
    }
  }
  __syncthreads();
  int r = t>>3, sub = t&7;
  float* rowp = uni + r*264 + sub*32;
  f32x4 v[8];
  #pragma unroll
  for(int jj=0;jj<8;jj++) v[jj] = *(const f32x4*)(rowp + jj*4);
  float m = -3.0e38f;
  #pragma unroll
  for(int jj=0;jj<8;jj++)
    #pragma unroll
    for(int i=0;i<4;i++) m = fmaxf(m, v[jj][i]);
  m = fmaxf(m, __shfl_xor(m,1));
  m = fmaxf(m, __shfl_xor(m,2));
  m = fmaxf(m, __shfl_xor(m,4));
  if(z==0){
    us8 dvu = *(const us8*)(dns + r*64 + ((sub^(r&7))<<3));
    float s2 = 0.f;
    #pragma unroll
    for(int j=0;j<8;j++){ float xx = bf2f(dvu[j]); s2 += xx*xx; }
    s2 += __shfl_xor(s2,1); s2 += __shfl_xor(s2,2); s2 += __shfl_xor(s2,4);
    float ds = 0.5f*s2;
    unsigned short* op = qp + (R0+r)*256 + sub*32;
    #pragma unroll
    for(int jj=0;jj<8;jj++){
      us4 u4;
      #pragma unroll
      for(int i=0;i<4;i++) u4[i] = f2bf(expf(v[jj][i] - ds - m)*0.0625f + 1e-4f);
      *(us4*)(op + jj*4) = u4;
    }
  } else {
    float bm = m;
    bm = fmaxf(bm, __shfl_xor(bm,8));
    bm = fmaxf(bm, __shfl_xor(bm,16));
    bm = fmaxf(bm, __shfl_xor(bm,32));
    __shared__ float wm[4];
    if(l==0) wm[w] = bm;
    __syncthreads();
    if(t==0){
      float g = fmaxf(fmaxf(wm[0],wm[1]),fmaxf(wm[2],wm[3]));
      atomicMax(gmaxbits, enc_max(g));
    }
  }
}

__global__ __launch_bounds__(256) void featB_k(const unsigned short* __restrict__ kn,
    const unsigned short* __restrict__ projl, const unsigned int* __restrict__ gmaxbits,
    unsigned short* __restrict__ kp){
  __shared__ float uni[32*264];
  __shared__ unsigned short dns[2048];
  unsigned short* ps = (unsigned short*)uni;
  int t = threadIdx.x;
  size_t R0 = (size_t)blockIdx.x*32;
  {
    int row = t>>3, sl = t&7;
    us8 u = *(const us8*)(kn + (R0+row)*64 + sl*8);
    *(us8*)(dns + row*64 + ((sl^(row&7))<<3)) = u;
  }
  #pragma unroll
  for(int j=0;j<8;j++){
    int ridx = t + 256*j;
    int row = ridx>>3, sl = ridx&7;
    us8 u = *(const us8*)(projl + row*64 + sl*8);
    *(us8*)(ps + row*64 + ((sl^(row&7))<<3)) = u;
  }
  __syncthreads();
  int w = t>>6, l = t&63;
  int rt = w&1, cb = (w>>1)*8;
  f32x4 acc[8] = {};
  #pragma unroll
  for(int kk=0;kk<2;kk++){
    int ar = rt*16 + (l&15);
    int slot = kk*4 + (l>>4);
    short8 a = *(const short8*)(dns + ar*64 + ((slot^(ar&7))<<3));
    #pragma unroll
    for(int ct=0;ct<8;ct++){
      int br = (cb+ct)*16 + (l&15);
      short8 b = *(const short8*)(ps + br*64 + ((slot^(br&7))<<3));
      acc[ct] = __builtin_amdgcn_mfma_f32_16x16x32_bf16(a, b, acc[ct], 0, 0, 0);
    }
  }
  __syncthreads();
  #pragma unroll
  for(int ct=0;ct<8;ct++){
    int col = (cb+ct)*16 + (l&15);
    #pragma unroll
    for(int i=0;i<4;i++){
      int row = rt*16 + (l>>4)*4 + i;
      uni[row*264 + col] = acc[ct][i];
    }
  }
  __syncthreads();
  float g = dec_max(gmaxbits[0]);
  int r = t>>3, sub = t&7;
  us8 dvu = *(const us8*)(dns + r*64 + ((sub^(r&7))<<3));
  float s2 = 0.f;
  #pragma unroll
  for(int j=0;j<8;j++){ float xx = bf2f(dvu[j]); s2 += xx*xx; }
  s2 += __shfl_xor(s2,1); s2 += __shfl_xor(s2,2); s2 += __shfl_xor(s2,4);
  float ds = 0.5f*s2;
  float* rowp = uni + r*264 + sub*32;
  unsigned short* op = kp + (R0+r)*256 + sub*32;
  #pragma unroll
  for(int jj=0;jj<8;jj++){
    f32x4 v = *(const f32x4*)(rowp + jj*4);
    us4 u4;
    #pragma unroll
    for(int i=0;i<4;i++) u4[i] = f2bf(expf(v[i] - ds - g)*0.0625f + 1e-4f);
    *(us4*)(op + jj*4) = u4;
  }
}

// ---------------- quadratic causal attention --------------------------------
__global__ __launch_bounds__(256) void attn_k(const unsigned short* __restrict__ qp,
    const unsigned short* __restrict__ kp, const unsigned short* __restrict__ vn,
    unsigned short* __restrict__ ob){
  int qt = blockIdx.x, bh = blockIdx.y;
  int b = bh>>3, hh = bh&7;
  __shared__ unsigned short qs[32*256];
  __shared__ unsigned short ks[32*256];
  __shared__ float vs[32][68];
  __shared__ float Ss[32][33];
  __shared__ float dens[2][32];
  int t = threadIdx.x;
  int w = t>>6, l = t&63;
  int qh = w>>1, kh = w&1;
  {
    int rr = t>>3, s0 = (t&7)*4;
    int gr = qt*32 + rr;
    const us8* src = (const us8*)(qp + ((size_t)bh*SEQL + (gr<SEQL?gr:0))*256 + s0*8);
    #pragma unroll
    for(int j=0;j<4;j++){
      us8 u = {};
      if(gr<SEQL) u = src[j];
      *(us8*)(qs + rr*256 + (((s0+j)^(rr&7))<<3)) = u;
    }
  }
  if(t<64) dens[t>>5][t&31] = 0.f;
  float o[8] = {0.f,0.f,0.f,0.f,0.f,0.f,0.f,0.f};
  int orow = t>>3, od = (t&7)*8;
  for(int kt=0; kt<=qt; kt++){
    __syncthreads();
    {
      int rr = t>>3, s0 = (t&7)*4;
      int gk = kt*32 + rr;
      const us8* src = (const us8*)(kp + ((size_t)bh*SEQL + (gk<SEQL?gk:0))*256 + s0*8);
      #pragma unroll
      for(int j=0;j<4;j++){
        us8 u = {};
        if(gk<SEQL) u = src[j];
        *(us8*)(ks + rr*256 + (((s0+j)^(rr&7))<<3)) = u;
      }
      const us8* vsrc = (const us8*)(vn + ((size_t)bh*SEQL + (gk<SEQL?gk:0))*64 + od);
      us8 uv = {};
      if(gk<SEQL) uv = vsrc[0];
      #pragma unroll
      for(int i=0;i<8;i++) vs[rr][od+i] = bf2f(uv[i]);
    }
    __syncthreads();
    f32x4 sacc = {};
    #pragma unroll
    for(int kk=0;kk<8;kk++){
      int ar = qh*16 + (l&15); int slot = kk*4 + (l>>4);
      short8 a = *(const short8*)(qs + ar*256 + ((slot^(ar&7))<<3));
      int br = kh*16 + (l&15);
      short8 bb2 = *(const short8*)(ks + br*256 + ((slot^(br&7))<<3));
      sacc = __builtin_amdgcn_mfma_f32_16x16x32_bf16(a, bb2, sacc, 0, 0, 0);
    }
    int scol = kh*16 + (l&15);
    int gcol = kt*32 + scol;
    float dp[4];
    #pragma unroll
    for(int i=0;i<4;i++){
      int sr = qh*16 + (l>>4)*4 + i;
      int grw = qt*32 + sr;
      float v2 = sacc[i];
      if(gcol > grw) v2 = 0.f;
      Ss[sr][scol] = v2;
      dp[i] = v2;
    }
    #pragma unroll
    for(int off=1;off<16;off<<=1)
      #pragma unroll
      for(int i=0;i<4;i++) dp[i] += __shfl_xor(dp[i], off);
    if((l&15)==0){
      #pragma unroll
      for(int i=0;i<4;i++) dens[kh][qh*16 + (l>>4)*4 + i] += dp[i];
    }
    __syncthreads();
    #pragma unroll
    for(int k2=0;k2<32;k2++){
      float s = Ss[orow][k2];
      #pragma unroll
      for(int j=0;j<8;j++) o[j] += s*vs[k2][od+j];
    }
  }
  __syncthreads();
  int gr = qt*32 + orow;
  if(gr < SEQL){
    float inv = 1.f/(dens[0][orow] + dens[1][orow]);
    us8 u;
    #pragma unroll
    for(int j=0;j<8;j++) u[j] = f2bf(o[j]*inv);
    *(us8*)(ob + ((size_t)(b*SEQL+gr))*DIMM + hh*64 + od) = u;
  }
}

// ---------------- loss ------------------------------------------------------
__global__ __launch_bounds__(256) void loss_k(const float* __restrict__ logits,
    const int* __restrict__ iarr, const int* __restrict__ inds,
    float* __restrict__ rnll){
  int row = blockIdx.x; int t = threadIdx.x;
  const float* lr = logits + (size_t)row*VSZ;
  float m = -3.0e38f;
  for(int j=t;j<VSZ;j+=256) m = fmaxf(m, lr[j]);
  m = blk_max(m);
  float s = 0.f;
  for(int j=t;j<VSZ;j+=256) s += expf(lr[j]-m);
  s = blk_sum(s);
  if(t==0){
    int b = row/SEQL, l = row - b*SEQL;
    int tgt = tok_at(iarr, inds, b, l+1);
    rnll[row] = (m + logf(s)) - lr[tgt];
  }
}

__global__ __launch_bounds__(256) void fin_k(const float* __restrict__ rnll,
    float* __restrict__ out){
  int t = threadIdx.x;
  float s = 0.f;
  for(int i=t;i<NROWS;i+=256) s += rnll[i];
  s = blk_sum(s);
  if(t==0) out[0] = s/(float)NROWS;
}

// ---------------------------------------------------------------------------
extern "C" void kernel_launch(void* const* d_in, const int* in_sizes, int n_in,
                              void* d_out, int out_size, void* d_ws, size_t ws_size,
                              hipStream_t stream){
  (void)in_sizes; (void)n_in; (void)out_size; (void)ws_size;
  const float* x        = (const float*)d_in[0];
  const float* xn       = (const float*)d_in[1];
  const int*   iarr     = (const int*)  d_in[2];
  const float* conv1_w  = (const float*)d_in[3];
  const float* conv1_b  = (const float*)d_in[4];
  const float* conv2_w  = (const float*)d_in[5];
  const float* conv2_b  = (const float*)d_in[6];
  const float* codebook = (const float*)d_in[7];
  const float* proj     = (const float*)d_in[8];
  const float* tok_emb  = (const float*)d_in[9];
  const float* pos_emb  = (const float*)d_in[10];
  const float* ln1_g    = (const float*)d_in[11];
  const float* ln1_b    = (const float*)d_in[12];
  const float* wq       = (const float*)d_in[13];
  const float* wk       = (const float*)d_in[14];
  const float* wv       = (const float*)d_in[15];
  const float* wo       = (const float*)d_in[16];
  const float* bo       = (const float*)d_in[17];
  const float* ln2_g    = (const float*)d_in[18];
  const float* ln2_b    = (const float*)d_in[19];
  const float* ff1_w    = (const float*)d_in[20];
  const float* ff1_b    = (const float*)d_in[21];
  const float* ff2_w    = (const float*)d_in[22];
  const float* ff2_b    = (const float*)d_in[23];
  const float* lnf_g    = (const float*)d_in[24];
  const float* lnf_b    = (const float*)d_in[25];
  const float* logits_w = (const float*)d_in[26];
  const float* logits_b = (const float*)d_in[27];

  float* wsf = (float*)d_ws;
  size_t off = 0;
  unsigned short* qp_bf = (unsigned short*)(wsf + off); off += 2129920;
  unsigned short* kp_bf = (unsigned short*)(wsf + off); off += 2129920;
  float* h = wsf + off; off += 1064960;
  unsigned short* x1b = (unsigned short*)(wsf + off); off += 532480;
  unsigned short* qkvb = (unsigned short*)(wsf + off); off += 1597440;
  unsigned short* ob  = (unsigned short*)(wsf + off); off += 532480;
  unsigned short* projb = (unsigned short*)(wsf + off); off += 49152;
  unsigned short* wqkvt = (unsigned short*)(wsf + off); off += 393216;
  unsigned short* wot   = (unsigned short*)(wsf + off); off += 131072;
  unsigned short* ff1t  = (unsigned short*)(wsf + off); off += 524288;
  unsigned short* ff2t  = (unsigned short*)(wsf + off); off += 524288;
  unsigned short* logt  = (unsigned short*)(wsf + off); off += 133888;
  unsigned short* ffmid = (unsigned short*)(wsf + off); off += 2129920;
  float* logits = wsf + off; off += 1087840;
  int* inds = (int*)(wsf + off); off += 2048;
  unsigned int* gmaxbits = (unsigned int*)(wsf + off); off += 64;
  float* rnll = wsf + off; off += 2112;

  // conv scratch aliases dead ffmid region
  float* c1 = (float*)ffmid;            // 524288 f32
  float* c2 = ((float*)ffmid) + 524288; // 131072 f32

  unsigned short* qnb = qkvb;
  unsigned short* knb = qkvb + QSEG;
  unsigned short* vnb = qkvb + 2*QSEG;

  conv1_k<<<2048,256,0,stream>>>(x, xn, conv1_w, conv1_b, c1);
  conv2_k<<<dim3(4,32,2),512,0,stream>>>(c1, conv2_w, conv2_b, c2);
  vq_k<<<2048,256,0,stream>>>(c2, codebook, inds);
  embed_k<<<(NROWS*DIMM)/256,256,0,stream>>>(iarr, inds, tok_emb, pos_emb, h);
  projcv_k<<<384,256,0,stream>>>(proj, projb);
  wconv_k<<<dim3(17,16),256,0,stream>>>(logits_w, logt, 512, 523);

  for(int l=0;l<6;l++){
    wprep_k<<<3072,256,0,stream>>>(wq + (size_t)l*262144, wk + (size_t)l*262144,
        wv + (size_t)l*262144, wo + (size_t)l*262144,
        ff1_w + (size_t)l*1048576, ff2_w + (size_t)l*1048576,
        wqkvt, wot, ff1t, ff2t, gmaxbits);
    ln_k<<<NROWS,256,0,stream>>>(h, ln1_g+l*DIMM, ln1_b+l*DIMM, x1b);
    mgemm_k<1><<<dim3(24,33),256,0,stream>>>(x1b, wqkvt, nullptr, nullptr, qkvb, NROWS, 1536, DIMM);
    featA_k<<<dim3(520,2),256,0,stream>>>(qnb, knb, projb + l*16384, qp_bf, gmaxbits);
    featB_k<<<520,256,0,stream>>>(knb, projb + l*16384, gmaxbits, kp_bf);
    attn_k<<<dim3(5,NBH),256,0,stream>>>(qp_bf, kp_bf, vnb, ob);
    mgemm32_k<<<dim3(8,65),256,0,stream>>>(ob, wot, bo+l*DIMM, h, DIMM, DIMM);
    ln_k<<<NROWS,256,0,stream>>>(h, ln2_g+l*DIMM, ln2_b+l*DIMM, x1b);
    mgemm_k<4><<<dim3(32,33),256,0,stream>>>(x1b, ff1t, ff1_b+l*2048, nullptr, ffmid, NROWS, 2048, DIMM);
    mgemm32_k<<<dim3(8,65),256,0,stream>>>(ffmid, ff2t, ff2_b+l*DIMM, h, DIMM, 2048);
  }

  ln_k<<<NROWS,256,0,stream>>>(h, lnf_g, lnf_b, x1b);
  mgemm_k<0><<<dim3(9,33),256,0,stream>>>(x1b, logt, logits_b, logits, nullptr, NROWS, VSZ, DIMM);
  loss_k<<<NROWS,256,0,stream>>>(logits, iarr, inds, rnll);
  fin_k<<<1,256,0,stream>>>(rnll, (float*)d_out);
}

// Round 5
// 787.714 us; speedup vs baseline: 7.6978x; 1.0105x over previous
//
#include <hip/hip_runtime.h>

#define SEQL 130
#define LSEQ 131
#define DIMM 512
#define NHEADS 8
#define MF 256
#define VSZ 523
#define NROWS (16*SEQL)          // 2080
#define NBH (16*NHEADS)          // 128
#define NBHL (NBH*SEQL)          // 16640
#define QSEG 1064960             // us elements per q/k/v segment

typedef __attribute__((ext_vector_type(8))) short short8;
typedef __attribute__((ext_vector_type(8))) unsigned short us8;
typedef __attribute__((ext_vector_type(4))) unsigned short us4;
typedef __attribute__((ext_vector_type(4))) float f32x4;

__device__ __forceinline__ unsigned short f2bf(float f){
  unsigned int u = __float_as_uint(f);
  u += 0x7fffu + ((u>>16)&1u);
  return (unsigned short)(u>>16);
}
__device__ __forceinline__ float bf2f(unsigned short h){
  return __uint_as_float(((unsigned int)h)<<16);
}
__device__ __forceinline__ float gelu_f(float x){
  float x3 = x*x*x;
  return 0.5f*x*(1.f+tanhf(0.7978845608028654f*(x+0.044715f*x3)));
}
__device__ __forceinline__ unsigned enc_max(float f){
  unsigned u = __float_as_uint(f);
  return (u & 0x80000000u) ? ~u : (u | 0x80000000u);
}
__device__ __forceinline__ float dec_max(unsigned k){
  unsigned u = (k>>31) ? (k & 0x7fffffffu) : ~k;
  return __uint_as_float(u);
}
__device__ __forceinline__ float blk_sum(float v){
  #pragma unroll
  for(int off=32;off;off>>=1) v += __shfl_xor(v,off);
  __shared__ float tmp_s[4];
  int t=threadIdx.x;
  if((t&63)==0) tmp_s[t>>6]=v;
  __syncthreads();
  v = tmp_s[0]+tmp_s[1]+tmp_s[2]+tmp_s[3];
  __syncthreads();
  return v;
}
__device__ __forceinline__ float blk_max(float v){
  #pragma unroll
  for(int off=32;off;off>>=1) v = fmaxf(v,__shfl_xor(v,off));
  __shared__ float tmp_m[4];
  int t=threadIdx.x;
  if((t&63)==0) tmp_m[t>>6]=v;
  __syncthreads();
  v = fmaxf(fmaxf(tmp_m[0],tmp_m[1]),fmaxf(tmp_m[2],tmp_m[3]));
  __syncthreads();
  return v;
}
__device__ __forceinline__ int tok_at(const int* __restrict__ iarr,
    const int* __restrict__ inds, int b, int p){
  if(p<3)  return iarr[b*3+p];
  if(p<67) return inds[(16+b)*64 + (p-3)];
  return inds[b*64 + (p-67)];
}

// ---------------- conv1: (32,1,16,16,16) -> relu (32,32,8,8,8), stride2 pad1
__global__ __launch_bounds__(256) void conv1_k(const float* __restrict__ x,
    const float* __restrict__ xn, const float* __restrict__ w,
    const float* __restrict__ bias, float* __restrict__ out){
  int idx = blockIdx.x*256 + threadIdx.x;
  if(idx >= 32*32*8*8*8) return;
  int ow = idx & 7, oh = (idx>>3)&7, od = (idx>>6)&7, oc = (idx>>9)&31, n = idx>>14;
  const float* xp = (n<16) ? (x + n*4096) : (xn + (n-16)*4096);
  const float* wp = w + oc*64;
  float acc = bias[oc];
  #pragma unroll
  for(int kd=0;kd<4;kd++){ int id = od*2-1+kd; if((unsigned)id>=16u) continue;
    #pragma unroll
    for(int kh=0;kh<4;kh++){ int ih = oh*2-1+kh; if((unsigned)ih>=16u) continue;
      #pragma unroll
      for(int kw=0;kw<4;kw++){ int iw = ow*2-1+kw; if((unsigned)iw>=16u) continue;
        acc += xp[(id*16+ih)*16+iw]*wp[(kd*4+kh)*4+kw];
      }}}
  out[idx] = fmaxf(acc,0.f);
}

// ---------------- generic f32 -> bf16 vector convert ------------------------
__global__ __launch_bounds__(256) void cvt8_k(const float* __restrict__ src,
    unsigned short* __restrict__ dst, int n8){
  int i = blockIdx.x*256 + threadIdx.x;
  if(i >= n8) return;
  const float* s = src + (size_t)i*8;
  us8 u;
  #pragma unroll
  for(int j=0;j<8;j++) u[j] = f2bf(s[j]);
  *(us8*)(dst + (size_t)i*8) = u;
}

// ---------------- conv2 im2col: c1 (32,32,8,8,8) -> icol[2048][2048] bf16 ---
// row r=(n,od,oh,ow); k=(ic,kd,kh,kw); zero-padded
__global__ __launch_bounds__(256) void im2col_k(const float* __restrict__ c1,
    unsigned short* __restrict__ icol){
  int tid = blockIdx.x*256 + threadIdx.x;
  size_t e0 = (size_t)tid*8;
  int r = (int)(e0 >> 11);
  int k0 = (int)(e0 & 2047);
  int n = r>>6, od = (r>>4)&3, oh = (r>>2)&3, ow = r&3;
  int ic = k0>>6, kd = (k0>>4)&3, kh0 = (k0>>2)&3;
  int id = od*2 - 1 + kd;
  us8 u = {};
  if((unsigned)id < 8u){
    const float* base = c1 + (size_t)(n*32+ic)*512 + id*64;
    #pragma unroll
    for(int j=0;j<8;j++){
      int kh = kh0 + (j>>2), kw = j&3;
      int ih = oh*2 - 1 + kh, iw = ow*2 - 1 + kw;
      float v = 0.f;
      if((unsigned)ih < 8u && (unsigned)iw < 8u) v = base[ih*8 + iw];
      u[j] = f2bf(v);
    }
  }
  *(us8*)(icol + e0) = u;
}

// ---------------- VQ argmin (z[row][64] f32, contiguous rows) ---------------
__global__ __launch_bounds__(256) void vq_k(const float* __restrict__ z,
    const float* __restrict__ cb, int* __restrict__ inds){
  int nf = blockIdx.x;               // 0..2047 = (n, spatial)
  __shared__ float zs[64];
  int t = threadIdx.x;
  if(t<64) zs[t] = z[(size_t)nf*64 + t];
  __syncthreads();
  float best = 3.0e38f; int bi = 0;
  for(int j=t; j<512; j+=256){
    const float* cr = cb + j*64;
    float dot=0.f, nn=0.f;
    #pragma unroll 8
    for(int d=0;d<64;d++){ float cv=cr[d]; dot += zs[d]*cv; nn += cv*cv; }
    float dist = nn - 2.f*dot;
    if(dist < best){ best=dist; bi=j; }
  }
  #pragma unroll
  for(int off=32;off;off>>=1){
    float ob = __shfl_down(best,off); int oi = __shfl_down(bi,off);
    if(ob<best || (ob==best && oi<bi)){ best=ob; bi=oi; }
  }
  __shared__ float rb[4]; __shared__ int ri[4];
  if((t&63)==0){ rb[t>>6]=best; ri[t>>6]=bi; }
  __syncthreads();
  if(t==0){
    for(int wv=1;wv<4;wv++){ if(rb[wv]<best || (rb[wv]==best && ri[wv]<bi)){ best=rb[wv]; bi=ri[wv]; } }
    inds[nf]=bi;
  }
}

__global__ __launch_bounds__(256) void embed_k(const int* __restrict__ iarr,
    const int* __restrict__ inds, const float* __restrict__ tok,
    const float* __restrict__ pos, float* __restrict__ h){
  int idx = blockIdx.x*256 + threadIdx.x;
  int c = idx & 511; int row = idx >> 9;
  int b = row/SEQL, l = row - b*SEQL;
  int tk = tok_at(iarr, inds, b, l);
  h[idx] = tok[tk*DIMM + c] + pos[l*DIMM + c];
}

// ---------------- layernorm: f32 in, bf16 out -------------------------------
__global__ __launch_bounds__(256) void ln_k(const float* __restrict__ in,
    const float* __restrict__ g, const float* __restrict__ bb,
    unsigned short* __restrict__ out){
  int row = blockIdx.x; int t = threadIdx.x;
  const float* xr = in + (size_t)row*DIMM;
  float x0 = xr[t], x1 = xr[t+256];
  float s = x0+x1, ss = x0*x0 + x1*x1;
  #pragma unroll
  for(int off=32;off;off>>=1){ s += __shfl_xor(s,off); ss += __shfl_xor(ss,off); }
  __shared__ float bs[4], bss[4];
  if((t&63)==0){ bs[t>>6]=s; bss[t>>6]=ss; }
  __syncthreads();
  s = bs[0]+bs[1]+bs[2]+bs[3]; ss = bss[0]+bss[1]+bss[2]+bss[3];
  float mu = s*(1.f/512.f);
  float var = ss*(1.f/512.f) - mu*mu;
  float inv = rsqrtf(var + 1e-5f);
  out[(size_t)row*DIMM+t]     = f2bf((x0-mu)*inv*g[t]     + bb[t]);
  out[(size_t)row*DIMM+t+256] = f2bf((x1-mu)*inv*g[t+256] + bb[t+256]);
}

// ---------------- per-layer weight prep (transpose + bf16) ------------------
__global__ __launch_bounds__(256) void wprep_k(const float* __restrict__ wq_l,
    const float* __restrict__ wk_l, const float* __restrict__ wv_l,
    const float* __restrict__ wo_l, const float* __restrict__ ff1_l,
    const float* __restrict__ ff2_l,
    unsigned short* __restrict__ wqkvt, unsigned short* __restrict__ wot,
    unsigned short* __restrict__ ff1t, unsigned short* __restrict__ ff2t,
    unsigned int* __restrict__ gmaxbits){
  int bid = blockIdx.x;
  int t = threadIdx.x;
  if(bid==0 && t==0) gmaxbits[0] = 0u;
  const float* src; unsigned short* dst;
  int n0, k0, srcN, dstK;
  if(bid < 768){
    int nt = bid % 48, kt = bid / 48;
    n0 = nt*32; k0 = kt*32;
    int seg = n0 >> 9;
    src = (seg==0 ? wq_l : seg==1 ? wk_l : wv_l);
    dst = wqkvt; srcN = 512; dstK = 512;
  } else if(bid < 1024){
    int b2 = bid-768; int nt = b2 % 16, kt = b2 / 16;
    n0 = nt*32; k0 = kt*32; src = wo_l; dst = wot; srcN = 512; dstK = 512;
  } else if(bid < 2048){
    int b2 = bid-1024; int nt = b2 % 64, kt = b2 / 64;
    n0 = nt*32; k0 = kt*32; src = ff1_l; dst = ff1t; srcN = 2048; dstK = 512;
  } else {
    int b2 = bid-2048; int nt = b2 % 16, kt = b2 / 16;
    n0 = nt*32; k0 = kt*32; src = ff2_l; dst = ff2t; srcN = 512; dstK = 2048;
  }
  int srcCol0 = (bid < 768) ? (n0 & 0x1ff) : n0;
  __shared__ float tile[32][33];
  int c = t&31, r = t>>5;
  #pragma unroll
  for(int j=0;j<4;j++)
    tile[r+8*j][c] = src[(size_t)(k0+r+8*j)*srcN + srcCol0 + c];
  __syncthreads();
  #pragma unroll
  for(int j=0;j<4;j++){
    int n = n0 + r + 8*j;
    dst[(size_t)n*dstK + k0 + c] = f2bf(tile[c][r+8*j]);
  }
}

// generic transpose for logits weight [512][523] -> [523][512]
__global__ __launch_bounds__(256) void wconv_k(const float* __restrict__ W,
    unsigned short* __restrict__ dst, int K, int N){
  __shared__ float tile[32][33];
  int k0 = blockIdx.y*32, n0 = blockIdx.x*32;
  int t = threadIdx.x; int c = t&31, r = t>>5;
  #pragma unroll
  for(int j=0;j<4;j++){
    int n = n0+c;
    tile[r+8*j][c] = (n<N) ? W[(size_t)(k0+r+8*j)*N + n] : 0.f;
  }
  __syncthreads();
  #pragma unroll
  for(int j=0;j<4;j++){
    int n = n0 + r + 8*j;
    if(n<N) dst[(size_t)n*K + k0 + c] = f2bf(tile[c][r+8*j]);
  }
}

// ---------------- MFMA GEMM 64x64: C[M,N] = A[M,K]bf16 @ Bt[N,K]bf16^T ------
// MODE 0: f32 out (+optional bias); MODE 1: bf16 qkv head-major;
// MODE 3: f32 += (bias); MODE 4: bf16 out bias+gelu
template<int MODE>
__global__ __launch_bounds__(256) void mgemm_k(const unsigned short* __restrict__ A,
    const unsigned short* __restrict__ Bt, const float* __restrict__ bias,
    float* __restrict__ Cf, unsigned short* __restrict__ Cb,
    int M, int N, int K){
  __shared__ unsigned short As[4096];
  __shared__ unsigned short Bs[4096];
  int t = threadIdx.x;
  const int m0 = blockIdx.y*64, n0 = blockIdx.x*64;
  int w = t>>6, l = t&63;
  int wr = w>>1, wc = w&1;
  f32x4 acc[2][2] = {};
  int srow = t>>2, sp = (t&3)*2;
  int arow = m0 + srow, brow = n0 + srow;
  bool aok = arow < M, bok = brow < N;
  const us8* Ap = (const us8*)(A + (size_t)arow*K + sp*8);
  const us8* Bp = (const us8*)(Bt + (size_t)brow*K + sp*8);
  unsigned short* Aw0 = As + srow*64 + (((sp  )^(srow&7))<<3);
  unsigned short* Aw1 = As + srow*64 + (((sp+1)^(srow&7))<<3);
  unsigned short* Bw0 = Bs + srow*64 + (((sp  )^(srow&7))<<3);
  unsigned short* Bw1 = Bs + srow*64 + (((sp+1)^(srow&7))<<3);
  for(int k0=0; k0<K; k0+=64){
    us8 a0={}, a1={}, b0={}, b1={};
    if(aok){ a0 = Ap[0]; a1 = Ap[1]; }
    if(bok){ b0 = Bp[0]; b1 = Bp[1]; }
    Ap += 8; Bp += 8;
    __syncthreads();
    *(us8*)Aw0 = a0; *(us8*)Aw1 = a1;
    *(us8*)Bw0 = b0; *(us8*)Bw1 = b1;
    __syncthreads();
    #pragma unroll
    for(int kk=0;kk<2;kk++){
      short8 af[2], bf[2];
      #pragma unroll
      for(int m=0;m<2;m++){
        int row = wr*32 + m*16 + (l&15);
        int slot = kk*4 + (l>>4);
        af[m] = *(const short8*)(As + row*64 + ((slot^(row&7))<<3));
      }
      #pragma unroll
      for(int n=0;n<2;n++){
        int col = wc*32 + n*16 + (l&15);
        int slot = kk*4 + (l>>4);
        bf[n] = *(const short8*)(Bs + col*64 + ((slot^(col&7))<<3));
      }
      #pragma unroll
      for(int m=0;m<2;m++)
        #pragma unroll
        for(int n=0;n<2;n++)
          acc[m][n] = __builtin_amdgcn_mfma_f32_16x16x32_bf16(af[m], bf[n], acc[m][n], 0, 0, 0);
    }
  }
  #pragma unroll
  for(int m=0;m<2;m++){
    #pragma unroll
    for(int n=0;n<2;n++){
      int col = n0 + wc*32 + n*16 + (l&15);
      #pragma unroll
      for(int i=0;i<4;i++){
        int row = m0 + wr*32 + m*16 + (l>>4)*4 + i;
        if(row < M && col < N){
          float v = acc[m][n][i];
          if(MODE==0){
            if(bias) v += bias[col];
            Cf[(size_t)row*N+col] = v;
          } else if(MODE==1){
            v *= (col < 1024) ? 0.35355339059327378f : 1.0f;
            int seg = col>>9, d0 = col&511;
            int hh = d0>>6, d = d0&63;
            int bb = row/SEQL, ll = row - bb*SEQL;
            Cb[(size_t)seg*QSEG + (((size_t)(bb*NHEADS+hh))*SEQL + ll)*64 + d] = f2bf(v);
          } else if(MODE==3){
            v += bias[col];
            Cf[(size_t)row*N+col] += v;
          } else {
            v += bias[col];
            v = gelu_f(v);
            Cb[(size_t)row*N+col] = f2bf(v);
          }
        }
      }
    }
  }
}

// ---------------- MFMA GEMM 32x64 (M%32==0, N%64==0, K%64==0) ---------------
// ACC=1: Cf += acc + bias;  ACC=0: Cf = acc + bias
template<int ACC>
__global__ __launch_bounds__(256) void mgemm32_k(const unsigned short* __restrict__ A,
    const unsigned short* __restrict__ Bt, const float* __restrict__ bias,
    float* __restrict__ Cf, int N, int K){
  __shared__ unsigned short As[2048];
  __shared__ unsigned short Bs[4096];
  int t = threadIdx.x;
  const int m0 = blockIdx.y*32, n0 = blockIdx.x*64;
  int w = t>>6, l = t&63;
  int wm = w&1, wn2 = w>>1;
  f32x4 acc[2] = {};
  int srowA = t>>3, spA = t&7;
  int srowB = t>>2, spB = (t&3)*2;
  const us8* Ap = (const us8*)(A + (size_t)(m0+srowA)*K + spA*8);
  const us8* Bp = (const us8*)(Bt + (size_t)(n0+srowB)*K + spB*8);
  unsigned short* Aw  = As + srowA*64 + ((spA^(srowA&7))<<3);
  unsigned short* Bw0 = Bs + srowB*64 + (((spB  )^(srowB&7))<<3);
  unsigned short* Bw1 = Bs + srowB*64 + (((spB+1)^(srowB&7))<<3);
  for(int k0=0; k0<K; k0+=64){
    us8 a0 = Ap[0];
    us8 b0 = Bp[0], b1 = Bp[1];
    Ap += 8; Bp += 8;
    __syncthreads();
    *(us8*)Aw = a0;
    *(us8*)Bw0 = b0; *(us8*)Bw1 = b1;
    __syncthreads();
    #pragma unroll
    for(int kk=0;kk<2;kk++){
      int arow = wm*16 + (l&15);
      int slot = kk*4 + (l>>4);
      short8 af = *(const short8*)(As + arow*64 + ((slot^(arow&7))<<3));
      #pragma unroll
      for(int n=0;n<2;n++){
        int col = (wn2*2+n)*16 + (l&15);
        short8 bf = *(const short8*)(Bs + col*64 + ((slot^(col&7))<<3));
        acc[n] = __builtin_amdgcn_mfma_f32_16x16x32_bf16(af, bf, acc[n], 0, 0, 0);
      }
    }
  }
  #pragma unroll
  for(int n=0;n<2;n++){
    int col = n0 + (wn2*2+n)*16 + (l&15);
    float bv = bias[col];
    #pragma unroll
    for(int i=0;i<4;i++){
      int row = m0 + wm*16 + (l>>4)*4 + i;
      if(ACC) Cf[(size_t)row*N+col] += acc[n][i] + bv;
      else    Cf[(size_t)row*N+col]  = acc[n][i] + bv;
    }
  }
}

// ---------------- fused feature-map kernels ---------------------------------
__global__ __launch_bounds__(256) void featA_k(const unsigned short* __restrict__ qn,
    const unsigned short* __restrict__ kn, const unsigned short* __restrict__ projl,
    unsigned short* __restrict__ qp, unsigned int* __restrict__ gmaxbits){
  int z = blockIdx.y;
  const unsigned short* dn = z ? kn : qn;
  __shared__ float uni[32*264];
  __shared__ unsigned short dns[2048];
  unsigned short* ps = (unsigned short*)uni;
  int t = threadIdx.x;
  size_t R0 = (size_t)blockIdx.x*32;
  {
    int row = t>>3, sl = t&7;
    us8 u = *(const us8*)(dn + (R0+row)*64 + sl*8);
    *(us8*)(dns + row*64 + ((sl^(row&7))<<3)) = u;
  }
  #pragma unroll
  for(int j=0;j<8;j++){
    int ridx = t + 256*j;
    int row = ridx>>3, sl = ridx&7;
    us8 u = *(const us8*)(projl + row*64 + sl*8);
    *(us8*)(ps + row*64 + ((sl^(row&7))<<3)) = u;
  }
  __syncthreads();
  int w = t>>6, l = t&63;
  int rt = w&1, cb = (w>>1)*8;
  f32x4 acc[8] = {};
  #pragma unroll
  for(int kk=0;kk<2;kk++){
    int ar = rt*16 + (l&15);
    int slot = kk*4 + (l>>4);
    short8 a = *(const short8*)(dns + ar*64 + ((slot^(ar&7))<<3));
    #pragma unroll
    for(int ct=0;ct<8;ct++){
      int br = (cb+ct)*16 + (l&15);
      short8 b = *(const short8*)(ps + br*64 + ((slot^(br&7))<<3));
      acc[ct] = __builtin_amdgcn_mfma_f32_16x16x32_bf16(a, b, acc[ct], 0, 0, 0);
    }
  }
  __syncthreads();
  #pragma unroll
  for(int ct=0;ct<8;ct++){
    int col = (cb+ct)*16 + (l&15);
    #pragma unroll
    for(int i=0;i<4;i++){
      int row = rt*16 + (l>>4)*4 + i;
      uni[row*264 + col] = acc[ct][i];
    }
  }
  __syncthreads();
  int r = t>>3, sub = t&7;
  float* rowp = uni + r*264 + sub*32;
  f32x4 v[8];
  #pragma unroll
  for(int jj=0;jj<8;jj++) v[jj] = *(const f32x4*)(rowp + jj*4);
  float m = -3.0e38f;
  #pragma unroll
  for(int jj=0;jj<8;jj++)
    #pragma unroll
    for(int i=0;i<4;i++) m = fmaxf(m, v[jj][i]);
  m = fmaxf(m, __shfl_xor(m,1));
  m = fmaxf(m, __shfl_xor(m,2));
  m = fmaxf(m, __shfl_xor(m,4));
  if(z==0){
    us8 dvu = *(const us8*)(dns + r*64 + ((sub^(r&7))<<3));
    float s2 = 0.f;
    #pragma unroll
    for(int j=0;j<8;j++){ float xx = bf2f(dvu[j]); s2 += xx*xx; }
    s2 += __shfl_xor(s2,1); s2 += __shfl_xor(s2,2); s2 += __shfl_xor(s2,4);
    float ds = 0.5f*s2;
    unsigned short* op = qp + (R0+r)*256 + sub*32;
    #pragma unroll
    for(int jj=0;jj<8;jj++){
      us4 u4;
      #pragma unroll
      for(int i=0;i<4;i++) u4[i] = f2bf(expf(v[jj][i] - ds - m)*0.0625f + 1e-4f);
      *(us4*)(op + jj*4) = u4;
    }
  } else {
    float bm = m;
    bm = fmaxf(bm, __shfl_xor(bm,8));
    bm = fmaxf(bm, __shfl_xor(bm,16));
    bm = fmaxf(bm, __shfl_xor(bm,32));
    __shared__ float wm[4];
    if(l==0) wm[w] = bm;
    __syncthreads();
    if(t==0){
      float g = fmaxf(fmaxf(wm[0],wm[1]),fmaxf(wm[2],wm[3]));
      atomicMax(gmaxbits, enc_max(g));
    }
  }
}

__global__ __launch_bounds__(256) void featB_k(const unsigned short* __restrict__ kn,
    const unsigned short* __restrict__ projl, const unsigned int* __restrict__ gmaxbits,
    unsigned short* __restrict__ kp){
  __shared__ float uni[32*264];
  __shared__ unsigned short dns[2048];
  unsigned short* ps = (unsigned short*)uni;
  int t = threadIdx.x;
  size_t R0 = (size_t)blockIdx.x*32;
  {
    int row = t>>3, sl = t&7;
    us8 u = *(const us8*)(kn + (R0+row)*64 + sl*8);
    *(us8*)(dns + row*64 + ((sl^(row&7))<<3)) = u;
  }
  #pragma unroll
  for(int j=0;j<8;j++){
    int ridx = t + 256*j;
    int row = ridx>>3, sl = ridx&7;
    us8 u = *(const us8*)(projl + row*64 + sl*8);
    *(us8*)(ps + row*64 + ((sl^(row&7))<<3)) = u;
  }
  __syncthreads();
  int w = t>>6, l = t&63;
  int rt = w&1, cb = (w>>1)*8;
  f32x4 acc[8] = {};
  #pragma unroll
  for(int kk=0;kk<2;kk++){
    int ar = rt*16 + (l&15);
    int slot = kk*4 + (l>>4);
    short8 a = *(const short8*)(dns + ar*64 + ((slot^(ar&7))<<3));
    #pragma unroll
    for(int ct=0;ct<8;ct++){
      int br = (cb+ct)*16 + (l&15);
      short8 b = *(const short8*)(ps + br*64 + ((slot^(br&7))<<3));
      acc[ct] = __builtin_amdgcn_mfma_f32_16x16x32_bf16(a, b, acc[ct], 0, 0, 0);
    }
  }
  __syncthreads();
  #pragma unroll
  for(int ct=0;ct<8;ct++){
    int col = (cb+ct)*16 + (l&15);
    #pragma unroll
    for(int i=0;i<4;i++){
      int row = rt*16 + (l>>4)*4 + i;
      uni[row*264 + col] = acc[ct][i];
    }
  }
  __syncthreads();
  float g = dec_max(gmaxbits[0]);
  int r = t>>3, sub = t&7;
  us8 dvu = *(const us8*)(dns + r*64 + ((sub^(r&7))<<3));
  float s2 = 0.f;
  #pragma unroll
  for(int j=0;j<8;j++){ float xx = bf2f(dvu[j]); s2 += xx*xx; }
  s2 += __shfl_xor(s2,1); s2 += __shfl_xor(s2,2); s2 += __shfl_xor(s2,4);
  float ds = 0.5f*s2;
  float* rowp = uni + r*264 + sub*32;
  unsigned short* op = kp + (R0+r)*256 + sub*32;
  #pragma unroll
  for(int jj=0;jj<8;jj++){
    f32x4 v = *(const f32x4*)(rowp + jj*4);
    us4 u4;
    #pragma unroll
    for(int i=0;i<4;i++) u4[i] = f2bf(expf(v[i] - ds - g)*0.0625f + 1e-4f);
    *(us4*)(op + jj*4) = u4;
  }
}

// ---------------- quadratic causal attention --------------------------------
__global__ __launch_bounds__(256) void attn_k(const unsigned short* __restrict__ qp,
    const unsigned short* __restrict__ kp, const unsigned short* __restrict__ vn,
    unsigned short* __restrict__ ob){
  int qt = blockIdx.x, bh = blockIdx.y;
  int b = bh>>3, hh = bh&7;
  __shared__ unsigned short qs[32*256];
  __shared__ unsigned short ks[32*256];
  __shared__ float vs[32][68];
  __shared__ float Ss[32][33];
  __shared__ float dens[2][32];
  int t = threadIdx.x;
  int w = t>>6, l = t&63;
  int qh = w>>1, kh = w&1;
  {
    int rr = t>>3, s0 = (t&7)*4;
    int gr = qt*32 + rr;
    const us8* src = (const us8*)(qp + ((size_t)bh*SEQL + (gr<SEQL?gr:0))*256 + s0*8);
    #pragma unroll
    for(int j=0;j<4;j++){
      us8 u = {};
      if(gr<SEQL) u = src[j];
      *(us8*)(qs + rr*256 + (((s0+j)^(rr&7))<<3)) = u;
    }
  }
  if(t<64) dens[t>>5][t&31] = 0.f;
  float o[8] = {0.f,0.f,0.f,0.f,0.f,0.f,0.f,0.f};
  int orow = t>>3, od = (t&7)*8;
  for(int kt=0; kt<=qt; kt++){
    __syncthreads();
    {
      int rr = t>>3, s0 = (t&7)*4;
      int gk = kt*32 + rr;
      const us8* src = (const us8*)(kp + ((size_t)bh*SEQL + (gk<SEQL?gk:0))*256 + s0*8);
      #pragma unroll
      for(int j=0;j<4;j++){
        us8 u = {};
        if(gk<SEQL) u = src[j];
        *(us8*)(ks + rr*256 + (((s0+j)^(rr&7))<<3)) = u;
      }
      const us8* vsrc = (const us8*)(vn + ((size_t)bh*SEQL + (gk<SEQL?gk:0))*64 + od);
      us8 uv = {};
      if(gk<SEQL) uv = vsrc[0];
      #pragma unroll
      for(int i=0;i<8;i++) vs[rr][od+i] = bf2f(uv[i]);
    }
    __syncthreads();
    f32x4 sacc = {};
    #pragma unroll
    for(int kk=0;kk<8;kk++){
      int ar = qh*16 + (l&15); int slot = kk*4 + (l>>4);
      short8 a = *(const short8*)(qs + ar*256 + ((slot^(ar&7))<<3));
      int br = kh*16 + (l&15);
      short8 bb2 = *(const short8*)(ks + br*256 + ((slot^(br&7))<<3));
      sacc = __builtin_amdgcn_mfma_f32_16x16x32_bf16(a, bb2, sacc, 0, 0, 0);
    }
    int scol = kh*16 + (l&15);
    int gcol = kt*32 + scol;
    float dp[4];
    #pragma unroll
    for(int i=0;i<4;i++){
      int sr = qh*16 + (l>>4)*4 + i;
      int grw = qt*32 + sr;
      float v2 = sacc[i];
      if(gcol > grw) v2 = 0.f;
      Ss[sr][scol] = v2;
      dp[i] = v2;
    }
    #pragma unroll
    for(int off=1;off<16;off<<=1)
      #pragma unroll
      for(int i=0;i<4;i++) dp[i] += __shfl_xor(dp[i], off);
    if((l&15)==0){
      #pragma unroll
      for(int i=0;i<4;i++) dens[kh][qh*16 + (l>>4)*4 + i] += dp[i];
    }
    __syncthreads();
    #pragma unroll
    for(int k2=0;k2<32;k2++){
      float s = Ss[orow][k2];
      #pragma unroll
      for(int j=0;j<8;j++) o[j] += s*vs[k2][od+j];
    }
  }
  __syncthreads();
  int gr = qt*32 + orow;
  if(gr < SEQL){
    float inv = 1.f/(dens[0][orow] + dens[1][orow]);
    us8 u;
    #pragma unroll
    for(int j=0;j<8;j++) u[j] = f2bf(o[j]*inv);
    *(us8*)(ob + ((size_t)(b*SEQL+gr))*DIMM + hh*64 + od) = u;
  }
}

// ---------------- loss ------------------------------------------------------
__global__ __launch_bounds__(256) void loss_k(const float* __restrict__ logits,
    const int* __restrict__ iarr, const int* __restrict__ inds,
    float* __restrict__ rnll){
  int row = blockIdx.x; int t = threadIdx.x;
  const float* lr = logits + (size_t)row*VSZ;
  float m = -3.0e38f;
  for(int j=t;j<VSZ;j+=256) m = fmaxf(m, lr[j]);
  m = blk_max(m);
  float s = 0.f;
  for(int j=t;j<VSZ;j+=256) s += expf(lr[j]-m);
  s = blk_sum(s);
  if(t==0){
    int b = row/SEQL, l = row - b*SEQL;
    int tgt = tok_at(iarr, inds, b, l+1);
    rnll[row] = (m + logf(s)) - lr[tgt];
  }
}

__global__ __launch_bounds__(256) void fin_k(const float* __restrict__ rnll,
    float* __restrict__ out){
  int t = threadIdx.x;
  float s = 0.f;
  for(int i=t;i<NROWS;i+=256) s += rnll[i];
  s = blk_sum(s);
  if(t==0) out[0] = s/(float)NROWS;
}

// ---------------------------------------------------------------------------
extern "C" void kernel_launch(void* const* d_in, const int* in_sizes, int n_in,
                              void* d_out, int out_size, void* d_ws, size_t ws_size,
                              hipStream_t stream){
  (void)in_sizes; (void)n_in; (void)out_size; (void)ws_size;
  const float* x        = (const float*)d_in[0];
  const float* xn       = (const float*)d_in[1];
  const int*   iarr     = (const int*)  d_in[2];
  const float* conv1_w  = (const float*)d_in[3];
  const float* conv1_b  = (const float*)d_in[4];
  const float* conv2_w  = (const float*)d_in[5];
  const float* conv2_b  = (const float*)d_in[6];
  const float* codebook = (const float*)d_in[7];
  const float* proj     = (const float*)d_in[8];
  const float* tok_emb  = (const float*)d_in[9];
  const float* pos_emb  = (const float*)d_in[10];
  const float* ln1_g    = (const float*)d_in[11];
  const float* ln1_b    = (const float*)d_in[12];
  const float* wq       = (const float*)d_in[13];
  const float* wk       = (const float*)d_in[14];
  const float* wv       = (const float*)d_in[15];
  const float* wo       = (const float*)d_in[16];
  const float* bo       = (const float*)d_in[17];
  const float* ln2_g    = (const float*)d_in[18];
  const float* ln2_b    = (const float*)d_in[19];
  const float* ff1_w    = (const float*)d_in[20];
  const float* ff1_b    = (const float*)d_in[21];
  const float* ff2_w    = (const float*)d_in[22];
  const float* ff2_b    = (const float*)d_in[23];
  const float* lnf_g    = (const float*)d_in[24];
  const float* lnf_b    = (const float*)d_in[25];
  const float* logits_w = (const float*)d_in[26];
  const float* logits_b = (const float*)d_in[27];

  float* wsf = (float*)d_ws;
  size_t off = 0;
  unsigned short* qp_bf = (unsigned short*)(wsf + off); off += 2129920;
  unsigned short* kp_bf = (unsigned short*)(wsf + off); off += 2129920;
  float* h = wsf + off; off += 1064960;
  unsigned short* x1b = (unsigned short*)(wsf + off); off += 532480;
  unsigned short* qkvb = (unsigned short*)(wsf + off); off += 1597440;
  unsigned short* ob  = (unsigned short*)(wsf + off); off += 532480;
  unsigned short* projb = (unsigned short*)(wsf + off); off += 49152;
  unsigned short* wqkvt = (unsigned short*)(wsf + off); off += 393216;
  unsigned short* wot   = (unsigned short*)(wsf + off); off += 131072;
  unsigned short* ff1t  = (unsigned short*)(wsf + off); off += 524288;
  unsigned short* ff2t  = (unsigned short*)(wsf + off); off += 524288;
  unsigned short* logt  = (unsigned short*)(wsf + off); off += 133888;
  unsigned short* ffmid = (unsigned short*)(wsf + off); off += 2129920;
  float* logits = wsf + off; off += 1087840;
  int* inds = (int*)(wsf + off); off += 2048;
  unsigned int* gmaxbits = (unsigned int*)(wsf + off); off += 64;
  float* rnll = wsf + off; off += 2112;

  // pre-loop aliases into regions that are dead before the layer loop
  float* c1 = logits;                                  // 524288 f32
  unsigned short* icol = ffmid;                        // 2048*2048 us
  float* zbuf = (float*)qp_bf;                         // 2048*64 f32
  unsigned short* cw2b = (unsigned short*)kp_bf;       // 64*2048 us

  unsigned short* qnb = qkvb;
  unsigned short* knb = qkvb + QSEG;
  unsigned short* vnb = qkvb + 2*QSEG;

  conv1_k<<<2048,256,0,stream>>>(x, xn, conv1_w, conv1_b, c1);
  cvt8_k<<<64,256,0,stream>>>(conv2_w, cw2b, 16384);          // 64x2048 weights
  im2col_k<<<2048,256,0,stream>>>(c1, icol);
  mgemm32_k<0><<<dim3(1,64),256,0,stream>>>(icol, cw2b, conv2_b, zbuf, 64, 2048);
  vq_k<<<2048,256,0,stream>>>(zbuf, codebook, inds);
  embed_k<<<(NROWS*DIMM)/256,256,0,stream>>>(iarr, inds, tok_emb, pos_emb, h);
  cvt8_k<<<48,256,0,stream>>>(proj, projb, 12288);            // 6*256*64 proj
  wconv_k<<<dim3(17,16),256,0,stream>>>(logits_w, logt, 512, 523);

  for(int l=0;l<6;l++){
    wprep_k<<<3072,256,0,stream>>>(wq + (size_t)l*262144, wk + (size_t)l*262144,
        wv + (size_t)l*262144, wo + (size_t)l*262144,
        ff1_w + (size_t)l*1048576, ff2_w + (size_t)l*1048576,
        wqkvt, wot, ff1t, ff2t, gmaxbits);
    ln_k<<<NROWS,256,0,stream>>>(h, ln1_g+l*DIMM, ln1_b+l*DIMM, x1b);
    mgemm_k<1><<<dim3(24,33),256,0,stream>>>(x1b, wqkvt, nullptr, nullptr, qkvb, NROWS, 1536, DIMM);
    featA_k<<<dim3(520,2),256,0,stream>>>(qnb, knb, projb + l*16384, qp_bf, gmaxbits);
    featB_k<<<520,256,0,stream>>>(knb, projb + l*16384, gmaxbits, kp_bf);
    attn_k<<<dim3(5,NBH),256,0,stream>>>(qp_bf, kp_bf, vnb, ob);
    mgemm32_k<1><<<dim3(8,65),256,0,stream>>>(ob, wot, bo+l*DIMM, h, DIMM, DIMM);
    ln_k<<<NROWS,256,0,stream>>>(h, ln2_g+l*DIMM, ln2_b+l*DIMM, x1b);
    mgemm_k<4><<<dim3(32,33),256,0,stream>>>(x1b, ff1t, ff1_b+l*2048, nullptr, ffmid, NROWS, 2048, DIMM);
    mgemm32_k<1><<<dim3(8,65),256,0,stream>>>(ffmid, ff2t, ff2_b+l*DIMM, h, DIMM, 2048);
  }

  ln_k<<<NROWS,256,0,stream>>>(h, lnf_g, lnf_b, x1b);
  mgemm_k<0><<<dim3(9,33),256,0,stream>>>(x1b, logt, logits_b, logits, nullptr, NROWS, VSZ, DIMM);
  loss_k<<<NROWS,256,0,stream>>>(logits, iarr, inds, rnll);
  fin_k<<<1,256,0,stream>>>(rnll, (float*)d_out);
}

// Round 6
// 749.353 us; speedup vs baseline: 8.0919x; 1.0512x over previous
//
#include <hip/hip_runtime.h>

#define SEQL 130
#define LSEQ 131
#define DIMM 512
#define NHEADS 8
#define MF 256
#define VSZ 523
#define NROWS (16*SEQL)          // 2080
#define NBH (16*NHEADS)          // 128
#define NBHL (NBH*SEQL)          // 16640
#define QSEG 1064960             // us elements per q/k/v segment
#define WLAYER 3145728           // us elements of weights per layer

typedef __attribute__((ext_vector_type(8))) short short8;
typedef __attribute__((ext_vector_type(8))) unsigned short us8;
typedef __attribute__((ext_vector_type(4))) unsigned short us4;
typedef __attribute__((ext_vector_type(4))) float f32x4;

__device__ __forceinline__ unsigned short f2bf(float f){
  unsigned int u = __float_as_uint(f);
  u += 0x7fffu + ((u>>16)&1u);
  return (unsigned short)(u>>16);
}
__device__ __forceinline__ float bf2f(unsigned short h){
  return __uint_as_float(((unsigned int)h)<<16);
}
__device__ __forceinline__ float gelu_f(float x){
  float x3 = x*x*x;
  return 0.5f*x*(1.f+tanhf(0.7978845608028654f*(x+0.044715f*x3)));
}
__device__ __forceinline__ unsigned enc_max(float f){
  unsigned u = __float_as_uint(f);
  return (u & 0x80000000u) ? ~u : (u | 0x80000000u);
}
__device__ __forceinline__ float dec_max(unsigned k){
  unsigned u = (k>>31) ? (k & 0x7fffffffu) : ~k;
  return __uint_as_float(u);
}
// async global->LDS, 16B per lane; lds must be wave-uniform, 16B aligned
__device__ __forceinline__ void gload16(const void* g, void* lds){
  __builtin_amdgcn_global_load_lds(
      (const __attribute__((address_space(1))) void*)g,
      (__attribute__((address_space(3))) void*)lds, 16, 0, 0);
}
__device__ __forceinline__ float blk_sum(float v){
  #pragma unroll
  for(int off=32;off;off>>=1) v += __shfl_xor(v,off);
  __shared__ float tmp_s[4];
  int t=threadIdx.x;
  if((t&63)==0) tmp_s[t>>6]=v;
  __syncthreads();
  v = tmp_s[0]+tmp_s[1]+tmp_s[2]+tmp_s[3];
  __syncthreads();
  return v;
}
__device__ __forceinline__ float blk_max(float v){
  #pragma unroll
  for(int off=32;off;off>>=1) v = fmaxf(v,__shfl_xor(v,off));
  __shared__ float tmp_m[4];
  int t=threadIdx.x;
  if((t&63)==0) tmp_m[t>>6]=v;
  __syncthreads();
  v = fmaxf(fmaxf(tmp_m[0],tmp_m[1]),fmaxf(tmp_m[2],tmp_m[3]));
  __syncthreads();
  return v;
}
__device__ __forceinline__ int tok_at(const int* __restrict__ iarr,
    const int* __restrict__ inds, int b, int p){
  if(p<3)  return iarr[b*3+p];
  if(p<67) return inds[(16+b)*64 + (p-3)];
  return inds[b*64 + (p-67)];
}

// ---------------- conv1: (32,1,16,16,16) -> relu (32,32,8,8,8), stride2 pad1
__global__ __launch_bounds__(256) void conv1_k(const float* __restrict__ x,
    const float* __restrict__ xn, const float* __restrict__ w,
    const float* __restrict__ bias, float* __restrict__ out){
  int idx = blockIdx.x*256 + threadIdx.x;
  if(idx >= 32*32*8*8*8) return;
  int ow = idx & 7, oh = (idx>>3)&7, od = (idx>>6)&7, oc = (idx>>9)&31, n = idx>>14;
  const float* xp = (n<16) ? (x + n*4096) : (xn + (n-16)*4096);
  const float* wp = w + oc*64;
  float acc = bias[oc];
  #pragma unroll
  for(int kd=0;kd<4;kd++){ int id = od*2-1+kd; if((unsigned)id>=16u) continue;
    #pragma unroll
    for(int kh=0;kh<4;kh++){ int ih = oh*2-1+kh; if((unsigned)ih>=16u) continue;
      #pragma unroll
      for(int kw=0;kw<4;kw++){ int iw = ow*2-1+kw; if((unsigned)iw>=16u) continue;
        acc += xp[(id*16+ih)*16+iw]*wp[(kd*4+kh)*4+kw];
      }}}
  out[idx] = fmaxf(acc,0.f);
}

// ---------------- generic f32 -> bf16 vector convert ------------------------
__global__ __launch_bounds__(256) void cvt8_k(const float* __restrict__ src,
    unsigned short* __restrict__ dst, int n8){
  int i = blockIdx.x*256 + threadIdx.x;
  if(i >= n8) return;
  const float* s = src + (size_t)i*8;
  us8 u;
  #pragma unroll
  for(int j=0;j<8;j++) u[j] = f2bf(s[j]);
  *(us8*)(dst + (size_t)i*8) = u;
}

// ---------------- conv2 im2col: c1 (32,32,8,8,8) -> icol[2048][2048] bf16 ---
__global__ __launch_bounds__(256) void im2col_k(const float* __restrict__ c1,
    unsigned short* __restrict__ icol){
  int tid = blockIdx.x*256 + threadIdx.x;
  size_t e0 = (size_t)tid*8;
  int r = (int)(e0 >> 11);
  int k0 = (int)(e0 & 2047);
  int n = r>>6, od = (r>>4)&3, oh = (r>>2)&3, ow = r&3;
  int ic = k0>>6, kd = (k0>>4)&3, kh0 = (k0>>2)&3;
  int id = od*2 - 1 + kd;
  us8 u = {};
  if((unsigned)id < 8u){
    const float* base = c1 + (size_t)(n*32+ic)*512 + id*64;
    #pragma unroll
    for(int j=0;j<8;j++){
      int kh = kh0 + (j>>2), kw = j&3;
      int ih = oh*2 - 1 + kh, iw = ow*2 - 1 + kw;
      float v = 0.f;
      if((unsigned)ih < 8u && (unsigned)iw < 8u) v = base[ih*8 + iw];
      u[j] = f2bf(v);
    }
  }
  *(us8*)(icol + e0) = u;
}

// ---------------- VQ argmin (z[row][64] f32, contiguous rows) ---------------
__global__ __launch_bounds__(256) void vq_k(const float* __restrict__ z,
    const float* __restrict__ cb, int* __restrict__ inds){
  int nf = blockIdx.x;
  __shared__ float zs[64];
  int t = threadIdx.x;
  if(t<64) zs[t] = z[(size_t)nf*64 + t];
  __syncthreads();
  float best = 3.0e38f; int bi = 0;
  for(int j=t; j<512; j+=256){
    const float* cr = cb + j*64;
    float dot=0.f, nn=0.f;
    #pragma unroll 8
    for(int d=0;d<64;d++){ float cv=cr[d]; dot += zs[d]*cv; nn += cv*cv; }
    float dist = nn - 2.f*dot;
    if(dist < best){ best=dist; bi=j; }
  }
  #pragma unroll
  for(int off=32;off;off>>=1){
    float ob = __shfl_down(best,off); int oi = __shfl_down(bi,off);
    if(ob<best || (ob==best && oi<bi)){ best=ob; bi=oi; }
  }
  __shared__ float rb[4]; __shared__ int ri[4];
  if((t&63)==0){ rb[t>>6]=best; ri[t>>6]=bi; }
  __syncthreads();
  if(t==0){
    for(int wv=1;wv<4;wv++){ if(rb[wv]<best || (rb[wv]==best && ri[wv]<bi)){ best=rb[wv]; bi=ri[wv]; } }
    inds[nf]=bi;
  }
}

__global__ __launch_bounds__(256) void embed_k(const int* __restrict__ iarr,
    const int* __restrict__ inds, const float* __restrict__ tok,
    const float* __restrict__ pos, float* __restrict__ h){
  int idx = blockIdx.x*256 + threadIdx.x;
  int c = idx & 511; int row = idx >> 9;
  int b = row/SEQL, l = row - b*SEQL;
  int tk = tok_at(iarr, inds, b, l);
  h[idx] = tok[tk*DIMM + c] + pos[l*DIMM + c];
}

// ---------------- layernorm: f32 in, bf16 out -------------------------------
__global__ __launch_bounds__(256) void ln_k(const float* __restrict__ in,
    const float* __restrict__ g, const float* __restrict__ bb,
    unsigned short* __restrict__ out){
  int row = blockIdx.x; int t = threadIdx.x;
  const float* xr = in + (size_t)row*DIMM;
  float x0 = xr[t], x1 = xr[t+256];
  float s = x0+x1, ss = x0*x0 + x1*x1;
  #pragma unroll
  for(int off=32;off;off>>=1){ s += __shfl_xor(s,off); ss += __shfl_xor(ss,off); }
  __shared__ float bs[4], bss[4];
  if((t&63)==0){ bs[t>>6]=s; bss[t>>6]=ss; }
  __syncthreads();
  s = bs[0]+bs[1]+bs[2]+bs[3]; ss = bss[0]+bss[1]+bss[2]+bss[3];
  float mu = s*(1.f/512.f);
  float var = ss*(1.f/512.f) - mu*mu;
  float inv = rsqrtf(var + 1e-5f);
  out[(size_t)row*DIMM+t]     = f2bf((x0-mu)*inv*g[t]     + bb[t]);
  out[(size_t)row*DIMM+t+256] = f2bf((x1-mu)*inv*g[t+256] + bb[t+256]);
}

// ---------------- all-layer weight prep (transpose + bf16), 6*3072 blocks ---
__global__ __launch_bounds__(256) void wprep_k(const float* __restrict__ wq,
    const float* __restrict__ wk, const float* __restrict__ wv,
    const float* __restrict__ wo, const float* __restrict__ ff1,
    const float* __restrict__ ff2, unsigned short* __restrict__ wall,
    unsigned int* __restrict__ gmaxbits){
  int bid0 = blockIdx.x;
  int t = threadIdx.x;
  if(bid0==0 && t<8) gmaxbits[t] = 0u;
  int lyr = bid0 / 3072;
  int bid = bid0 - lyr*3072;
  unsigned short* wl = wall + (size_t)lyr*WLAYER;
  const float* src; unsigned short* dst;
  int n0, k0, srcN, dstK;
  if(bid < 768){
    int nt = bid % 48, kt = bid / 48;
    n0 = nt*32; k0 = kt*32;
    int seg = n0 >> 9;
    src = (seg==0 ? wq : seg==1 ? wk : wv) + (size_t)lyr*262144;
    dst = wl; srcN = 512; dstK = 512;
  } else if(bid < 1024){
    int b2 = bid-768; int nt = b2 % 16, kt = b2 / 16;
    n0 = nt*32; k0 = kt*32; src = wo + (size_t)lyr*262144;
    dst = wl + 786432; srcN = 512; dstK = 512;
  } else if(bid < 2048){
    int b2 = bid-1024; int nt = b2 % 64, kt = b2 / 64;
    n0 = nt*32; k0 = kt*32; src = ff1 + (size_t)lyr*1048576;
    dst = wl + 1048576; srcN = 2048; dstK = 512;
  } else {
    int b2 = bid-2048; int nt = b2 % 16, kt = b2 / 16;
    n0 = nt*32; k0 = kt*32; src = ff2 + (size_t)lyr*1048576;
    dst = wl + 2097152; srcN = 512; dstK = 2048;
  }
  int srcCol0 = (bid < 768) ? (n0 & 0x1ff) : n0;
  __shared__ float tile[32][33];
  int c = t&31, r = t>>5;
  #pragma unroll
  for(int j=0;j<4;j++)
    tile[r+8*j][c] = src[(size_t)(k0+r+8*j)*srcN + srcCol0 + c];
  __syncthreads();
  #pragma unroll
  for(int j=0;j<4;j++){
    int n = n0 + r + 8*j;
    dst[(size_t)n*dstK + k0 + c] = f2bf(tile[c][r+8*j]);
  }
}

// generic transpose for logits weight [512][523] -> [523][512]
__global__ __launch_bounds__(256) void wconv_k(const float* __restrict__ W,
    unsigned short* __restrict__ dst, int K, int N){
  __shared__ float tile[32][33];
  int k0 = blockIdx.y*32, n0 = blockIdx.x*32;
  int t = threadIdx.x; int c = t&31, r = t>>5;
  #pragma unroll
  for(int j=0;j<4;j++){
    int n = n0+c;
    tile[r+8*j][c] = (n<N) ? W[(size_t)(k0+r+8*j)*N + n] : 0.f;
  }
  __syncthreads();
  #pragma unroll
  for(int j=0;j<4;j++){
    int n = n0 + r + 8*j;
    if(n<N) dst[(size_t)n*K + k0 + c] = f2bf(tile[c][r+8*j]);
  }
}

// ---------------- MFMA GEMM 64x64, gload_lds double-buffered ----------------
// MODE 0: f32 out (+opt bias); 1: bf16 qkv head-major; 3: f32 += bias; 4: bf16 gelu
template<int MODE>
__global__ __launch_bounds__(256) void mgemm_k(const unsigned short* __restrict__ A,
    const unsigned short* __restrict__ Bt, const float* __restrict__ bias,
    float* __restrict__ Cf, unsigned short* __restrict__ Cb,
    int M, int N, int K){
  __shared__ __attribute__((aligned(16))) unsigned short As[2][4096];
  __shared__ __attribute__((aligned(16))) unsigned short Bs[2][4096];
  int t = threadIdx.x;
  const int m0 = blockIdx.y*64, n0 = blockIdx.x*64;
  int w = t>>6, l = t&63;
  int wr = w>>1, wc = w&1;
  f32x4 acc[2][2] = {};
  auto stage = [&](unsigned short* Ad, unsigned short* Bd, int k0){
    #pragma unroll
    for(int i=0;i<2;i++){
      int c = w*2 + i;
      int r = c*8 + (l>>3);
      int gc = k0 + (((l&7) ^ (r&7))<<3);
      int ar = m0 + r; if(ar >= M) ar = 0;
      gload16(A + (size_t)ar*K + gc, Ad + c*512);
      int br = n0 + r; if(br >= N) br = 0;
      gload16(Bt + (size_t)br*K + gc, Bd + c*512);
    }
  };
  stage(As[0], Bs[0], 0);
  int NT = K>>6;
  int buf = 0;
  for(int kt=0; kt<NT; kt++){
    __syncthreads();
    if(kt+1 < NT) stage(As[buf^1], Bs[buf^1], (kt+1)*64);
    const unsigned short* Ab = &As[buf][0];
    const unsigned short* Bb = &Bs[buf][0];
    #pragma unroll
    for(int kk=0;kk<2;kk++){
      short8 af[2], bf[2];
      #pragma unroll
      for(int m=0;m<2;m++){
        int row = wr*32 + m*16 + (l&15);
        int slot = kk*4 + (l>>4);
        af[m] = *(const short8*)(Ab + row*64 + ((slot^(row&7))<<3));
      }
      #pragma unroll
      for(int n=0;n<2;n++){
        int col = wc*32 + n*16 + (l&15);
        int slot = kk*4 + (l>>4);
        bf[n] = *(const short8*)(Bb + col*64 + ((slot^(col&7))<<3));
      }
      #pragma unroll
      for(int m=0;m<2;m++)
        #pragma unroll
        for(int n=0;n<2;n++)
          acc[m][n] = __builtin_amdgcn_mfma_f32_16x16x32_bf16(af[m], bf[n], acc[m][n], 0, 0, 0);
    }
    buf ^= 1;
  }
  #pragma unroll
  for(int m=0;m<2;m++){
    #pragma unroll
    for(int n=0;n<2;n++){
      int col = n0 + wc*32 + n*16 + (l&15);
      #pragma unroll
      for(int i=0;i<4;i++){
        int row = m0 + wr*32 + m*16 + (l>>4)*4 + i;
        if(row < M && col < N){
          float v = acc[m][n][i];
          if(MODE==0){
            if(bias) v += bias[col];
            Cf[(size_t)row*N+col] = v;
          } else if(MODE==1){
            v *= (col < 1024) ? 0.35355339059327378f : 1.0f;
            int seg = col>>9, d0 = col&511;
            int hh = d0>>6, d = d0&63;
            int bb = row/SEQL, ll = row - bb*SEQL;
            Cb[(size_t)seg*QSEG + (((size_t)(bb*NHEADS+hh))*SEQL + ll)*64 + d] = f2bf(v);
          } else if(MODE==3){
            v += bias[col];
            Cf[(size_t)row*N+col] += v;
          } else {
            v += bias[col];
            v = gelu_f(v);
            Cb[(size_t)row*N+col] = f2bf(v);
          }
        }
      }
    }
  }
}

// ---------------- MFMA GEMM 32x64 (M%32==0, N%64==0, K%64==0) ---------------
template<int ACC>
__global__ __launch_bounds__(256) void mgemm32_k(const unsigned short* __restrict__ A,
    const unsigned short* __restrict__ Bt, const float* __restrict__ bias,
    float* __restrict__ Cf, int N, int K){
  __shared__ __attribute__((aligned(16))) unsigned short As[2][2048];
  __shared__ __attribute__((aligned(16))) unsigned short Bs[2][4096];
  int t = threadIdx.x;
  const int m0 = blockIdx.y*32, n0 = blockIdx.x*64;
  int w = t>>6, l = t&63;
  int wm = w&1, wn2 = w>>1;
  f32x4 acc[2] = {};
  auto stage = [&](unsigned short* Ad, unsigned short* Bd, int k0){
    {
      int c = w;
      int r = c*8 + (l>>3);
      int gc = k0 + (((l&7) ^ (r&7))<<3);
      gload16(A + (size_t)(m0+r)*K + gc, Ad + c*512);
    }
    #pragma unroll
    for(int i=0;i<2;i++){
      int c = w*2 + i;
      int r = c*8 + (l>>3);
      int gc = k0 + (((l&7) ^ (r&7))<<3);
      gload16(Bt + (size_t)(n0+r)*K + gc, Bd + c*512);
    }
  };
  stage(As[0], Bs[0], 0);
  int NT = K>>6;
  int buf = 0;
  for(int kt=0; kt<NT; kt++){
    __syncthreads();
    if(kt+1 < NT) stage(As[buf^1], Bs[buf^1], (kt+1)*64);
    const unsigned short* Ab = &As[buf][0];
    const unsigned short* Bb = &Bs[buf][0];
    #pragma unroll
    for(int kk=0;kk<2;kk++){
      int arow = wm*16 + (l&15);
      int slot = kk*4 + (l>>4);
      short8 af = *(const short8*)(Ab + arow*64 + ((slot^(arow&7))<<3));
      #pragma unroll
      for(int n=0;n<2;n++){
        int col = (wn2*2+n)*16 + (l&15);
        short8 bf = *(const short8*)(Bb + col*64 + ((slot^(col&7))<<3));
        acc[n] = __builtin_amdgcn_mfma_f32_16x16x32_bf16(af, bf, acc[n], 0, 0, 0);
      }
    }
    buf ^= 1;
  }
  #pragma unroll
  for(int n=0;n<2;n++){
    int col = n0 + (wn2*2+n)*16 + (l&15);
    float bv = bias[col];
    #pragma unroll
    for(int i=0;i<4;i++){
      int row = m0 + wm*16 + (l>>4)*4 + i;
      if(ACC) Cf[(size_t)row*N+col] += acc[n][i] + bv;
      else    Cf[(size_t)row*N+col]  = acc[n][i] + bv;
    }
  }
}

// ---------------- fused feature-map kernels ---------------------------------
__global__ __launch_bounds__(256) void featA_k(const unsigned short* __restrict__ qn,
    const unsigned short* __restrict__ kn, const unsigned short* __restrict__ projl,
    unsigned short* __restrict__ qp, unsigned int* __restrict__ gmaxbits){
  int z = blockIdx.y;
  const unsigned short* dn = z ? kn : qn;
  __shared__ __attribute__((aligned(16))) float uni[32*264];
  __shared__ __attribute__((aligned(16))) unsigned short dns[2048];
  unsigned short* ps = (unsigned short*)uni;
  int t = threadIdx.x;
  int w = t>>6, l = t&63;
  size_t R0 = (size_t)blockIdx.x*32;
  {
    int c = w; int r = c*8 + (l>>3);
    int gc = (((l&7) ^ (r&7))<<3);
    gload16(dn + (R0+r)*64 + gc, dns + c*512);
  }
  #pragma unroll
  for(int i=0;i<8;i++){
    int c = w*8 + i; int r = c*8 + (l>>3);
    int gc = (((l&7) ^ (r&7))<<3);
    gload16(projl + (size_t)r*64 + gc, ps + c*512);
  }
  __syncthreads();
  int rt = w&1, cb = (w>>1)*8;
  f32x4 acc[8] = {};
  #pragma unroll
  for(int kk=0;kk<2;kk++){
    int ar = rt*16 + (l&15);
    int slot = kk*4 + (l>>4);
    short8 a = *(const short8*)(dns + ar*64 + ((slot^(ar&7))<<3));
    #pragma unroll
    for(int ct=0;ct<8;ct++){
      int br = (cb+ct)*16 + (l&15);
      short8 b = *(const short8*)(ps + br*64 + ((slot^(br&7))<<3));
      acc[ct] = __builtin_amdgcn_mfma_f32_16x16x32_bf16(a, b, acc[ct], 0, 0, 0);
    }
  }
  __syncthreads();
  #pragma unroll
  for(int ct=0;ct<8;ct++){
    int col = (cb+ct)*16 + (l&15);
    #pragma unroll
    for(int i=0;i<4;i++){
      int row = rt*16 + (l>>4)*4 + i;
      uni[row*264 + col] = acc[ct][i];
    }
  }
  __syncthreads();
  int r = t>>3, sub = t&7;
  float* rowp = uni + r*264 + sub*32;
  f32x4 v[8];
  #pragma unroll
  for(int jj=0;jj<8;jj++) v[jj] = *(const f32x4*)(rowp + jj*4);
  float m = -3.0e38f;
  #pragma unroll
  for(int jj=0;jj<8;jj++)
    #pragma unroll
    for(int i=0;i<4;i++) m = fmaxf(m, v[jj][i]);
  m = fmaxf(m, __shfl_xor(m,1));
  m = fmaxf(m, __shfl_xor(m,2));
  m = fmaxf(m, __shfl_xor(m,4));
  if(z==0){
    us8 dvu = *(const us8*)(dns + r*64 + ((sub^(r&7))<<3));
    float s2 = 0.f;
    #pragma unroll
    for(int j=0;j<8;j++){ float xx = bf2f(dvu[j]); s2 += xx*xx; }
    s2 += __shfl_xor(s2,1); s2 += __shfl_xor(s2,2); s2 += __shfl_xor(s2,4);
    float ds = 0.5f*s2;
    unsigned short* op = qp + (R0+r)*256 + sub*32;
    #pragma unroll
    for(int jj=0;jj<8;jj++){
      us4 u4;
      #pragma unroll
      for(int i=0;i<4;i++) u4[i] = f2bf(expf(v[jj][i] - ds - m)*0.0625f + 1e-4f);
      *(us4*)(op + jj*4) = u4;
    }
  } else {
    float bm = m;
    bm = fmaxf(bm, __shfl_xor(bm,8));
    bm = fmaxf(bm, __shfl_xor(bm,16));
    bm = fmaxf(bm, __shfl_xor(bm,32));
    __shared__ float wm[4];
    if(l==0) wm[w] = bm;
    __syncthreads();
    if(t==0){
      float g = fmaxf(fmaxf(wm[0],wm[1]),fmaxf(wm[2],wm[3]));
      atomicMax(gmaxbits, enc_max(g));
    }
  }
}

__global__ __launch_bounds__(256) void featB_k(const unsigned short* __restrict__ kn,
    const unsigned short* __restrict__ projl, const unsigned int* __restrict__ gmaxbits,
    unsigned short* __restrict__ kp){
  __shared__ __attribute__((aligned(16))) float uni[32*264];
  __shared__ __attribute__((aligned(16))) unsigned short dns[2048];
  unsigned short* ps = (unsigned short*)uni;
  int t = threadIdx.x;
  int w = t>>6, l = t&63;
  size_t R0 = (size_t)blockIdx.x*32;
  {
    int c = w; int r = c*8 + (l>>3);
    int gc = (((l&7) ^ (r&7))<<3);
    gload16(kn + (R0+r)*64 + gc, dns + c*512);
  }
  #pragma unroll
  for(int i=0;i<8;i++){
    int c = w*8 + i; int r = c*8 + (l>>3);
    int gc = (((l&7) ^ (r&7))<<3);
    gload16(projl + (size_t)r*64 + gc, ps + c*512);
  }
  __syncthreads();
  int rt = w&1, cb = (w>>1)*8;
  f32x4 acc[8] = {};
  #pragma unroll
  for(int kk=0;kk<2;kk++){
    int ar = rt*16 + (l&15);
    int slot = kk*4 + (l>>4);
    short8 a = *(const short8*)(dns + ar*64 + ((slot^(ar&7))<<3));
    #pragma unroll
    for(int ct=0;ct<8;ct++){
      int br = (cb+ct)*16 + (l&15);
      short8 b = *(const short8*)(ps + br*64 + ((slot^(br&7))<<3));
      acc[ct] = __builtin_amdgcn_mfma_f32_16x16x32_bf16(a, b, acc[ct], 0, 0, 0);
    }
  }
  __syncthreads();
  #pragma unroll
  for(int ct=0;ct<8;ct++){
    int col = (cb+ct)*16 + (l&15);
    #pragma unroll
    for(int i=0;i<4;i++){
      int row = rt*16 + (l>>4)*4 + i;
      uni[row*264 + col] = acc[ct][i];
    }
  }
  __syncthreads();
  float g = dec_max(gmaxbits[0]);
  int r = t>>3, sub = t&7;
  us8 dvu = *(const us8*)(dns + r*64 + ((sub^(r&7))<<3));
  float s2 = 0.f;
  #pragma unroll
  for(int j=0;j<8;j++){ float xx = bf2f(dvu[j]); s2 += xx*xx; }
  s2 += __shfl_xor(s2,1); s2 += __shfl_xor(s2,2); s2 += __shfl_xor(s2,4);
  float ds = 0.5f*s2;
  float* rowp = uni + r*264 + sub*32;
  unsigned short* op = kp + (R0+r)*256 + sub*32;
  #pragma unroll
  for(int jj=0;jj<8;jj++){
    f32x4 v = *(const f32x4*)(rowp + jj*4);
    us4 u4;
    #pragma unroll
    for(int i=0;i<4;i++) u4[i] = f2bf(expf(v[i] - ds - g)*0.0625f + 1e-4f);
    *(us4*)(op + jj*4) = u4;
  }
}

// ---------------- quadratic causal attention (MFMA scores + MFMA PV) --------
__global__ __launch_bounds__(256) void attn_k(const unsigned short* __restrict__ qp,
    const unsigned short* __restrict__ kp, const unsigned short* __restrict__ vn,
    unsigned short* __restrict__ ob){
  int qt = blockIdx.x, bh = blockIdx.y;
  int b = bh>>3, hh = bh&7;
  __shared__ __attribute__((aligned(16))) unsigned short qs[8192];
  __shared__ __attribute__((aligned(16))) unsigned short ks[8192];
  __shared__ __attribute__((aligned(16))) unsigned short VTs[64*34];
  __shared__ __attribute__((aligned(16))) unsigned short Sb[32*36];
  __shared__ float dens[2][32];
  int t = threadIdx.x;
  int w = t>>6, l = t&63;
  int qh = w>>1, nc = w&1;
  #pragma unroll
  for(int i=0;i<4;i++){
    int c = w*4 + i; int r = (c<<1) + (l>>5); int sl = l&31;
    int gc = ((sl ^ (r&7))<<3);
    int gr = qt*32 + r; if(gr >= SEQL) gr = 0;
    gload16(qp + ((size_t)bh*SEQL + gr)*256 + gc, qs + c*512);
  }
  if(t<64) dens[t>>5][t&31] = 0.f;
  f32x4 oacc[2] = {};
  for(int kt=0; kt<=qt; kt++){
    __syncthreads();            // prev PV done; qs/stage drained
    #pragma unroll
    for(int i=0;i<4;i++){
      int c = w*4 + i; int r = (c<<1) + (l>>5); int sl = l&31;
      int gc = ((sl ^ (r&7))<<3);
      int gk = kt*32 + r; if(gk >= SEQL) gk = 0;
      gload16(kp + ((size_t)bh*SEQL + gk)*256 + gc, ks + c*512);
    }
    {
      int rr = t>>3, od = (t&7)*8;
      int gk = kt*32 + rr;
      us8 uv = {};
      if(gk < SEQL) uv = *(const us8*)(vn + ((size_t)bh*SEQL + gk)*64 + od);
      #pragma unroll
      for(int j=0;j<8;j++) VTs[(od+j)*34 + rr] = uv[j];
    }
    __syncthreads();            // ks + VTs ready
    f32x4 sacc = {};
    #pragma unroll
    for(int kk=0;kk<8;kk++){
      int ar = qh*16 + (l&15); int slot = kk*4 + (l>>4);
      short8 a = *(const short8*)(qs + ar*256 + ((slot^(ar&7))<<3));
      int br = nc*16 + (l&15);
      short8 bb2 = *(const short8*)(ks + br*256 + ((slot^(br&7))<<3));
      sacc = __builtin_amdgcn_mfma_f32_16x16x32_bf16(a, bb2, sacc, 0, 0, 0);
    }
    int scol = nc*16 + (l&15);
    int gcol = kt*32 + scol;
    float dp[4];
    #pragma unroll
    for(int i=0;i<4;i++){
      int sr = qh*16 + (l>>4)*4 + i;
      int grw = qt*32 + sr;
      float v2 = sacc[i];
      if(gcol > grw) v2 = 0.f;
      Sb[sr*36 + scol] = f2bf(v2);
      dp[i] = v2;
    }
    #pragma unroll
    for(int off=1;off<16;off<<=1)
      #pragma unroll
      for(int i=0;i<4;i++) dp[i] += __shfl_xor(dp[i], off);
    if((l&15)==0){
      #pragma unroll
      for(int i=0;i<4;i++) dens[nc][qh*16 + (l>>4)*4 + i] += dp[i];
    }
    __syncthreads();            // Sb ready
    short8 a2 = *(const short8*)(Sb + (qh*16 + (l&15))*36 + (l>>4)*8);
    #pragma unroll
    for(int n2=0;n2<2;n2++){
      int d = nc*32 + n2*16 + (l&15);
      short8 b2 = *(const short8*)(VTs + d*34 + (l>>4)*8);
      oacc[n2] = __builtin_amdgcn_mfma_f32_16x16x32_bf16(a2, b2, oacc[n2], 0, 0, 0);
    }
  }
  __syncthreads();
  #pragma unroll
  for(int n2=0;n2<2;n2++){
    int d = nc*32 + n2*16 + (l&15);
    #pragma unroll
    for(int i=0;i<4;i++){
      int rit = qh*16 + (l>>4)*4 + i;
      int gr = qt*32 + rit;
      if(gr < SEQL){
        float inv = 1.f/(dens[0][rit] + dens[1][rit]);
        ob[((size_t)(b*SEQL+gr))*DIMM + hh*64 + d] = f2bf(oacc[n2][i]*inv);
      }
    }
  }
}

// ---------------- loss ------------------------------------------------------
__global__ __launch_bounds__(256) void loss_k(const float* __restrict__ logits,
    const int* __restrict__ iarr, const int* __restrict__ inds,
    float* __restrict__ rnll){
  int row = blockIdx.x; int t = threadIdx.x;
  const float* lr = logits + (size_t)row*VSZ;
  float m = -3.0e38f;
  for(int j=t;j<VSZ;j+=256) m = fmaxf(m, lr[j]);
  m = blk_max(m);
  float s = 0.f;
  for(int j=t;j<VSZ;j+=256) s += expf(lr[j]-m);
  s = blk_sum(s);
  if(t==0){
    int b = row/SEQL, l = row - b*SEQL;
    int tgt = tok_at(iarr, inds, b, l+1);
    rnll[row] = (m + logf(s)) - lr[tgt];
  }
}

__global__ __launch_bounds__(256) void fin_k(const float* __restrict__ rnll,
    float* __restrict__ out){
  int t = threadIdx.x;
  float s = 0.f;
  for(int i=t;i<NROWS;i+=256) s += rnll[i];
  s = blk_sum(s);
  if(t==0) out[0] = s/(float)NROWS;
}

// ---------------------------------------------------------------------------
extern "C" void kernel_launch(void* const* d_in, const int* in_sizes, int n_in,
                              void* d_out, int out_size, void* d_ws, size_t ws_size,
                              hipStream_t stream){
  (void)in_sizes; (void)n_in; (void)out_size; (void)ws_size;
  const float* x        = (const float*)d_in[0];
  const float* xn       = (const float*)d_in[1];
  const int*   iarr     = (const int*)  d_in[2];
  const float* conv1_w  = (const float*)d_in[3];
  const float* conv1_b  = (const float*)d_in[4];
  const float* conv2_w  = (const float*)d_in[5];
  const float* conv2_b  = (const float*)d_in[6];
  const float* codebook = (const float*)d_in[7];
  const float* proj     = (const float*)d_in[8];
  const float* tok_emb  = (const float*)d_in[9];
  const float* pos_emb  = (const float*)d_in[10];
  const float* ln1_g    = (const float*)d_in[11];
  const float* ln1_b    = (const float*)d_in[12];
  const float* wq       = (const float*)d_in[13];
  const float* wk       = (const float*)d_in[14];
  const float* wv       = (const float*)d_in[15];
  const float* wo       = (const float*)d_in[16];
  const float* bo       = (const float*)d_in[17];
  const float* ln2_g    = (const float*)d_in[18];
  const float* ln2_b    = (const float*)d_in[19];
  const float* ff1_w    = (const float*)d_in[20];
  const float* ff1_b    = (const float*)d_in[21];
  const float* ff2_w    = (const float*)d_in[22];
  const float* ff2_b    = (const float*)d_in[23];
  const float* lnf_g    = (const float*)d_in[24];
  const float* lnf_b    = (const float*)d_in[25];
  const float* logits_w = (const float*)d_in[26];
  const float* logits_b = (const float*)d_in[27];

  float* wsf = (float*)d_ws;
  size_t off = 0;
  unsigned short* qp_bf = (unsigned short*)(wsf + off); off += 2129920;
  unsigned short* kp_bf = (unsigned short*)(wsf + off); off += 2129920;
  float* h = wsf + off; off += 1064960;
  unsigned short* x1b = (unsigned short*)(wsf + off); off += 532480;
  unsigned short* qkvb = (unsigned short*)(wsf + off); off += 1597440;
  unsigned short* ob  = (unsigned short*)(wsf + off); off += 532480;
  unsigned short* projb = (unsigned short*)(wsf + off); off += 49152;
  unsigned short* wall  = (unsigned short*)(wsf + off); off += 9437184; // 6 layers
  unsigned short* logt  = (unsigned short*)(wsf + off); off += 133888;
  unsigned short* ffmid = (unsigned short*)(wsf + off); off += 2129920;
  float* logits = wsf + off; off += 1087840;
  int* inds = (int*)(wsf + off); off += 2048;
  unsigned int* gmaxbits = (unsigned int*)(wsf + off); off += 64;
  float* rnll = wsf + off; off += 2112;

  // pre-loop aliases into regions that are dead before the layer loop
  float* c1 = logits;                                  // 524288 f32
  unsigned short* icol = ffmid;                        // 2048*2048 us
  float* zbuf = (float*)qp_bf;                         // 2048*64 f32
  unsigned short* cw2b = (unsigned short*)kp_bf;       // 64*2048 us

  unsigned short* qnb = qkvb;
  unsigned short* knb = qkvb + QSEG;
  unsigned short* vnb = qkvb + 2*QSEG;

  conv1_k<<<2048,256,0,stream>>>(x, xn, conv1_w, conv1_b, c1);
  cvt8_k<<<64,256,0,stream>>>(conv2_w, cw2b, 16384);
  im2col_k<<<2048,256,0,stream>>>(c1, icol);
  mgemm32_k<0><<<dim3(1,64),256,0,stream>>>(icol, cw2b, conv2_b, zbuf, 64, 2048);
  vq_k<<<2048,256,0,stream>>>(zbuf, codebook, inds);
  embed_k<<<(NROWS*DIMM)/256,256,0,stream>>>(iarr, inds, tok_emb, pos_emb, h);
  cvt8_k<<<48,256,0,stream>>>(proj, projb, 12288);
  wconv_k<<<dim3(17,16),256,0,stream>>>(logits_w, logt, 512, 523);
  wprep_k<<<18432,256,0,stream>>>(wq, wk, wv, wo, ff1_w, ff2_w, wall, gmaxbits);

  for(int l=0;l<6;l++){
    unsigned short* wl    = wall + (size_t)l*WLAYER;
    unsigned short* wqkvt = wl;
    unsigned short* wot   = wl + 786432;
    unsigned short* ff1t  = wl + 1048576;
    unsigned short* ff2t  = wl + 2097152;
    ln_k<<<NROWS,256,0,stream>>>(h, ln1_g+l*DIMM, ln1_b+l*DIMM, x1b);
    mgemm_k<1><<<dim3(24,33),256,0,stream>>>(x1b, wqkvt, nullptr, nullptr, qkvb, NROWS, 1536, DIMM);
    featA_k<<<dim3(520,2),256,0,stream>>>(qnb, knb, projb + l*16384, qp_bf, gmaxbits + l);
    featB_k<<<520,256,0,stream>>>(knb, projb + l*16384, gmaxbits + l, kp_bf);
    attn_k<<<dim3(5,NBH),256,0,stream>>>(qp_bf, kp_bf, vnb, ob);
    mgemm32_k<1><<<dim3(8,65),256,0,stream>>>(ob, wot, bo+l*DIMM, h, DIMM, DIMM);
    ln_k<<<NROWS,256,0,stream>>>(h, ln2_g+l*DIMM, ln2_b+l*DIMM, x1b);
    mgemm_k<4><<<dim3(32,33),256,0,stream>>>(x1b, ff1t, ff1_b+l*2048, nullptr, ffmid, NROWS, 2048, DIMM);
    mgemm32_k<1><<<dim3(8,65),256,0,stream>>>(ffmid, ff2t, ff2_b+l*DIMM, h, DIMM, 2048);
  }

  ln_k<<<NROWS,256,0,stream>>>(h, lnf_g, lnf_b, x1b);
  mgemm_k<0><<<dim3(9,33),256,0,stream>>>(x1b, logt, logits_b, logits, nullptr, NROWS, VSZ, DIMM);
  loss_k<<<NROWS,256,0,stream>>>(logits, iarr, inds, rnll);
  fin_k<<<1,256,0,stream>>>(rnll, (float*)d_out);
}